// Round 1
// baseline (8619.803 us; speedup 1.0000x reference)
//
#include <hip/hip_runtime.h>
#include <hip/hip_bf16.h>
#include <math.h>

#define NN 100000
#define NEDGE 1600000
#define HIDF 128
#define NCLS 18
#define NGR 512

// ---------------- degree / norm prep ----------------
__global__ void count_deg_kernel(const int* __restrict__ dst, int* __restrict__ cnt, int nE) {
    int e = blockIdx.x * blockDim.x + threadIdx.x;
    if (e < nE) atomicAdd(&cnt[dst[e]], 1);
}

__global__ void node_prep_kernel(const int* __restrict__ cnt, float* __restrict__ dinv,
                                 float* __restrict__ selfw, int n) {
    int i = blockIdx.x * blockDim.x + threadIdx.x;
    if (i < n) {
        float deg = (float)cnt[i] + 1.0f;   // +1 self loop
        dinv[i]  = rsqrtf(deg);
        selfw[i] = 1.0f / deg;
    }
}

// ---------------- GEMM: H = f(X) @ W, f = optional (+bias, relu) on input ----------------
// block 256 threads, tile 64 rows x 128 cols, W rows read from global (L2-resident)
__global__ __launch_bounds__(256) void gemm_kernel(const float* __restrict__ X,
                                                   const float* __restrict__ W,
                                                   float* __restrict__ H, int n,
                                                   const float* __restrict__ bias_in,
                                                   int relu_in) {
    __shared__ float xs[64][HIDF];
    int row0 = blockIdx.x * 64;
    for (int idx = threadIdx.x; idx < 64 * HIDF; idx += 256) {
        int r = idx >> 7, c = idx & 127;
        int gr = row0 + r;
        float v = 0.f;
        if (gr < n) v = X[gr * HIDF + c];
        if (bias_in) { v += bias_in[c]; if (relu_in) v = fmaxf(v, 0.f); }
        xs[r][c] = v;
    }
    __syncthreads();
    int tx = threadIdx.x & 31;   // col group: cols 4*tx .. 4*tx+3
    int ty = threadIdx.x >> 5;   // 0..7
    float acc[8][4];
    #pragma unroll
    for (int i = 0; i < 8; i++)
        #pragma unroll
        for (int j = 0; j < 4; j++) acc[i][j] = 0.f;
    #pragma unroll 4
    for (int k = 0; k < HIDF; ++k) {
        float4 w = *reinterpret_cast<const float4*>(&W[k * HIDF + tx * 4]);
        #pragma unroll
        for (int i = 0; i < 8; i++) {
            float xv = xs[i * 8 + ty][k];
            acc[i][0] += xv * w.x; acc[i][1] += xv * w.y;
            acc[i][2] += xv * w.z; acc[i][3] += xv * w.w;
        }
    }
    #pragma unroll
    for (int i = 0; i < 8; i++) {
        int gr = row0 + i * 8 + ty;
        if (gr < n)
            *reinterpret_cast<float4*>(&H[gr * HIDF + tx * 4]) =
                make_float4(acc[i][0], acc[i][1], acc[i][2], acc[i][3]);
    }
}

// ---------------- self-loop init: Hout = Hin * selfw ----------------
__global__ void init_out_kernel(const float* __restrict__ Hin, const float* __restrict__ selfw,
                                float* __restrict__ Hout, int n) {
    int idx = blockIdx.x * blockDim.x + threadIdx.x;  // over n*32 float4s
    if (idx < n * 32) {
        int node = idx >> 5;
        float w = selfw[node];
        float4 v = reinterpret_cast<const float4*>(Hin)[idx];
        v.x *= w; v.y *= w; v.z *= w; v.w *= w;
        reinterpret_cast<float4*>(Hout)[idx] = v;
    }
}

// ---------------- edge aggregation: Hout[dst] += Hin[src] * dinv[src]*dinv[dst] ----------------
__global__ void edge_agg_kernel(const int* __restrict__ src, const int* __restrict__ dst,
                                const float* __restrict__ dinv, const float* __restrict__ Hin,
                                float* __restrict__ Hout, int nE) {
    long long gid = (long long)blockIdx.x * blockDim.x + threadIdx.x;
    int e = (int)(gid >> 5);
    if (e >= nE) return;
    int lane = (int)(gid & 31);
    int s = src[e], d = dst[e];
    float w = dinv[s] * dinv[d];
    float4 v = *reinterpret_cast<const float4*>(&Hin[s * HIDF + lane * 4]);
    float* outp = &Hout[d * HIDF + lane * 4];
    atomicAdd(outp + 0, v.x * w);
    atomicAdd(outp + 1, v.y * w);
    atomicAdd(outp + 2, v.z * w);
    atomicAdd(outp + 3, v.w * w);
}

// ---------------- mean pool (sum + count) ----------------
__global__ void pool_kernel(const float* __restrict__ H, const int* __restrict__ batch,
                            float* __restrict__ gsum, int* __restrict__ gcnt, int n) {
    long long gid = (long long)blockIdx.x * blockDim.x + threadIdx.x;
    int node = (int)(gid >> 5);
    if (node >= n) return;
    int lane = (int)(gid & 31);
    int b = batch[node];
    float4 v = *reinterpret_cast<const float4*>(&H[node * HIDF + lane * 4]);
    float* outp = &gsum[b * HIDF + lane * 4];
    atomicAdd(outp + 0, v.x); atomicAdd(outp + 1, v.y);
    atomicAdd(outp + 2, v.z); atomicAdd(outp + 3, v.w);
    if (lane == 0) atomicAdd(&gcnt[b], 1);
}

// ---------------- centroid head: one wave per graph ----------------
__global__ __launch_bounds__(64) void final_kernel(const float* __restrict__ gsum,
                                                   const int* __restrict__ gcnt,
                                                   const float* __restrict__ b3,
                                                   const float* __restrict__ centroids,
                                                   const float* __restrict__ std_scale,
                                                   const float* __restrict__ ac_temp,
                                                   float* __restrict__ out) {
    int b = blockIdx.x;
    int lane = threadIdx.x;
    float cntf = fmaxf((float)gcnt[b], 1.0f);
    float inv = 1.0f / cntf;
    float g0 = gsum[b * HIDF + lane] * inv + b3[lane];
    float g1 = gsum[b * HIDF + 64 + lane] * inv + b3[64 + lane];
    float mind = 1e30f;
    for (int c = 0; c < NCLS; ++c) {
        float dd[2];
        #pragma unroll
        for (int cent = 0; cent < 2; ++cent) {
            const float* cp = &centroids[(c * 2 + cent) * HIDF];
            float df0 = cp[lane] - g0;
            float df1 = cp[64 + lane] - g1;
            float p = df0 * df0 + df1 * df1;
            #pragma unroll
            for (int off = 32; off > 0; off >>= 1) p += __shfl_xor(p, off);
            dd[cent] = p;
        }
        float dist = fminf(sqrtf(dd[0]), sqrtf(dd[1]));
        mind = fminf(mind, dist);
        if (lane == 0) out[b * NCLS + c] = -dist;
    }
    if (lane == 0) {
        float ss = std_scale[0];
        float clipped = fminf(fmaxf(ss, 0.0f), 5.0f);
        float max_ac = 1.0f + clipped * 0.0f;      // RUNNING_MEAN=1, sqrt(RUNNING_VAR)=0
        float accept = max_ac - mind;
        float soft = 1.0f / (1.0f + expf(-accept / ac_temp[0]));
        out[NGR * NCLS + b] = soft;
    }
}

// ---------------- launch ----------------
extern "C" void kernel_launch(void* const* d_in, const int* in_sizes, int n_in,
                              void* d_out, int out_size, void* d_ws, size_t ws_size,
                              hipStream_t stream) {
    const float* x         = (const float*)d_in[0];
    const int*   edge      = (const int*)d_in[1];
    const int*   batch     = (const int*)d_in[2];
    const float* W1        = (const float*)d_in[3];
    const float* b1        = (const float*)d_in[4];
    const float* W2        = (const float*)d_in[5];
    const float* b2        = (const float*)d_in[6];
    const float* W3        = (const float*)d_in[7];
    const float* b3        = (const float*)d_in[8];
    const float* centroids = (const float*)d_in[9];
    const float* std_scale = (const float*)d_in[10];
    const float* ac_temp   = (const float*)d_in[11];
    float* out = (float*)d_out;

    const int n  = NN;
    const int nE = in_sizes[1] / 2;
    const int* srcp = edge;
    const int* dstp = edge + nE;

    // workspace layout (256B aligned)
    char* ws = (char*)d_ws;
    size_t off = 0;
    auto alloc = [&](size_t bytes) { void* p = ws + off; off = (off + bytes + 255) & ~(size_t)255; return p; };
    float* hA    = (float*)alloc((size_t)NN * HIDF * 4);
    float* hB    = (float*)alloc((size_t)NN * HIDF * 4);
    float* dinv  = (float*)alloc((size_t)NN * 4);
    float* selfw = (float*)alloc((size_t)NN * 4);
    int*   cnt   = (int*)  alloc((size_t)NN * 4);
    float* gsum  = (float*)alloc((size_t)NGR * HIDF * 4);
    int*   gcnt  = (int*)  alloc((size_t)NGR * 4);

    hipMemsetAsync(cnt, 0, (size_t)NN * 4, stream);
    hipMemsetAsync(gsum, 0, (size_t)NGR * HIDF * 4, stream);
    hipMemsetAsync(gcnt, 0, (size_t)NGR * 4, stream);

    count_deg_kernel<<<(nE + 255) / 256, 256, 0, stream>>>(dstp, cnt, nE);
    node_prep_kernel<<<(n + 255) / 256, 256, 0, stream>>>(cnt, dinv, selfw, n);

    int gemm_blocks = (n + 63) / 64;
    int agg_blocks  = (int)(((long long)nE * 32 + 255) / 256);
    int vec_blocks  = (n * 32 + 255) / 256;

    // layer 1: h = x @ W1
    gemm_kernel<<<gemm_blocks, 256, 0, stream>>>(x, W1, hA, n, nullptr, 0);
    init_out_kernel<<<vec_blocks, 256, 0, stream>>>(hA, selfw, hB, n);
    edge_agg_kernel<<<agg_blocks, 256, 0, stream>>>(srcp, dstp, dinv, hA, hB, nE);

    // layer 2: input transform (+b1, relu) fused into GEMM staging
    gemm_kernel<<<gemm_blocks, 256, 0, stream>>>(hB, W2, hA, n, b1, 1);
    init_out_kernel<<<vec_blocks, 256, 0, stream>>>(hA, selfw, hB, n);
    edge_agg_kernel<<<agg_blocks, 256, 0, stream>>>(srcp, dstp, dinv, hA, hB, nE);

    // layer 3: input transform (+b2, relu)
    gemm_kernel<<<gemm_blocks, 256, 0, stream>>>(hB, W3, hA, n, b2, 1);
    init_out_kernel<<<vec_blocks, 256, 0, stream>>>(hA, selfw, hB, n);
    edge_agg_kernel<<<agg_blocks, 256, 0, stream>>>(srcp, dstp, dinv, hA, hB, nE);

    // mean pool (b3 folded into head)
    pool_kernel<<<vec_blocks, 256, 0, stream>>>(hB, batch, gsum, gcnt, n);
    final_kernel<<<NGR, 64, 0, stream>>>(gsum, gcnt, b3, centroids, std_scale, ac_temp, out);
}

// Round 2
// 999.712 us; speedup vs baseline: 8.6223x; 8.6223x over previous
//
#include <hip/hip_runtime.h>
#include <hip/hip_bf16.h>
#include <math.h>

#define NN 100000
#define NEDGE 1600000
#define HIDF 128
#define NCLS 18
#define NGR 512

// ---------------- degree count ----------------
__global__ void count_deg_kernel(const int* __restrict__ dst, int* __restrict__ cnt, int nE) {
    int e = blockIdx.x * blockDim.x + threadIdx.x;
    if (e < nE) atomicAdd(&cnt[dst[e]], 1);
}

__global__ void node_prep_kernel(const int* __restrict__ cnt, float* __restrict__ dinv,
                                 float* __restrict__ selfw, int n) {
    int i = blockIdx.x * blockDim.x + threadIdx.x;
    if (i < n) {
        float deg = (float)cnt[i] + 1.0f;   // +1 self loop
        dinv[i]  = rsqrtf(deg);
        selfw[i] = 1.0f / deg;
    }
}

// ---------------- exclusive scan of cnt -> rowptr (single block) ----------------
__global__ __launch_bounds__(1024) void scan_kernel(const int* __restrict__ cnt,
                                                    int* __restrict__ rowptr, int n) {
    __shared__ int tsum[1024];
    int tid = threadIdx.x;
    int chunk = (n + 1023) / 1024;
    int s = tid * chunk, e = min(s + chunk, n);
    int sum = 0;
    for (int i = s; i < e; i++) sum += cnt[i];
    tsum[tid] = sum;
    __syncthreads();
    // Hillis-Steele inclusive scan in LDS
    for (int off = 1; off < 1024; off <<= 1) {
        int v = (tid >= off) ? tsum[tid - off] : 0;
        __syncthreads();
        tsum[tid] += v;
        __syncthreads();
    }
    int run = (tid == 0) ? 0 : tsum[tid - 1];
    for (int i = s; i < e; i++) { rowptr[i] = run; run += cnt[i]; }
    if (tid == 1023) rowptr[n] = tsum[1023];
}

// ---------------- fill CSR (by dst) ----------------
__global__ void fill_csr_kernel(const int* __restrict__ src, const int* __restrict__ dst,
                                const int* __restrict__ rowptr, int* __restrict__ cursor,
                                int* __restrict__ csr_src, int nE) {
    int e = blockIdx.x * blockDim.x + threadIdx.x;
    if (e < nE) {
        int d = dst[e];
        int pos = atomicAdd(&cursor[d], 1);
        csr_src[rowptr[d] + pos] = src[e];
    }
}

// ---------------- GEMM: H = f(X) @ W, f = optional (+bias, relu) on input ----------------
__global__ __launch_bounds__(256) void gemm_kernel(const float* __restrict__ X,
                                                   const float* __restrict__ W,
                                                   float* __restrict__ H, int n,
                                                   const float* __restrict__ bias_in,
                                                   int relu_in) {
    __shared__ float xs[64][HIDF];
    int row0 = blockIdx.x * 64;
    for (int idx = threadIdx.x; idx < 64 * HIDF; idx += 256) {
        int r = idx >> 7, c = idx & 127;
        int gr = row0 + r;
        float v = 0.f;
        if (gr < n) v = X[gr * HIDF + c];
        if (bias_in) { v += bias_in[c]; if (relu_in) v = fmaxf(v, 0.f); }
        xs[r][c] = v;
    }
    __syncthreads();
    int tx = threadIdx.x & 31;
    int ty = threadIdx.x >> 5;
    float acc[8][4];
    #pragma unroll
    for (int i = 0; i < 8; i++)
        #pragma unroll
        for (int j = 0; j < 4; j++) acc[i][j] = 0.f;
    #pragma unroll 4
    for (int k = 0; k < HIDF; ++k) {
        float4 w = *reinterpret_cast<const float4*>(&W[k * HIDF + tx * 4]);
        #pragma unroll
        for (int i = 0; i < 8; i++) {
            float xv = xs[i * 8 + ty][k];
            acc[i][0] += xv * w.x; acc[i][1] += xv * w.y;
            acc[i][2] += xv * w.z; acc[i][3] += xv * w.w;
        }
    }
    #pragma unroll
    for (int i = 0; i < 8; i++) {
        int gr = row0 + i * 8 + ty;
        if (gr < n)
            *reinterpret_cast<float4*>(&H[gr * HIDF + tx * 4]) =
                make_float4(acc[i][0], acc[i][1], acc[i][2], acc[i][3]);
    }
}

// ---------------- gather aggregation: one 32-lane group per dst node ----------------
// Hout[d] = selfw[d]*Hin[d] + sum_{s in N(d)} dinv[s]*dinv[d]*Hin[s]
__global__ __launch_bounds__(256) void gather_agg_kernel(const float* __restrict__ Hin,
                                                         const int* __restrict__ rowptr,
                                                         const int* __restrict__ csr_src,
                                                         const float* __restrict__ dinv,
                                                         const float* __restrict__ selfw,
                                                         float* __restrict__ Hout, int n) {
    int node = blockIdx.x * 8 + (threadIdx.x >> 5);
    if (node >= n) return;
    int lane = threadIdx.x & 31;
    float dn = dinv[node];
    float4 acc = *reinterpret_cast<const float4*>(&Hin[(size_t)node * HIDF + lane * 4]);
    float sw = selfw[node];
    acc.x *= sw; acc.y *= sw; acc.z *= sw; acc.w *= sw;
    int beg = rowptr[node], end = rowptr[node + 1];
    for (int s = beg; s < end; ++s) {
        int sn = csr_src[s];
        float w = dinv[sn] * dn;
        float4 v = *reinterpret_cast<const float4*>(&Hin[(size_t)sn * HIDF + lane * 4]);
        acc.x += v.x * w; acc.y += v.y * w;
        acc.z += v.z * w; acc.w += v.w * w;
    }
    *reinterpret_cast<float4*>(&Hout[(size_t)node * HIDF + lane * 4]) = acc;
}

// ---------------- mean pool via sorted-batch segment reduce (no atomics) ----------------
__device__ __forceinline__ int lower_bound_i(const int* __restrict__ a, int n, int key) {
    int lo = 0, hi = n;
    while (lo < hi) { int mid = (lo + hi) >> 1; if (a[mid] < key) lo = mid + 1; else hi = mid; }
    return lo;
}

__global__ __launch_bounds__(128) void pool_kernel(const float* __restrict__ H,
                                                   const int* __restrict__ batch,
                                                   const float* __restrict__ b3,
                                                   float* __restrict__ gmean, int n) {
    int b = blockIdx.x;
    int f = threadIdx.x;
    int s = lower_bound_i(batch, n, b);
    int e = lower_bound_i(batch, n, b + 1);
    float sum = 0.f;
    for (int i = s; i < e; ++i) sum += H[(size_t)i * HIDF + f];
    float cnt = fmaxf((float)(e - s), 1.0f);
    gmean[b * HIDF + f] = sum / cnt + b3[f];
}

// ---------------- centroid head: one wave per graph ----------------
__global__ __launch_bounds__(64) void final_kernel(const float* __restrict__ gmean,
                                                   const float* __restrict__ centroids,
                                                   const float* __restrict__ std_scale,
                                                   const float* __restrict__ ac_temp,
                                                   float* __restrict__ out) {
    int b = blockIdx.x;
    int lane = threadIdx.x;
    float g0 = gmean[b * HIDF + lane];
    float g1 = gmean[b * HIDF + 64 + lane];
    float mind = 1e30f;
    for (int c = 0; c < NCLS; ++c) {
        float dd[2];
        #pragma unroll
        for (int cent = 0; cent < 2; ++cent) {
            const float* cp = &centroids[(c * 2 + cent) * HIDF];
            float df0 = cp[lane] - g0;
            float df1 = cp[64 + lane] - g1;
            float p = df0 * df0 + df1 * df1;
            #pragma unroll
            for (int off = 32; off > 0; off >>= 1) p += __shfl_xor(p, off);
            dd[cent] = p;
        }
        float dist = fminf(sqrtf(dd[0]), sqrtf(dd[1]));
        mind = fminf(mind, dist);
        if (lane == 0) out[b * NCLS + c] = -dist;
    }
    if (lane == 0) {
        float ss = std_scale[0];
        float clipped = fminf(fmaxf(ss, 0.0f), 5.0f);
        float max_ac = 1.0f + clipped * 0.0f;      // RUNNING_MEAN=1, sqrt(RUNNING_VAR)=0
        float accept = max_ac - mind;
        float soft = 1.0f / (1.0f + expf(-accept / ac_temp[0]));
        out[NGR * NCLS + b] = soft;
    }
}

// ---------------- launch ----------------
extern "C" void kernel_launch(void* const* d_in, const int* in_sizes, int n_in,
                              void* d_out, int out_size, void* d_ws, size_t ws_size,
                              hipStream_t stream) {
    const float* x         = (const float*)d_in[0];
    const int*   edge      = (const int*)d_in[1];
    const int*   batch     = (const int*)d_in[2];
    const float* W1        = (const float*)d_in[3];
    const float* b1        = (const float*)d_in[4];
    const float* W2        = (const float*)d_in[5];
    const float* b2        = (const float*)d_in[6];
    const float* W3        = (const float*)d_in[7];
    const float* b3        = (const float*)d_in[8];
    const float* centroids = (const float*)d_in[9];
    const float* std_scale = (const float*)d_in[10];
    const float* ac_temp   = (const float*)d_in[11];
    float* out = (float*)d_out;

    const int n  = NN;
    const int nE = in_sizes[1] / 2;
    const int* srcp = edge;
    const int* dstp = edge + nE;

    // workspace layout (256B aligned)
    char* ws = (char*)d_ws;
    size_t off = 0;
    auto alloc = [&](size_t bytes) { void* p = ws + off; off = (off + bytes + 255) & ~(size_t)255; return p; };
    float* hA      = (float*)alloc((size_t)NN * HIDF * 4);
    float* hB      = (float*)alloc((size_t)NN * HIDF * 4);
    float* dinv    = (float*)alloc((size_t)NN * 4);
    float* selfw   = (float*)alloc((size_t)NN * 4);
    int*   cnt     = (int*)  alloc((size_t)NN * 4);       // reused as cursor
    int*   rowptr  = (int*)  alloc((size_t)(NN + 1) * 4);
    int*   csr_src = (int*)  alloc((size_t)NEDGE * 4);
    float* gmean   = (float*)alloc((size_t)NGR * HIDF * 4);

    // ---- CSR build (once, reused by all 3 layers) ----
    hipMemsetAsync(cnt, 0, (size_t)NN * 4, stream);
    count_deg_kernel<<<(nE + 255) / 256, 256, 0, stream>>>(dstp, cnt, nE);
    scan_kernel<<<1, 1024, 0, stream>>>(cnt, rowptr, n);
    node_prep_kernel<<<(n + 255) / 256, 256, 0, stream>>>(cnt, dinv, selfw, n);
    hipMemsetAsync(cnt, 0, (size_t)NN * 4, stream);        // cnt becomes cursor
    fill_csr_kernel<<<(nE + 255) / 256, 256, 0, stream>>>(srcp, dstp, rowptr, cnt, csr_src, nE);

    int gemm_blocks   = (n + 63) / 64;
    int gather_blocks = (n + 7) / 8;

    // layer 1
    gemm_kernel<<<gemm_blocks, 256, 0, stream>>>(x, W1, hA, n, nullptr, 0);
    gather_agg_kernel<<<gather_blocks, 256, 0, stream>>>(hA, rowptr, csr_src, dinv, selfw, hB, n);
    // layer 2 (+b1, relu fused into GEMM input staging)
    gemm_kernel<<<gemm_blocks, 256, 0, stream>>>(hB, W2, hA, n, b1, 1);
    gather_agg_kernel<<<gather_blocks, 256, 0, stream>>>(hA, rowptr, csr_src, dinv, selfw, hB, n);
    // layer 3 (+b2, relu)
    gemm_kernel<<<gemm_blocks, 256, 0, stream>>>(hB, W3, hA, n, b2, 1);
    gather_agg_kernel<<<gather_blocks, 256, 0, stream>>>(hA, rowptr, csr_src, dinv, selfw, hB, n);

    // mean pool (+b3 folded) — batch is sorted, no atomics
    pool_kernel<<<NGR, 128, 0, stream>>>(hB, batch, b3, gmean, n);
    final_kernel<<<NGR, 64, 0, stream>>>(gmean, centroids, std_scale, ac_temp, out);
}

// Round 3
// 845.845 us; speedup vs baseline: 10.1908x; 1.1819x over previous
//
#include <hip/hip_runtime.h>
#include <hip/hip_bf16.h>
#include <math.h>

#define NN 100000
#define NEDGE 1600000
#define HIDF 128
#define NCLS 18
#define NGR 512
#define SC 1024                       // elements per scan chunk
#define SB ((NN + SC - 1) / SC)       // 98 scan blocks

// ---------------- degree count ----------------
__global__ void count_deg_kernel(const int* __restrict__ dst, int* __restrict__ cnt, int nE) {
    int e = blockIdx.x * blockDim.x + threadIdx.x;
    if (e < nE) atomicAdd(&cnt[dst[e]], 1);
}

__global__ void node_prep_kernel(const int* __restrict__ cnt, float* __restrict__ dinv,
                                 float* __restrict__ selfw, int n) {
    int i = blockIdx.x * blockDim.x + threadIdx.x;
    if (i < n) {
        float deg = (float)cnt[i] + 1.0f;   // +1 self loop
        dinv[i]  = rsqrtf(deg);
        selfw[i] = 1.0f / deg;
    }
}

// ---------------- device-wide exclusive scan: 3 phases ----------------
__global__ __launch_bounds__(256) void block_sum_kernel(const int* __restrict__ cnt,
                                                        int* __restrict__ bsum, int n) {
    int base = blockIdx.x * SC;
    int sum = 0;
    for (int i = threadIdx.x; i < SC; i += 256) {
        int idx = base + i;
        if (idx < n) sum += cnt[idx];
    }
    #pragma unroll
    for (int off = 32; off > 0; off >>= 1) sum += __shfl_down(sum, off);
    __shared__ int wsum[4];
    if ((threadIdx.x & 63) == 0) wsum[threadIdx.x >> 6] = sum;
    __syncthreads();
    if (threadIdx.x == 0) bsum[blockIdx.x] = wsum[0] + wsum[1] + wsum[2] + wsum[3];
}

__global__ __launch_bounds__(128) void scan_bsum_kernel(const int* __restrict__ bsum,
                                                        int* __restrict__ boff, int nb) {
    __shared__ int t[128];
    int tid = threadIdx.x;
    t[tid] = (tid < nb) ? bsum[tid] : 0;
    __syncthreads();
    for (int off = 1; off < 128; off <<= 1) {
        int v = (tid >= off) ? t[tid - off] : 0;
        __syncthreads();
        t[tid] += v;
        __syncthreads();
    }
    if (tid < nb) boff[tid] = (tid == 0) ? 0 : t[tid - 1];
}

__global__ __launch_bounds__(256) void scan_fill_kernel(const int* __restrict__ cnt,
                                                        const int* __restrict__ boff,
                                                        int* __restrict__ rowptr, int n, int nE) {
    __shared__ int t[256];
    int base = blockIdx.x * SC;
    int s = base + threadIdx.x * 4;
    int v0 = 0, v1 = 0, v2 = 0, v3 = 0;
    if (s + 0 < n) v0 = cnt[s + 0];
    if (s + 1 < n) v1 = cnt[s + 1];
    if (s + 2 < n) v2 = cnt[s + 2];
    if (s + 3 < n) v3 = cnt[s + 3];
    int sum = v0 + v1 + v2 + v3;
    t[threadIdx.x] = sum;
    __syncthreads();
    for (int off = 1; off < 256; off <<= 1) {
        int v = (threadIdx.x >= off) ? t[threadIdx.x - off] : 0;
        __syncthreads();
        t[threadIdx.x] += v;
        __syncthreads();
    }
    int run = boff[blockIdx.x] + ((threadIdx.x == 0) ? 0 : t[threadIdx.x - 1]);
    if (s + 0 < n) { rowptr[s + 0] = run; run += v0; }
    if (s + 1 < n) { rowptr[s + 1] = run; run += v1; }
    if (s + 2 < n) { rowptr[s + 2] = run; run += v2; }
    if (s + 3 < n) { rowptr[s + 3] = run; run += v3; }
    if (blockIdx.x == 0 && threadIdx.x == 0) rowptr[n] = nE;
}

// ---------------- fill CSR (by dst) ----------------
__global__ void fill_csr_kernel(const int* __restrict__ src, const int* __restrict__ dst,
                                const int* __restrict__ rowptr, int* __restrict__ cursor,
                                int* __restrict__ csr_src, int nE) {
    int e = blockIdx.x * blockDim.x + threadIdx.x;
    if (e < nE) {
        int d = dst[e];
        int pos = atomicAdd(&cursor[d], 1);
        csr_src[rowptr[d] + pos] = src[e];
    }
}

// ---------------- GEMM: H = f(X) @ W, f = optional (+bias, relu) on input ----------------
__global__ __launch_bounds__(256) void gemm_kernel(const float* __restrict__ X,
                                                   const float* __restrict__ W,
                                                   float* __restrict__ H, int n,
                                                   const float* __restrict__ bias_in,
                                                   int relu_in) {
    __shared__ float xs[64][HIDF];
    int row0 = blockIdx.x * 64;
    for (int idx = threadIdx.x; idx < 64 * HIDF; idx += 256) {
        int r = idx >> 7, c = idx & 127;
        int gr = row0 + r;
        float v = 0.f;
        if (gr < n) v = X[gr * HIDF + c];
        if (bias_in) { v += bias_in[c]; if (relu_in) v = fmaxf(v, 0.f); }
        xs[r][c] = v;
    }
    __syncthreads();
    int tx = threadIdx.x & 31;
    int ty = threadIdx.x >> 5;
    float acc[8][4];
    #pragma unroll
    for (int i = 0; i < 8; i++)
        #pragma unroll
        for (int j = 0; j < 4; j++) acc[i][j] = 0.f;
    #pragma unroll 4
    for (int k = 0; k < HIDF; ++k) {
        float4 w = *reinterpret_cast<const float4*>(&W[k * HIDF + tx * 4]);
        #pragma unroll
        for (int i = 0; i < 8; i++) {
            float xv = xs[i * 8 + ty][k];
            acc[i][0] += xv * w.x; acc[i][1] += xv * w.y;
            acc[i][2] += xv * w.z; acc[i][3] += xv * w.w;
        }
    }
    #pragma unroll
    for (int i = 0; i < 8; i++) {
        int gr = row0 + i * 8 + ty;
        if (gr < n)
            *reinterpret_cast<float4*>(&H[gr * HIDF + tx * 4]) =
                make_float4(acc[i][0], acc[i][1], acc[i][2], acc[i][3]);
    }
}

// ---------------- gather aggregation: one 32-lane group per dst node ----------------
// Hout[d] = selfw[d]*Hin[d] + sum_{s in N(d)} dinv[s]*dinv[d]*Hin[s]
__global__ __launch_bounds__(256) void gather_agg_kernel(const float* __restrict__ Hin,
                                                         const int* __restrict__ rowptr,
                                                         const int* __restrict__ csr_src,
                                                         const float* __restrict__ dinv,
                                                         const float* __restrict__ selfw,
                                                         float* __restrict__ Hout, int n) {
    int node = blockIdx.x * 8 + (threadIdx.x >> 5);
    if (node >= n) return;
    int lane = threadIdx.x & 31;
    float dn = dinv[node];
    float4 acc = *reinterpret_cast<const float4*>(&Hin[(size_t)node * HIDF + lane * 4]);
    float sw = selfw[node];
    acc.x *= sw; acc.y *= sw; acc.z *= sw; acc.w *= sw;
    int beg = rowptr[node], end = rowptr[node + 1];
    for (int s = beg; s < end; ++s) {
        int sn = csr_src[s];
        float w = dinv[sn] * dn;
        float4 v = *reinterpret_cast<const float4*>(&Hin[(size_t)sn * HIDF + lane * 4]);
        acc.x += v.x * w; acc.y += v.y * w;
        acc.z += v.z * w; acc.w += v.w * w;
    }
    *reinterpret_cast<float4*>(&Hout[(size_t)node * HIDF + lane * 4]) = acc;
}

// ---------------- mean pool via sorted-batch segment reduce (no atomics) ----------------
__device__ __forceinline__ int lower_bound_i(const int* __restrict__ a, int n, int key) {
    int lo = 0, hi = n;
    while (lo < hi) { int mid = (lo + hi) >> 1; if (a[mid] < key) lo = mid + 1; else hi = mid; }
    return lo;
}

__global__ __launch_bounds__(128) void pool_kernel(const float* __restrict__ H,
                                                   const int* __restrict__ batch,
                                                   const float* __restrict__ b3,
                                                   float* __restrict__ gmean, int n) {
    int b = blockIdx.x;
    int f = threadIdx.x;
    int s = lower_bound_i(batch, n, b);
    int e = lower_bound_i(batch, n, b + 1);
    float sum = 0.f;
    for (int i = s; i < e; ++i) sum += H[(size_t)i * HIDF + f];
    float cnt = fmaxf((float)(e - s), 1.0f);
    gmean[b * HIDF + f] = sum / cnt + b3[f];
}

// ---------------- centroid head: one wave per graph ----------------
__global__ __launch_bounds__(64) void final_kernel(const float* __restrict__ gmean,
                                                   const float* __restrict__ centroids,
                                                   const float* __restrict__ std_scale,
                                                   const float* __restrict__ ac_temp,
                                                   float* __restrict__ out) {
    int b = blockIdx.x;
    int lane = threadIdx.x;
    float g0 = gmean[b * HIDF + lane];
    float g1 = gmean[b * HIDF + 64 + lane];
    float mind = 1e30f;
    for (int c = 0; c < NCLS; ++c) {
        float dd[2];
        #pragma unroll
        for (int cent = 0; cent < 2; ++cent) {
            const float* cp = &centroids[(c * 2 + cent) * HIDF];
            float df0 = cp[lane] - g0;
            float df1 = cp[64 + lane] - g1;
            float p = df0 * df0 + df1 * df1;
            #pragma unroll
            for (int off = 32; off > 0; off >>= 1) p += __shfl_xor(p, off);
            dd[cent] = p;
        }
        float dist = fminf(sqrtf(dd[0]), sqrtf(dd[1]));
        mind = fminf(mind, dist);
        if (lane == 0) out[b * NCLS + c] = -dist;
    }
    if (lane == 0) {
        float ss = std_scale[0];
        float clipped = fminf(fmaxf(ss, 0.0f), 5.0f);
        float max_ac = 1.0f + clipped * 0.0f;      // RUNNING_MEAN=1, sqrt(RUNNING_VAR)=0
        float accept = max_ac - mind;
        float soft = 1.0f / (1.0f + expf(-accept / ac_temp[0]));
        out[NGR * NCLS + b] = soft;
    }
}

// ---------------- launch ----------------
extern "C" void kernel_launch(void* const* d_in, const int* in_sizes, int n_in,
                              void* d_out, int out_size, void* d_ws, size_t ws_size,
                              hipStream_t stream) {
    const float* x         = (const float*)d_in[0];
    const int*   edge      = (const int*)d_in[1];
    const int*   batch     = (const int*)d_in[2];
    const float* W1        = (const float*)d_in[3];
    const float* b1        = (const float*)d_in[4];
    const float* W2        = (const float*)d_in[5];
    const float* b2        = (const float*)d_in[6];
    const float* W3        = (const float*)d_in[7];
    const float* b3        = (const float*)d_in[8];
    const float* centroids = (const float*)d_in[9];
    const float* std_scale = (const float*)d_in[10];
    const float* ac_temp   = (const float*)d_in[11];
    float* out = (float*)d_out;

    const int n  = NN;
    const int nE = in_sizes[1] / 2;
    const int* srcp = edge;
    const int* dstp = edge + nE;

    // workspace layout (256B aligned)
    char* ws = (char*)d_ws;
    size_t off = 0;
    auto alloc = [&](size_t bytes) { void* p = ws + off; off = (off + bytes + 255) & ~(size_t)255; return p; };
    float* hA      = (float*)alloc((size_t)NN * HIDF * 4);
    float* hB      = (float*)alloc((size_t)NN * HIDF * 4);
    float* dinv    = (float*)alloc((size_t)NN * 4);
    float* selfw   = (float*)alloc((size_t)NN * 4);
    int*   cnt     = (int*)  alloc((size_t)NN * 4);       // reused as cursor
    int*   rowptr  = (int*)  alloc((size_t)(NN + 1) * 4);
    int*   csr_src = (int*)  alloc((size_t)NEDGE * 4);
    float* gmean   = (float*)alloc((size_t)NGR * HIDF * 4);
    int*   bsum    = (int*)  alloc((size_t)SB * 4);
    int*   boff    = (int*)  alloc((size_t)SB * 4);

    // ---- CSR build (once, reused by all 3 layers) ----
    hipMemsetAsync(cnt, 0, (size_t)NN * 4, stream);
    count_deg_kernel<<<(nE + 255) / 256, 256, 0, stream>>>(dstp, cnt, nE);
    block_sum_kernel<<<SB, 256, 0, stream>>>(cnt, bsum, n);
    scan_bsum_kernel<<<1, 128, 0, stream>>>(bsum, boff, SB);
    scan_fill_kernel<<<SB, 256, 0, stream>>>(cnt, boff, rowptr, n, nE);
    node_prep_kernel<<<(n + 255) / 256, 256, 0, stream>>>(cnt, dinv, selfw, n);
    hipMemsetAsync(cnt, 0, (size_t)NN * 4, stream);        // cnt becomes cursor
    fill_csr_kernel<<<(nE + 255) / 256, 256, 0, stream>>>(srcp, dstp, rowptr, cnt, csr_src, nE);

    int gemm_blocks   = (n + 63) / 64;
    int gather_blocks = (n + 7) / 8;

    // layer 1
    gemm_kernel<<<gemm_blocks, 256, 0, stream>>>(x, W1, hA, n, nullptr, 0);
    gather_agg_kernel<<<gather_blocks, 256, 0, stream>>>(hA, rowptr, csr_src, dinv, selfw, hB, n);
    // layer 2 (+b1, relu fused into GEMM input staging)
    gemm_kernel<<<gemm_blocks, 256, 0, stream>>>(hB, W2, hA, n, b1, 1);
    gather_agg_kernel<<<gather_blocks, 256, 0, stream>>>(hA, rowptr, csr_src, dinv, selfw, hB, n);
    // layer 3 (+b2, relu)
    gemm_kernel<<<gemm_blocks, 256, 0, stream>>>(hB, W3, hA, n, b2, 1);
    gather_agg_kernel<<<gather_blocks, 256, 0, stream>>>(hA, rowptr, csr_src, dinv, selfw, hB, n);

    // mean pool (+b3 folded) — batch is sorted, no atomics
    pool_kernel<<<NGR, 128, 0, stream>>>(hB, batch, b3, gmean, n);
    final_kernel<<<NGR, 64, 0, stream>>>(gmean, centroids, std_scale, ac_temp, out);
}

// Round 4
// 844.009 us; speedup vs baseline: 10.2129x; 1.0022x over previous
//
#include <hip/hip_runtime.h>
#include <hip/hip_bf16.h>
#include <math.h>

#define NN 100000
#define NEDGE 1600000
#define HIDF 128
#define NCLS 18
#define NGR 512
#define SC 1024                       // elements per scan chunk
#define SB ((NN + SC - 1) / SC)       // 98 scan blocks

__device__ __forceinline__ float b2f(unsigned short u) {
    return __uint_as_float(((unsigned)u) << 16);
}
__device__ __forceinline__ unsigned short f2b(float f) {   // round-to-nearest-even
    unsigned u = __float_as_uint(f);
    unsigned r = (u + 0x7fffu + ((u >> 16) & 1u)) >> 16;
    return (unsigned short)r;
}

// ---------------- degree count ----------------
__global__ void count_deg_kernel(const int* __restrict__ dst, int* __restrict__ cnt, int nE) {
    int e = blockIdx.x * blockDim.x + threadIdx.x;
    if (e < nE) atomicAdd(&cnt[dst[e]], 1);
}

__global__ void node_prep_kernel(const int* __restrict__ cnt, float* __restrict__ dinv,
                                 float* __restrict__ selfw, int n) {
    int i = blockIdx.x * blockDim.x + threadIdx.x;
    if (i < n) {
        float deg = (float)cnt[i] + 1.0f;   // +1 self loop
        dinv[i]  = rsqrtf(deg);
        selfw[i] = 1.0f / deg;
    }
}

// ---------------- device-wide exclusive scan: 3 phases ----------------
__global__ __launch_bounds__(256) void block_sum_kernel(const int* __restrict__ cnt,
                                                        int* __restrict__ bsum, int n) {
    int base = blockIdx.x * SC;
    int sum = 0;
    for (int i = threadIdx.x; i < SC; i += 256) {
        int idx = base + i;
        if (idx < n) sum += cnt[idx];
    }
    #pragma unroll
    for (int off = 32; off > 0; off >>= 1) sum += __shfl_down(sum, off);
    __shared__ int wsum[4];
    if ((threadIdx.x & 63) == 0) wsum[threadIdx.x >> 6] = sum;
    __syncthreads();
    if (threadIdx.x == 0) bsum[blockIdx.x] = wsum[0] + wsum[1] + wsum[2] + wsum[3];
}

__global__ __launch_bounds__(128) void scan_bsum_kernel(const int* __restrict__ bsum,
                                                        int* __restrict__ boff, int nb) {
    __shared__ int t[128];
    int tid = threadIdx.x;
    t[tid] = (tid < nb) ? bsum[tid] : 0;
    __syncthreads();
    for (int off = 1; off < 128; off <<= 1) {
        int v = (tid >= off) ? t[tid - off] : 0;
        __syncthreads();
        t[tid] += v;
        __syncthreads();
    }
    if (tid < nb) boff[tid] = (tid == 0) ? 0 : t[tid - 1];
}

__global__ __launch_bounds__(256) void scan_fill_kernel(const int* __restrict__ cnt,
                                                        const int* __restrict__ boff,
                                                        int* __restrict__ rowptr, int n, int nE) {
    __shared__ int t[256];
    int base = blockIdx.x * SC;
    int s = base + threadIdx.x * 4;
    int v0 = 0, v1 = 0, v2 = 0, v3 = 0;
    if (s + 0 < n) v0 = cnt[s + 0];
    if (s + 1 < n) v1 = cnt[s + 1];
    if (s + 2 < n) v2 = cnt[s + 2];
    if (s + 3 < n) v3 = cnt[s + 3];
    int sum = v0 + v1 + v2 + v3;
    t[threadIdx.x] = sum;
    __syncthreads();
    for (int off = 1; off < 256; off <<= 1) {
        int v = (threadIdx.x >= off) ? t[threadIdx.x - off] : 0;
        __syncthreads();
        t[threadIdx.x] += v;
        __syncthreads();
    }
    int run = boff[blockIdx.x] + ((threadIdx.x == 0) ? 0 : t[threadIdx.x - 1]);
    if (s + 0 < n) { rowptr[s + 0] = run; run += v0; }
    if (s + 1 < n) { rowptr[s + 1] = run; run += v1; }
    if (s + 2 < n) { rowptr[s + 2] = run; run += v2; }
    if (s + 3 < n) { rowptr[s + 3] = run; run += v3; }
    if (blockIdx.x == 0 && threadIdx.x == 0) rowptr[n] = nE;
}

// ---------------- fill CSR (by dst) ----------------
__global__ void fill_csr_kernel(const int* __restrict__ src, const int* __restrict__ dst,
                                const int* __restrict__ rowptr, int* __restrict__ cursor,
                                int* __restrict__ csr_src, int nE) {
    int e = blockIdx.x * blockDim.x + threadIdx.x;
    if (e < nE) {
        int d = dst[e];
        int pos = atomicAdd(&cursor[d], 1);
        csr_src[rowptr[d] + pos] = src[e];
    }
}

// ---------------- GEMM: Hbf = f(X) @ W  (bf16 output), f = optional (+bias, relu) ----------------
__global__ __launch_bounds__(256) void gemm_kernel(const float* __restrict__ X,
                                                   const float* __restrict__ W,
                                                   unsigned short* __restrict__ Hbf, int n,
                                                   const float* __restrict__ bias_in,
                                                   int relu_in) {
    __shared__ float xs[64][HIDF];
    int row0 = blockIdx.x * 64;
    for (int idx = threadIdx.x; idx < 64 * HIDF; idx += 256) {
        int r = idx >> 7, c = idx & 127;
        int gr = row0 + r;
        float v = 0.f;
        if (gr < n) v = X[gr * HIDF + c];
        if (bias_in) { v += bias_in[c]; if (relu_in) v = fmaxf(v, 0.f); }
        xs[r][c] = v;
    }
    __syncthreads();
    int tx = threadIdx.x & 31;
    int ty = threadIdx.x >> 5;
    float acc[8][4];
    #pragma unroll
    for (int i = 0; i < 8; i++)
        #pragma unroll
        for (int j = 0; j < 4; j++) acc[i][j] = 0.f;
    #pragma unroll 4
    for (int k = 0; k < HIDF; ++k) {
        float4 w = *reinterpret_cast<const float4*>(&W[k * HIDF + tx * 4]);
        #pragma unroll
        for (int i = 0; i < 8; i++) {
            float xv = xs[i * 8 + ty][k];
            acc[i][0] += xv * w.x; acc[i][1] += xv * w.y;
            acc[i][2] += xv * w.z; acc[i][3] += xv * w.w;
        }
    }
    #pragma unroll
    for (int i = 0; i < 8; i++) {
        int gr = row0 + i * 8 + ty;
        if (gr < n) {
            ushort4 o;
            o.x = f2b(acc[i][0]); o.y = f2b(acc[i][1]);
            o.z = f2b(acc[i][2]); o.w = f2b(acc[i][3]);
            *reinterpret_cast<ushort4*>(&Hbf[(size_t)gr * HIDF + tx * 4]) = o;
        }
    }
}

// ---------------- gather aggregation over bf16 table: one 32-lane group per dst node ----------------
// Hout[d] = selfw[d]*Hin[d] + sum_{s in N(d)} dinv[s]*dinv[d]*Hin[s]   (Hin bf16, acc f32)
__global__ __launch_bounds__(256) void gather_agg_kernel(const unsigned short* __restrict__ Hin,
                                                         const int* __restrict__ rowptr,
                                                         const int* __restrict__ csr_src,
                                                         const float* __restrict__ dinv,
                                                         const float* __restrict__ selfw,
                                                         float* __restrict__ Hout, int n) {
    int node = blockIdx.x * 8 + (threadIdx.x >> 5);
    if (node >= n) return;
    int lane = threadIdx.x & 31;
    float dn = dinv[node];
    ushort4 sv = *reinterpret_cast<const ushort4*>(&Hin[(size_t)node * HIDF + lane * 4]);
    float sw = selfw[node];
    float4 acc;
    acc.x = b2f(sv.x) * sw; acc.y = b2f(sv.y) * sw;
    acc.z = b2f(sv.z) * sw; acc.w = b2f(sv.w) * sw;
    int beg = rowptr[node], end = rowptr[node + 1];
    for (int s = beg; s < end; ++s) {
        int sn = csr_src[s];
        float w = dinv[sn] * dn;
        ushort4 v = *reinterpret_cast<const ushort4*>(&Hin[(size_t)sn * HIDF + lane * 4]);
        acc.x += b2f(v.x) * w; acc.y += b2f(v.y) * w;
        acc.z += b2f(v.z) * w; acc.w += b2f(v.w) * w;
    }
    *reinterpret_cast<float4*>(&Hout[(size_t)node * HIDF + lane * 4]) = acc;
}

// ---------------- mean pool via sorted-batch segment reduce (no atomics) ----------------
__device__ __forceinline__ int lower_bound_i(const int* __restrict__ a, int n, int key) {
    int lo = 0, hi = n;
    while (lo < hi) { int mid = (lo + hi) >> 1; if (a[mid] < key) lo = mid + 1; else hi = mid; }
    return lo;
}

__global__ __launch_bounds__(128) void pool_kernel(const float* __restrict__ H,
                                                   const int* __restrict__ batch,
                                                   const float* __restrict__ b3,
                                                   float* __restrict__ gmean, int n) {
    int b = blockIdx.x;
    int f = threadIdx.x;
    int s = lower_bound_i(batch, n, b);
    int e = lower_bound_i(batch, n, b + 1);
    float sum = 0.f;
    for (int i = s; i < e; ++i) sum += H[(size_t)i * HIDF + f];
    float cnt = fmaxf((float)(e - s), 1.0f);
    gmean[b * HIDF + f] = sum / cnt + b3[f];
}

// ---------------- centroid head: one wave per graph ----------------
__global__ __launch_bounds__(64) void final_kernel(const float* __restrict__ gmean,
                                                   const float* __restrict__ centroids,
                                                   const float* __restrict__ std_scale,
                                                   const float* __restrict__ ac_temp,
                                                   float* __restrict__ out) {
    int b = blockIdx.x;
    int lane = threadIdx.x;
    float g0 = gmean[b * HIDF + lane];
    float g1 = gmean[b * HIDF + 64 + lane];
    float mind = 1e30f;
    for (int c = 0; c < NCLS; ++c) {
        float dd[2];
        #pragma unroll
        for (int cent = 0; cent < 2; ++cent) {
            const float* cp = &centroids[(c * 2 + cent) * HIDF];
            float df0 = cp[lane] - g0;
            float df1 = cp[64 + lane] - g1;
            float p = df0 * df0 + df1 * df1;
            #pragma unroll
            for (int off = 32; off > 0; off >>= 1) p += __shfl_xor(p, off);
            dd[cent] = p;
        }
        float dist = fminf(sqrtf(dd[0]), sqrtf(dd[1]));
        mind = fminf(mind, dist);
        if (lane == 0) out[b * NCLS + c] = -dist;
    }
    if (lane == 0) {
        float ss = std_scale[0];
        float clipped = fminf(fmaxf(ss, 0.0f), 5.0f);
        float max_ac = 1.0f + clipped * 0.0f;      // RUNNING_MEAN=1, sqrt(RUNNING_VAR)=0
        float accept = max_ac - mind;
        float soft = 1.0f / (1.0f + expf(-accept / ac_temp[0]));
        out[NGR * NCLS + b] = soft;
    }
}

// ---------------- launch ----------------
extern "C" void kernel_launch(void* const* d_in, const int* in_sizes, int n_in,
                              void* d_out, int out_size, void* d_ws, size_t ws_size,
                              hipStream_t stream) {
    const float* x         = (const float*)d_in[0];
    const int*   edge      = (const int*)d_in[1];
    const int*   batch     = (const int*)d_in[2];
    const float* W1        = (const float*)d_in[3];
    const float* b1        = (const float*)d_in[4];
    const float* W2        = (const float*)d_in[5];
    const float* b2        = (const float*)d_in[6];
    const float* W3        = (const float*)d_in[7];
    const float* b3        = (const float*)d_in[8];
    const float* centroids = (const float*)d_in[9];
    const float* std_scale = (const float*)d_in[10];
    const float* ac_temp   = (const float*)d_in[11];
    float* out = (float*)d_out;

    const int n  = NN;
    const int nE = in_sizes[1] / 2;
    const int* srcp = edge;
    const int* dstp = edge + nE;

    // workspace layout (256B aligned)
    char* ws = (char*)d_ws;
    size_t off = 0;
    auto alloc = [&](size_t bytes) { void* p = ws + off; off = (off + bytes + 255) & ~(size_t)255; return p; };
    unsigned short* hA = (unsigned short*)alloc((size_t)NN * HIDF * 2);  // bf16 GEMM output
    float* hB      = (float*)alloc((size_t)NN * HIDF * 4);               // f32 gather output
    float* dinv    = (float*)alloc((size_t)NN * 4);
    float* selfw   = (float*)alloc((size_t)NN * 4);
    int*   cnt     = (int*)  alloc((size_t)NN * 4);       // reused as cursor
    int*   rowptr  = (int*)  alloc((size_t)(NN + 1) * 4);
    int*   csr_src = (int*)  alloc((size_t)NEDGE * 4);
    float* gmean   = (float*)alloc((size_t)NGR * HIDF * 4);
    int*   bsum    = (int*)  alloc((size_t)SB * 4);
    int*   boff    = (int*)  alloc((size_t)SB * 4);

    // ---- CSR build (once, reused by all 3 layers) ----
    hipMemsetAsync(cnt, 0, (size_t)NN * 4, stream);
    count_deg_kernel<<<(nE + 255) / 256, 256, 0, stream>>>(dstp, cnt, nE);
    block_sum_kernel<<<SB, 256, 0, stream>>>(cnt, bsum, n);
    scan_bsum_kernel<<<1, 128, 0, stream>>>(bsum, boff, SB);
    scan_fill_kernel<<<SB, 256, 0, stream>>>(cnt, boff, rowptr, n, nE);
    node_prep_kernel<<<(n + 255) / 256, 256, 0, stream>>>(cnt, dinv, selfw, n);
    hipMemsetAsync(cnt, 0, (size_t)NN * 4, stream);        // cnt becomes cursor
    fill_csr_kernel<<<(nE + 255) / 256, 256, 0, stream>>>(srcp, dstp, rowptr, cnt, csr_src, nE);

    int gemm_blocks   = (n + 63) / 64;
    int gather_blocks = (n + 7) / 8;

    // layer 1
    gemm_kernel<<<gemm_blocks, 256, 0, stream>>>(x, W1, hA, n, nullptr, 0);
    gather_agg_kernel<<<gather_blocks, 256, 0, stream>>>(hA, rowptr, csr_src, dinv, selfw, hB, n);
    // layer 2 (+b1, relu fused into GEMM input staging)
    gemm_kernel<<<gemm_blocks, 256, 0, stream>>>(hB, W2, hA, n, b1, 1);
    gather_agg_kernel<<<gather_blocks, 256, 0, stream>>>(hA, rowptr, csr_src, dinv, selfw, hB, n);
    // layer 3 (+b2, relu)
    gemm_kernel<<<gemm_blocks, 256, 0, stream>>>(hB, W3, hA, n, b2, 1);
    gather_agg_kernel<<<gather_blocks, 256, 0, stream>>>(hA, rowptr, csr_src, dinv, selfw, hB, n);

    // mean pool (+b3 folded) — batch is sorted, no atomics
    pool_kernel<<<NGR, 128, 0, stream>>>(hB, batch, b3, gmean, n);
    final_kernel<<<NGR, 64, 0, stream>>>(gmean, centroids, std_scale, ac_temp, out);
}

// Round 5
// 643.311 us; speedup vs baseline: 13.3991x; 1.3120x over previous
//
#include <hip/hip_runtime.h>
#include <hip/hip_bf16.h>
#include <math.h>

#define NN 100000
#define NEDGE 1600000
#define HIDF 128
#define NCLS 18
#define NGR 512
#define SC 1024                       // elements per scan chunk
#define SB ((NN + SC - 1) / SC)       // 98 scan blocks

__device__ __forceinline__ float b2f(unsigned short u) {
    return __uint_as_float(((unsigned)u) << 16);
}
__device__ __forceinline__ unsigned short f2b(float f) {   // round-to-nearest-even
    unsigned u = __float_as_uint(f);
    unsigned r = (u + 0x7fffu + ((u >> 16) & 1u)) >> 16;
    return (unsigned short)r;
}

// ---------------- degree count ----------------
__global__ void count_deg_kernel(const int* __restrict__ dst, int* __restrict__ cnt, int nE) {
    int e = blockIdx.x * blockDim.x + threadIdx.x;
    if (e < nE) atomicAdd(&cnt[dst[e]], 1);
}

__global__ void node_prep_kernel(const int* __restrict__ cnt, float* __restrict__ dinv,
                                 float* __restrict__ selfw, int n) {
    int i = blockIdx.x * blockDim.x + threadIdx.x;
    if (i < n) {
        float deg = (float)cnt[i] + 1.0f;   // +1 self loop
        dinv[i]  = rsqrtf(deg);
        selfw[i] = 1.0f / deg;
    }
}

// ---------------- device-wide exclusive scan: 3 phases ----------------
__global__ __launch_bounds__(256) void block_sum_kernel(const int* __restrict__ cnt,
                                                        int* __restrict__ bsum, int n) {
    int base = blockIdx.x * SC;
    int sum = 0;
    for (int i = threadIdx.x; i < SC; i += 256) {
        int idx = base + i;
        if (idx < n) sum += cnt[idx];
    }
    #pragma unroll
    for (int off = 32; off > 0; off >>= 1) sum += __shfl_down(sum, off);
    __shared__ int wsum[4];
    if ((threadIdx.x & 63) == 0) wsum[threadIdx.x >> 6] = sum;
    __syncthreads();
    if (threadIdx.x == 0) bsum[blockIdx.x] = wsum[0] + wsum[1] + wsum[2] + wsum[3];
}

__global__ __launch_bounds__(128) void scan_bsum_kernel(const int* __restrict__ bsum,
                                                        int* __restrict__ boff, int nb) {
    __shared__ int t[128];
    int tid = threadIdx.x;
    t[tid] = (tid < nb) ? bsum[tid] : 0;
    __syncthreads();
    for (int off = 1; off < 128; off <<= 1) {
        int v = (tid >= off) ? t[tid - off] : 0;
        __syncthreads();
        t[tid] += v;
        __syncthreads();
    }
    if (tid < nb) boff[tid] = (tid == 0) ? 0 : t[tid - 1];
}

__global__ __launch_bounds__(256) void scan_fill_kernel(const int* __restrict__ cnt,
                                                        const int* __restrict__ boff,
                                                        int* __restrict__ rowptr, int n, int nE) {
    __shared__ int t[256];
    int base = blockIdx.x * SC;
    int s = base + threadIdx.x * 4;
    int v0 = 0, v1 = 0, v2 = 0, v3 = 0;
    if (s + 0 < n) v0 = cnt[s + 0];
    if (s + 1 < n) v1 = cnt[s + 1];
    if (s + 2 < n) v2 = cnt[s + 2];
    if (s + 3 < n) v3 = cnt[s + 3];
    int sum = v0 + v1 + v2 + v3;
    t[threadIdx.x] = sum;
    __syncthreads();
    for (int off = 1; off < 256; off <<= 1) {
        int v = (threadIdx.x >= off) ? t[threadIdx.x - off] : 0;
        __syncthreads();
        t[threadIdx.x] += v;
        __syncthreads();
    }
    int run = boff[blockIdx.x] + ((threadIdx.x == 0) ? 0 : t[threadIdx.x - 1]);
    if (s + 0 < n) { rowptr[s + 0] = run; run += v0; }
    if (s + 1 < n) { rowptr[s + 1] = run; run += v1; }
    if (s + 2 < n) { rowptr[s + 2] = run; run += v2; }
    if (s + 3 < n) { rowptr[s + 3] = run; run += v3; }
    if (blockIdx.x == 0 && threadIdx.x == 0) rowptr[n] = nE;
}

// ---------------- fill CSR (by dst) with packed {src, weight} records ----------------
__global__ void fill_csr_kernel(const int* __restrict__ src, const int* __restrict__ dst,
                                const int* __restrict__ rowptr, int* __restrict__ cursor,
                                const float* __restrict__ dinv,
                                long long* __restrict__ csr_rec, int nE) {
    int e = blockIdx.x * blockDim.x + threadIdx.x;
    if (e < nE) {
        int d = dst[e], s = src[e];
        int pos = atomicAdd(&cursor[d], 1);
        float w = dinv[s] * dinv[d];
        long long rec = ((long long)__float_as_int(w) << 32) | (unsigned)s;
        csr_rec[rowptr[d] + pos] = rec;
    }
}

// ---------------- GEMM: Hbf = f(X) @ W  (bf16 output), f = optional (+bias, relu) ----------------
__global__ __launch_bounds__(256) void gemm_kernel(const float* __restrict__ X,
                                                   const float* __restrict__ W,
                                                   unsigned short* __restrict__ Hbf, int n,
                                                   const float* __restrict__ bias_in,
                                                   int relu_in) {
    __shared__ float xs[64][HIDF];
    int row0 = blockIdx.x * 64;
    for (int idx = threadIdx.x; idx < 64 * HIDF; idx += 256) {
        int r = idx >> 7, c = idx & 127;
        int gr = row0 + r;
        float v = 0.f;
        if (gr < n) v = X[gr * HIDF + c];
        if (bias_in) { v += bias_in[c]; if (relu_in) v = fmaxf(v, 0.f); }
        xs[r][c] = v;
    }
    __syncthreads();
    int tx = threadIdx.x & 31;
    int ty = threadIdx.x >> 5;
    float acc[8][4];
    #pragma unroll
    for (int i = 0; i < 8; i++)
        #pragma unroll
        for (int j = 0; j < 4; j++) acc[i][j] = 0.f;
    #pragma unroll 4
    for (int k = 0; k < HIDF; ++k) {
        float4 w = *reinterpret_cast<const float4*>(&W[k * HIDF + tx * 4]);
        #pragma unroll
        for (int i = 0; i < 8; i++) {
            float xv = xs[i * 8 + ty][k];
            acc[i][0] += xv * w.x; acc[i][1] += xv * w.y;
            acc[i][2] += xv * w.z; acc[i][3] += xv * w.w;
        }
    }
    #pragma unroll
    for (int i = 0; i < 8; i++) {
        int gr = row0 + i * 8 + ty;
        if (gr < n) {
            ushort4 o;
            o.x = f2b(acc[i][0]); o.y = f2b(acc[i][1]);
            o.z = f2b(acc[i][2]); o.w = f2b(acc[i][3]);
            *reinterpret_cast<ushort4*>(&Hbf[(size_t)gr * HIDF + tx * 4]) = o;
        }
    }
}

// ---------------- gather aggregation: batched record load + broadcast ----------------
// Hout[d] = selfw[d]*Hin[d] + sum_{(s,w) in rec(d)} w*Hin[s]   (Hin bf16, acc f32)
__global__ __launch_bounds__(256) void gather_agg_kernel(const unsigned short* __restrict__ Hin,
                                                         const int* __restrict__ rowptr,
                                                         const long long* __restrict__ csr_rec,
                                                         const float* __restrict__ selfw,
                                                         float* __restrict__ Hout, int n) {
    int node = blockIdx.x * 8 + (threadIdx.x >> 5);
    if (node >= n) return;
    int lane = threadIdx.x & 31;
    ushort4 sv = *reinterpret_cast<const ushort4*>(&Hin[(size_t)node * HIDF + lane * 4]);
    float sw = selfw[node];
    float4 acc;
    acc.x = b2f(sv.x) * sw; acc.y = b2f(sv.y) * sw;
    acc.z = b2f(sv.z) * sw; acc.w = b2f(sv.w) * sw;
    int beg = rowptr[node], end = rowptr[node + 1];
    for (int base = beg; base < end; base += 32) {
        int m = end - base; if (m > 32) m = 32;
        long long rec = 0;
        if (base + lane < end) rec = csr_rec[base + lane];   // one coalesced 8B/lane load
        #pragma unroll 4
        for (int j = 0; j < m; ++j) {
            long long r = __shfl(rec, j, 32);                // register broadcast, no cache hop
            int sn = (int)(unsigned)(r & 0xffffffffLL);
            float w = __int_as_float((int)(r >> 32));
            ushort4 v = *reinterpret_cast<const ushort4*>(&Hin[(size_t)sn * HIDF + lane * 4]);
            acc.x += b2f(v.x) * w; acc.y += b2f(v.y) * w;
            acc.z += b2f(v.z) * w; acc.w += b2f(v.w) * w;
        }
    }
    *reinterpret_cast<float4*>(&Hout[(size_t)node * HIDF + lane * 4]) = acc;
}

// ---------------- mean pool via sorted-batch segment reduce (no atomics) ----------------
__device__ __forceinline__ int lower_bound_i(const int* __restrict__ a, int n, int key) {
    int lo = 0, hi = n;
    while (lo < hi) { int mid = (lo + hi) >> 1; if (a[mid] < key) lo = mid + 1; else hi = mid; }
    return lo;
}

__global__ __launch_bounds__(128) void pool_kernel(const float* __restrict__ H,
                                                   const int* __restrict__ batch,
                                                   const float* __restrict__ b3,
                                                   float* __restrict__ gmean, int n) {
    int b = blockIdx.x;
    int f = threadIdx.x;
    int s = lower_bound_i(batch, n, b);
    int e = lower_bound_i(batch, n, b + 1);
    float sum = 0.f;
    for (int i = s; i < e; ++i) sum += H[(size_t)i * HIDF + f];
    float cnt = fmaxf((float)(e - s), 1.0f);
    gmean[b * HIDF + f] = sum / cnt + b3[f];
}

// ---------------- centroid head: one wave per graph ----------------
__global__ __launch_bounds__(64) void final_kernel(const float* __restrict__ gmean,
                                                   const float* __restrict__ centroids,
                                                   const float* __restrict__ std_scale,
                                                   const float* __restrict__ ac_temp,
                                                   float* __restrict__ out) {
    int b = blockIdx.x;
    int lane = threadIdx.x;
    float g0 = gmean[b * HIDF + lane];
    float g1 = gmean[b * HIDF + 64 + lane];
    float mind = 1e30f;
    for (int c = 0; c < NCLS; ++c) {
        float dd[2];
        #pragma unroll
        for (int cent = 0; cent < 2; ++cent) {
            const float* cp = &centroids[(c * 2 + cent) * HIDF];
            float df0 = cp[lane] - g0;
            float df1 = cp[64 + lane] - g1;
            float p = df0 * df0 + df1 * df1;
            #pragma unroll
            for (int off = 32; off > 0; off >>= 1) p += __shfl_xor(p, off);
            dd[cent] = p;
        }
        float dist = fminf(sqrtf(dd[0]), sqrtf(dd[1]));
        mind = fminf(mind, dist);
        if (lane == 0) out[b * NCLS + c] = -dist;
    }
    if (lane == 0) {
        float ss = std_scale[0];
        float clipped = fminf(fmaxf(ss, 0.0f), 5.0f);
        float max_ac = 1.0f + clipped * 0.0f;      // RUNNING_MEAN=1, sqrt(RUNNING_VAR)=0
        float accept = max_ac - mind;
        float soft = 1.0f / (1.0f + expf(-accept / ac_temp[0]));
        out[NGR * NCLS + b] = soft;
    }
}

// ---------------- launch ----------------
extern "C" void kernel_launch(void* const* d_in, const int* in_sizes, int n_in,
                              void* d_out, int out_size, void* d_ws, size_t ws_size,
                              hipStream_t stream) {
    const float* x         = (const float*)d_in[0];
    const int*   edge      = (const int*)d_in[1];
    const int*   batch     = (const int*)d_in[2];
    const float* W1        = (const float*)d_in[3];
    const float* b1        = (const float*)d_in[4];
    const float* W2        = (const float*)d_in[5];
    const float* b2        = (const float*)d_in[6];
    const float* W3        = (const float*)d_in[7];
    const float* b3        = (const float*)d_in[8];
    const float* centroids = (const float*)d_in[9];
    const float* std_scale = (const float*)d_in[10];
    const float* ac_temp   = (const float*)d_in[11];
    float* out = (float*)d_out;

    const int n  = NN;
    const int nE = in_sizes[1] / 2;
    const int* srcp = edge;
    const int* dstp = edge + nE;

    // workspace layout (256B aligned)
    char* ws = (char*)d_ws;
    size_t off = 0;
    auto alloc = [&](size_t bytes) { void* p = ws + off; off = (off + bytes + 255) & ~(size_t)255; return p; };
    unsigned short* hA = (unsigned short*)alloc((size_t)NN * HIDF * 2);  // bf16 GEMM output
    float* hB      = (float*)alloc((size_t)NN * HIDF * 4);               // f32 gather output
    float* dinv    = (float*)alloc((size_t)NN * 4);
    float* selfw   = (float*)alloc((size_t)NN * 4);
    int*   cnt     = (int*)  alloc((size_t)NN * 4);       // reused as cursor
    int*   rowptr  = (int*)  alloc((size_t)(NN + 1) * 4);
    long long* csr_rec = (long long*)alloc((size_t)NEDGE * 8);
    float* gmean   = (float*)alloc((size_t)NGR * HIDF * 4);
    int*   bsum    = (int*)  alloc((size_t)SB * 4);
    int*   boff    = (int*)  alloc((size_t)SB * 4);

    // ---- CSR build (once, reused by all 3 layers) ----
    hipMemsetAsync(cnt, 0, (size_t)NN * 4, stream);
    count_deg_kernel<<<(nE + 255) / 256, 256, 0, stream>>>(dstp, cnt, nE);
    block_sum_kernel<<<SB, 256, 0, stream>>>(cnt, bsum, n);
    scan_bsum_kernel<<<1, 128, 0, stream>>>(bsum, boff, SB);
    scan_fill_kernel<<<SB, 256, 0, stream>>>(cnt, boff, rowptr, n, nE);
    node_prep_kernel<<<(n + 255) / 256, 256, 0, stream>>>(cnt, dinv, selfw, n);
    hipMemsetAsync(cnt, 0, (size_t)NN * 4, stream);        // cnt becomes cursor
    fill_csr_kernel<<<(nE + 255) / 256, 256, 0, stream>>>(srcp, dstp, rowptr, cnt, dinv, csr_rec, nE);

    int gemm_blocks   = (n + 63) / 64;
    int gather_blocks = (n + 7) / 8;

    // layer 1
    gemm_kernel<<<gemm_blocks, 256, 0, stream>>>(x, W1, hA, n, nullptr, 0);
    gather_agg_kernel<<<gather_blocks, 256, 0, stream>>>(hA, rowptr, csr_rec, selfw, hB, n);
    // layer 2 (+b1, relu fused into GEMM input staging)
    gemm_kernel<<<gemm_blocks, 256, 0, stream>>>(hB, W2, hA, n, b1, 1);
    gather_agg_kernel<<<gather_blocks, 256, 0, stream>>>(hA, rowptr, csr_rec, selfw, hB, n);
    // layer 3 (+b2, relu)
    gemm_kernel<<<gemm_blocks, 256, 0, stream>>>(hB, W3, hA, n, b2, 1);
    gather_agg_kernel<<<gather_blocks, 256, 0, stream>>>(hA, rowptr, csr_rec, selfw, hB, n);

    // mean pool (+b3 folded) — batch is sorted, no atomics
    pool_kernel<<<NGR, 128, 0, stream>>>(hB, batch, b3, gmean, n);
    final_kernel<<<NGR, 64, 0, stream>>>(gmean, centroids, std_scale, ac_temp, out);
}

// Round 6
// 517.976 us; speedup vs baseline: 16.6413x; 1.2420x over previous
//
#include <hip/hip_runtime.h>
#include <hip/hip_bf16.h>
#include <math.h>

#define NN 100000
#define NEDGE 1600000
#define HIDF 128
#define NCLS 18
#define NGR 512
#define SC 1024                       // elements per scan chunk
#define SB ((NN + SC - 1) / SC)       // 98 scan blocks

using bf16x8 = __attribute__((ext_vector_type(8))) short;   // 8 bf16 in 4 VGPRs
using f32x4  = __attribute__((ext_vector_type(4))) float;

__device__ __forceinline__ float b2f(unsigned short u) {
    return __uint_as_float(((unsigned)u) << 16);
}
__device__ __forceinline__ unsigned short f2b(float f) {   // round-to-nearest-even
    unsigned u = __float_as_uint(f);
    unsigned r = (u + 0x7fffu + ((u >> 16) & 1u)) >> 16;
    return (unsigned short)r;
}

// ---------------- degree count ----------------
__global__ void count_deg_kernel(const int* __restrict__ dst, int* __restrict__ cnt, int nE) {
    int e = blockIdx.x * blockDim.x + threadIdx.x;
    if (e < nE) atomicAdd(&cnt[dst[e]], 1);
}

__global__ void node_prep_kernel(const int* __restrict__ cnt, float* __restrict__ dinv,
                                 float* __restrict__ selfw, int n) {
    int i = blockIdx.x * blockDim.x + threadIdx.x;
    if (i < n) {
        float deg = (float)cnt[i] + 1.0f;   // +1 self loop
        dinv[i]  = rsqrtf(deg);
        selfw[i] = 1.0f / deg;
    }
}

// ---------------- device-wide exclusive scan: 3 phases ----------------
__global__ __launch_bounds__(256) void block_sum_kernel(const int* __restrict__ cnt,
                                                        int* __restrict__ bsum, int n) {
    int base = blockIdx.x * SC;
    int sum = 0;
    for (int i = threadIdx.x; i < SC; i += 256) {
        int idx = base + i;
        if (idx < n) sum += cnt[idx];
    }
    #pragma unroll
    for (int off = 32; off > 0; off >>= 1) sum += __shfl_down(sum, off);
    __shared__ int wsum[4];
    if ((threadIdx.x & 63) == 0) wsum[threadIdx.x >> 6] = sum;
    __syncthreads();
    if (threadIdx.x == 0) bsum[blockIdx.x] = wsum[0] + wsum[1] + wsum[2] + wsum[3];
}

__global__ __launch_bounds__(128) void scan_bsum_kernel(const int* __restrict__ bsum,
                                                        int* __restrict__ boff, int nb) {
    __shared__ int t[128];
    int tid = threadIdx.x;
    t[tid] = (tid < nb) ? bsum[tid] : 0;
    __syncthreads();
    for (int off = 1; off < 128; off <<= 1) {
        int v = (tid >= off) ? t[tid - off] : 0;
        __syncthreads();
        t[tid] += v;
        __syncthreads();
    }
    if (tid < nb) boff[tid] = (tid == 0) ? 0 : t[tid - 1];
}

__global__ __launch_bounds__(256) void scan_fill_kernel(const int* __restrict__ cnt,
                                                        const int* __restrict__ boff,
                                                        int* __restrict__ rowptr, int n, int nE) {
    __shared__ int t[256];
    int base = blockIdx.x * SC;
    int s = base + threadIdx.x * 4;
    int v0 = 0, v1 = 0, v2 = 0, v3 = 0;
    if (s + 0 < n) v0 = cnt[s + 0];
    if (s + 1 < n) v1 = cnt[s + 1];
    if (s + 2 < n) v2 = cnt[s + 2];
    if (s + 3 < n) v3 = cnt[s + 3];
    int sum = v0 + v1 + v2 + v3;
    t[threadIdx.x] = sum;
    __syncthreads();
    for (int off = 1; off < 256; off <<= 1) {
        int v = (threadIdx.x >= off) ? t[threadIdx.x - off] : 0;
        __syncthreads();
        t[threadIdx.x] += v;
        __syncthreads();
    }
    int run = boff[blockIdx.x] + ((threadIdx.x == 0) ? 0 : t[threadIdx.x - 1]);
    if (s + 0 < n) { rowptr[s + 0] = run; run += v0; }
    if (s + 1 < n) { rowptr[s + 1] = run; run += v1; }
    if (s + 2 < n) { rowptr[s + 2] = run; run += v2; }
    if (s + 3 < n) { rowptr[s + 3] = run; run += v3; }
    if (blockIdx.x == 0 && threadIdx.x == 0) rowptr[n] = nE;
}

// ---------------- fill CSR (by dst) with packed {src, weight} records, 2 edges/thread ----------------
__global__ void fill_csr_kernel(const int* __restrict__ src, const int* __restrict__ dst,
                                const int* __restrict__ rowptr, int* __restrict__ cursor,
                                const float* __restrict__ dinv,
                                long long* __restrict__ csr_rec, int nE) {
    int e0 = (blockIdx.x * blockDim.x + threadIdx.x) * 2;
    int e1 = e0 + 1;
    bool ok0 = e0 < nE, ok1 = e1 < nE;
    int d0 = 0, s0 = 0, d1 = 0, s1 = 0;
    if (ok0) { d0 = dst[e0]; s0 = src[e0]; }
    if (ok1) { d1 = dst[e1]; s1 = src[e1]; }
    float w0 = 0.f, w1 = 0.f;
    if (ok0) w0 = dinv[s0] * dinv[d0];
    if (ok1) w1 = dinv[s1] * dinv[d1];
    int p0 = 0, p1 = 0;
    if (ok0) p0 = atomicAdd(&cursor[d0], 1);
    if (ok1) p1 = atomicAdd(&cursor[d1], 1);
    if (ok0) csr_rec[rowptr[d0] + p0] = ((long long)__float_as_int(w0) << 32) | (unsigned)s0;
    if (ok1) csr_rec[rowptr[d1] + p1] = ((long long)__float_as_int(w1) << 32) | (unsigned)s1;
}

// ---------------- weight prep: pack W (f32 row-major 128x128) into B-fragment-linear bf16 ----------------
// Wf[w][((kt*8+ct)*64 + lane)*8 + j] = bf16( W[kt*32 + (lane>>4)*8 + j][ct*16 + (lane&15)] )
__global__ __launch_bounds__(256) void wprep_kernel(const float* __restrict__ W1,
                                                    const float* __restrict__ W2,
                                                    const float* __restrict__ W3,
                                                    unsigned short* __restrict__ Wf) {
    int gid = blockIdx.x * 256 + threadIdx.x;   // 0..49151
    int w = gid >> 14;
    int o = gid & 16383;
    int j = o & 7, lane = (o >> 3) & 63, ct = (o >> 9) & 7, kt = o >> 12;
    int rk = kt * 32 + (lane >> 4) * 8 + j;
    int col = ct * 16 + (lane & 15);
    const float* W = (w == 0) ? W1 : ((w == 1) ? W2 : W3);
    Wf[gid] = f2b(W[rk * HIDF + col]);
}

// ---------------- MFMA GEMM: Hbf = f(X) @ W  (bf16 table out) ----------------
// f = (+bias, relu) applied on input when bias != nullptr. 4 waves, 64 rows/block.
template <typename T>
__global__ __launch_bounds__(256) void mfma_gemm_kernel(const T* __restrict__ X,
                                                        const unsigned short* __restrict__ Wfrag,
                                                        const float* __restrict__ bias,
                                                        unsigned short* __restrict__ Hbf, int n) {
    __shared__ unsigned short wl[16384];   // 32 KB: full 128x128 bf16 W in fragment-linear layout
    {
        const uint4* wsrc = reinterpret_cast<const uint4*>(Wfrag);
        uint4* wdst = reinterpret_cast<uint4*>(wl);
        for (int i = threadIdx.x; i < 2048; i += 256) wdst[i] = wsrc[i];
    }
    __syncthreads();

    int wv = threadIdx.x >> 6;          // wave 0..3
    int l  = threadIdx.x & 63;          // lane
    int row = blockIdx.x * 64 + wv * 16 + (l & 15);
    int koff = (l >> 4) * 8;
    bool rowok = row < n;

    f32x4 acc[8] = {};
    #pragma unroll
    for (int kt = 0; kt < 4; ++kt) {
        int kbase = kt * 32 + koff;
        bf16x8 a;
        if constexpr (sizeof(T) == 4) {          // f32 input (layer 1, no bias)
            float4 x0 = {0,0,0,0}, x1 = {0,0,0,0};
            if (rowok) {
                x0 = *reinterpret_cast<const float4*>(&X[(size_t)row * HIDF + kbase]);
                x1 = *reinterpret_cast<const float4*>(&X[(size_t)row * HIDF + kbase + 4]);
            }
            a[0] = (short)f2b(x0.x); a[1] = (short)f2b(x0.y);
            a[2] = (short)f2b(x0.z); a[3] = (short)f2b(x0.w);
            a[4] = (short)f2b(x1.x); a[5] = (short)f2b(x1.y);
            a[6] = (short)f2b(x1.z); a[7] = (short)f2b(x1.w);
        } else {                                  // bf16 input (layers 2,3; +bias,relu)
            uint4 raw = {0,0,0,0};
            if (rowok) raw = *reinterpret_cast<const uint4*>(&X[(size_t)row * HIDF + kbase]);
            unsigned short* ru = reinterpret_cast<unsigned short*>(&raw);
            if (bias) {
                #pragma unroll
                for (int j = 0; j < 8; ++j) {
                    float v = b2f(ru[j]) + bias[kbase + j];
                    ru[j] = f2b(fmaxf(v, 0.f));
                }
            }
            a = *reinterpret_cast<bf16x8*>(&raw);
        }
        #pragma unroll
        for (int ct = 0; ct < 8; ++ct) {
            bf16x8 b = *reinterpret_cast<bf16x8*>(&wl[((kt * 8 + ct) * 64 + l) * 8]);
            acc[ct] = __builtin_amdgcn_mfma_f32_16x16x32_bf16(a, b, acc[ct], 0, 0, 0);
        }
    }
    // C/D: lane l reg r -> row (l>>4)*4+r, col ct*16 + (l&15)
    int rbase = blockIdx.x * 64 + wv * 16 + ((l >> 4) << 2);
    int cbase = l & 15;
    #pragma unroll
    for (int ct = 0; ct < 8; ++ct) {
        #pragma unroll
        for (int r = 0; r < 4; ++r) {
            int gr = rbase + r;
            if (gr < n) Hbf[(size_t)gr * HIDF + ct * 16 + cbase] = f2b(acc[ct][r]);
        }
    }
}

// ---------------- gather aggregation: batched record load + broadcast (bf16 in, bf16 out) ----------------
__global__ __launch_bounds__(256) void gather_agg_kernel(const unsigned short* __restrict__ Hin,
                                                         const int* __restrict__ rowptr,
                                                         const long long* __restrict__ csr_rec,
                                                         const float* __restrict__ selfw,
                                                         unsigned short* __restrict__ Hout, int n) {
    int node = blockIdx.x * 8 + (threadIdx.x >> 5);
    if (node >= n) return;
    int lane = threadIdx.x & 31;
    ushort4 sv = *reinterpret_cast<const ushort4*>(&Hin[(size_t)node * HIDF + lane * 4]);
    float sw = selfw[node];
    float4 acc;
    acc.x = b2f(sv.x) * sw; acc.y = b2f(sv.y) * sw;
    acc.z = b2f(sv.z) * sw; acc.w = b2f(sv.w) * sw;
    int beg = rowptr[node], end = rowptr[node + 1];
    for (int base = beg; base < end; base += 32) {
        int m = end - base; if (m > 32) m = 32;
        long long rec = 0;
        if (base + lane < end) rec = csr_rec[base + lane];   // one coalesced 8B/lane load
        #pragma unroll 4
        for (int j = 0; j < m; ++j) {
            long long r = __shfl(rec, j, 32);                // register broadcast, no cache hop
            int sn = (int)(unsigned)(r & 0xffffffffLL);
            float w = __int_as_float((int)(r >> 32));
            ushort4 v = *reinterpret_cast<const ushort4*>(&Hin[(size_t)sn * HIDF + lane * 4]);
            acc.x += b2f(v.x) * w; acc.y += b2f(v.y) * w;
            acc.z += b2f(v.z) * w; acc.w += b2f(v.w) * w;
        }
    }
    ushort4 o;
    o.x = f2b(acc.x); o.y = f2b(acc.y); o.z = f2b(acc.z); o.w = f2b(acc.w);
    *reinterpret_cast<ushort4*>(&Hout[(size_t)node * HIDF + lane * 4]) = o;
}

// ---------------- mean pool via sorted-batch segment reduce (bf16 in) ----------------
__device__ __forceinline__ int lower_bound_i(const int* __restrict__ a, int n, int key) {
    int lo = 0, hi = n;
    while (lo < hi) { int mid = (lo + hi) >> 1; if (a[mid] < key) lo = mid + 1; else hi = mid; }
    return lo;
}

__global__ __launch_bounds__(128) void pool_kernel(const unsigned short* __restrict__ H,
                                                   const int* __restrict__ batch,
                                                   const float* __restrict__ b3,
                                                   float* __restrict__ gmean, int n) {
    int b = blockIdx.x;
    int f = threadIdx.x;
    int s = lower_bound_i(batch, n, b);
    int e = lower_bound_i(batch, n, b + 1);
    float sum = 0.f;
    for (int i = s; i < e; ++i) sum += b2f(H[(size_t)i * HIDF + f]);
    float cnt = fmaxf((float)(e - s), 1.0f);
    gmean[b * HIDF + f] = sum / cnt + b3[f];
}

// ---------------- centroid head: one wave per graph ----------------
__global__ __launch_bounds__(64) void final_kernel(const float* __restrict__ gmean,
                                                   const float* __restrict__ centroids,
                                                   const float* __restrict__ std_scale,
                                                   const float* __restrict__ ac_temp,
                                                   float* __restrict__ out) {
    int b = blockIdx.x;
    int lane = threadIdx.x;
    float g0 = gmean[b * HIDF + lane];
    float g1 = gmean[b * HIDF + 64 + lane];
    float mind = 1e30f;
    for (int c = 0; c < NCLS; ++c) {
        float dd[2];
        #pragma unroll
        for (int cent = 0; cent < 2; ++cent) {
            const float* cp = &centroids[(c * 2 + cent) * HIDF];
            float df0 = cp[lane] - g0;
            float df1 = cp[64 + lane] - g1;
            float p = df0 * df0 + df1 * df1;
            #pragma unroll
            for (int off = 32; off > 0; off >>= 1) p += __shfl_xor(p, off);
            dd[cent] = p;
        }
        float dist = fminf(sqrtf(dd[0]), sqrtf(dd[1]));
        mind = fminf(mind, dist);
        if (lane == 0) out[b * NCLS + c] = -dist;
    }
    if (lane == 0) {
        float ss = std_scale[0];
        float clipped = fminf(fmaxf(ss, 0.0f), 5.0f);
        float max_ac = 1.0f + clipped * 0.0f;      // RUNNING_MEAN=1, sqrt(RUNNING_VAR)=0
        float accept = max_ac - mind;
        float soft = 1.0f / (1.0f + expf(-accept / ac_temp[0]));
        out[NGR * NCLS + b] = soft;
    }
}

// ---------------- launch ----------------
extern "C" void kernel_launch(void* const* d_in, const int* in_sizes, int n_in,
                              void* d_out, int out_size, void* d_ws, size_t ws_size,
                              hipStream_t stream) {
    const float* x         = (const float*)d_in[0];
    const int*   edge      = (const int*)d_in[1];
    const int*   batch     = (const int*)d_in[2];
    const float* W1        = (const float*)d_in[3];
    const float* b1        = (const float*)d_in[4];
    const float* W2        = (const float*)d_in[5];
    const float* b2        = (const float*)d_in[6];
    const float* W3        = (const float*)d_in[7];
    const float* b3        = (const float*)d_in[8];
    const float* centroids = (const float*)d_in[9];
    const float* std_scale = (const float*)d_in[10];
    const float* ac_temp   = (const float*)d_in[11];
    float* out = (float*)d_out;

    const int n  = NN;
    const int nE = in_sizes[1] / 2;
    const int* srcp = edge;
    const int* dstp = edge + nE;

    // workspace layout (256B aligned)
    char* ws = (char*)d_ws;
    size_t off = 0;
    auto alloc = [&](size_t bytes) { void* p = ws + off; off = (off + bytes + 255) & ~(size_t)255; return p; };
    unsigned short* hA = (unsigned short*)alloc((size_t)NN * HIDF * 2);  // bf16 GEMM output table
    unsigned short* hG = (unsigned short*)alloc((size_t)NN * HIDF * 2);  // bf16 gather output table
    unsigned short* Wf = (unsigned short*)alloc((size_t)3 * HIDF * HIDF * 2);
    float* dinv    = (float*)alloc((size_t)NN * 4);
    float* selfw   = (float*)alloc((size_t)NN * 4);
    int*   cnt     = (int*)  alloc((size_t)NN * 4);       // reused as cursor
    int*   rowptr  = (int*)  alloc((size_t)(NN + 1) * 4);
    long long* csr_rec = (long long*)alloc((size_t)NEDGE * 8);
    float* gmean   = (float*)alloc((size_t)NGR * HIDF * 4);
    int*   bsum    = (int*)  alloc((size_t)SB * 4);
    int*   boff    = (int*)  alloc((size_t)SB * 4);

    // ---- weight prep + CSR build (CSR reused by all 3 layers) ----
    wprep_kernel<<<192, 256, 0, stream>>>(W1, W2, W3, Wf);
    hipMemsetAsync(cnt, 0, (size_t)NN * 4, stream);
    count_deg_kernel<<<(nE + 255) / 256, 256, 0, stream>>>(dstp, cnt, nE);
    block_sum_kernel<<<SB, 256, 0, stream>>>(cnt, bsum, n);
    scan_bsum_kernel<<<1, 128, 0, stream>>>(bsum, boff, SB);
    scan_fill_kernel<<<SB, 256, 0, stream>>>(cnt, boff, rowptr, n, nE);
    node_prep_kernel<<<(n + 255) / 256, 256, 0, stream>>>(cnt, dinv, selfw, n);
    hipMemsetAsync(cnt, 0, (size_t)NN * 4, stream);        // cnt becomes cursor
    fill_csr_kernel<<<(nE / 2 + 255) / 256, 256, 0, stream>>>(srcp, dstp, rowptr, cnt, dinv, csr_rec, nE);

    int gemm_blocks   = (n + 63) / 64;
    int gather_blocks = (n + 7) / 8;

    // layer 1: x f32 -> hA; gather -> hG
    mfma_gemm_kernel<float><<<gemm_blocks, 256, 0, stream>>>(x, Wf, nullptr, hA, n);
    gather_agg_kernel<<<gather_blocks, 256, 0, stream>>>(hA, rowptr, csr_rec, selfw, hG, n);
    // layer 2: (+b1, relu) fused into A-load
    mfma_gemm_kernel<unsigned short><<<gemm_blocks, 256, 0, stream>>>(hG, Wf + 16384, b1, hA, n);
    gather_agg_kernel<<<gather_blocks, 256, 0, stream>>>(hA, rowptr, csr_rec, selfw, hG, n);
    // layer 3: (+b2, relu)
    mfma_gemm_kernel<unsigned short><<<gemm_blocks, 256, 0, stream>>>(hG, Wf + 32768, b2, hA, n);
    gather_agg_kernel<<<gather_blocks, 256, 0, stream>>>(hA, rowptr, csr_rec, selfw, hG, n);

    // mean pool (+b3 folded) — batch is sorted, no atomics
    pool_kernel<<<NGR, 128, 0, stream>>>(hG, batch, b3, gmean, n);
    final_kernel<<<NGR, 64, 0, stream>>>(gmean, centroids, std_scale, ac_temp, out);
}

// Round 7
// 477.759 us; speedup vs baseline: 18.0421x; 1.0842x over previous
//
#include <hip/hip_runtime.h>
#include <hip/hip_bf16.h>
#include <math.h>

#define NN 100000
#define NEDGE 1600000
#define HIDF 128
#define NCLS 18
#define NGR 512
#define SC 1024                       // elements per scan chunk
#define SB ((NN + SC - 1) / SC)       // 98 scan blocks
#define CHSZ 2048                     // edges per bin chunk
#define NBKT 391                      // ceil(NN/256) buckets of 256 nodes

using bf16x8 = __attribute__((ext_vector_type(8))) short;   // 8 bf16 in 4 VGPRs
using f32x4  = __attribute__((ext_vector_type(4))) float;

__device__ __forceinline__ float b2f(unsigned short u) {
    return __uint_as_float(((unsigned)u) << 16);
}
__device__ __forceinline__ unsigned short f2b(float f) {   // round-to-nearest-even
    unsigned u = __float_as_uint(f);
    unsigned r = (u + 0x7fffu + ((u >> 16) & 1u)) >> 16;
    return (unsigned short)r;
}

// ---------------- degree count ----------------
__global__ void count_deg_kernel(const int* __restrict__ dst, int* __restrict__ cnt, int nE) {
    int e = blockIdx.x * blockDim.x + threadIdx.x;
    if (e < nE) atomicAdd(&cnt[dst[e]], 1);
}

__global__ void node_prep_kernel(const int* __restrict__ cnt, float* __restrict__ dinv,
                                 float* __restrict__ selfw, int n) {
    int i = blockIdx.x * blockDim.x + threadIdx.x;
    if (i < n) {
        float deg = (float)cnt[i] + 1.0f;   // +1 self loop
        dinv[i]  = rsqrtf(deg);
        selfw[i] = 1.0f / deg;
    }
}

// ---------------- device-wide exclusive scan: 3 phases ----------------
__global__ __launch_bounds__(256) void block_sum_kernel(const int* __restrict__ cnt,
                                                        int* __restrict__ bsum, int n) {
    int base = blockIdx.x * SC;
    int sum = 0;
    for (int i = threadIdx.x; i < SC; i += 256) {
        int idx = base + i;
        if (idx < n) sum += cnt[idx];
    }
    #pragma unroll
    for (int off = 32; off > 0; off >>= 1) sum += __shfl_down(sum, off);
    __shared__ int wsum[4];
    if ((threadIdx.x & 63) == 0) wsum[threadIdx.x >> 6] = sum;
    __syncthreads();
    if (threadIdx.x == 0) bsum[blockIdx.x] = wsum[0] + wsum[1] + wsum[2] + wsum[3];
}

__global__ __launch_bounds__(128) void scan_bsum_kernel(const int* __restrict__ bsum,
                                                        int* __restrict__ boff, int nb) {
    __shared__ int t[128];
    int tid = threadIdx.x;
    t[tid] = (tid < nb) ? bsum[tid] : 0;
    __syncthreads();
    for (int off = 1; off < 128; off <<= 1) {
        int v = (tid >= off) ? t[tid - off] : 0;
        __syncthreads();
        t[tid] += v;
        __syncthreads();
    }
    if (tid < nb) boff[tid] = (tid == 0) ? 0 : t[tid - 1];
}

__global__ __launch_bounds__(256) void scan_fill_kernel(const int* __restrict__ cnt,
                                                        const int* __restrict__ boff,
                                                        int* __restrict__ rowptr, int n, int nE) {
    __shared__ int t[256];
    int base = blockIdx.x * SC;
    int s = base + threadIdx.x * 4;
    int v0 = 0, v1 = 0, v2 = 0, v3 = 0;
    if (s + 0 < n) v0 = cnt[s + 0];
    if (s + 1 < n) v1 = cnt[s + 1];
    if (s + 2 < n) v2 = cnt[s + 2];
    if (s + 3 < n) v3 = cnt[s + 3];
    int sum = v0 + v1 + v2 + v3;
    t[threadIdx.x] = sum;
    __syncthreads();
    for (int off = 1; off < 256; off <<= 1) {
        int v = (threadIdx.x >= off) ? t[threadIdx.x - off] : 0;
        __syncthreads();
        t[threadIdx.x] += v;
        __syncthreads();
    }
    int run = boff[blockIdx.x] + ((threadIdx.x == 0) ? 0 : t[threadIdx.x - 1]);
    if (s + 0 < n) { rowptr[s + 0] = run; run += v0; }
    if (s + 1 < n) { rowptr[s + 1] = run; run += v1; }
    if (s + 2 < n) { rowptr[s + 2] = run; run += v2; }
    if (s + 3 < n) { rowptr[s + 3] = run; run += v3; }
    if (blockIdx.x == 0 && threadIdx.x == 0) rowptr[n] = nE;
}

// ---------------- phase 1: bin edges into 256-node buckets, chunk-local, coalesced out ----------------
// recs_out[chunk region]: {dst:hi32, src:lo32} grouped by bucket; cando[c][b] = {count, offset}
__global__ __launch_bounds__(256) void bin_kernel(const int* __restrict__ src,
                                                  const int* __restrict__ dst,
                                                  long long* __restrict__ recs_out,
                                                  int2* __restrict__ cando, int nE) {
    __shared__ int cnt[512];
    __shared__ int ssum[256];
    __shared__ long long recs[CHSZ];
    int c = blockIdx.x;
    int t = threadIdx.x;
    cnt[t] = 0; cnt[t + 256] = 0;
    __syncthreads();
    int e0 = c * CHSZ;
    int nv = nE - e0; if (nv > CHSZ) nv = CHSZ;
    int s8[8], d8[8];
    #pragma unroll
    for (int i = 0; i < 8; i++) {
        int li = t + i * 256;
        bool ok = li < nv;
        s8[i] = ok ? src[e0 + li] : -1;
        d8[i] = ok ? dst[e0 + li] : -1;
        if (ok) atomicAdd(&cnt[d8[i] >> 8], 1);
    }
    __syncthreads();
    int a = cnt[2 * t], b_ = cnt[2 * t + 1];
    ssum[t] = a + b_;
    __syncthreads();
    for (int off = 1; off < 256; off <<= 1) {       // Hillis-Steele inclusive over 256 pair-sums
        int v = (t >= off) ? ssum[t - off] : 0;
        __syncthreads();
        ssum[t] += v;
        __syncthreads();
    }
    int excl = ssum[t] - (a + b_);
    if (2 * t < NBKT)     cando[(size_t)c * NBKT + 2 * t]     = make_int2(a, excl);
    if (2 * t + 1 < NBKT) cando[(size_t)c * NBKT + 2 * t + 1] = make_int2(b_, excl + a);
    __syncthreads();
    cnt[2 * t] = excl; cnt[2 * t + 1] = excl + a;    // reuse as cursors
    __syncthreads();
    #pragma unroll
    for (int i = 0; i < 8; i++) {
        if (d8[i] >= 0) {
            int pos = atomicAdd(&cnt[d8[i] >> 8], 1);
            recs[pos] = ((long long)d8[i] << 32) | (unsigned)s8[i];
        }
    }
    __syncthreads();
    for (int j = t; j < nv; j += 256)
        recs_out[(size_t)e0 + j] = recs[j];          // fully coalesced 8B stores
}

// ---------------- phase 2: per-bucket fill of final CSR (L2-compact scatter region) ----------------
__global__ __launch_bounds__(512) void bucket_fill_kernel(const long long* __restrict__ recs_bin,
                                                          const int2* __restrict__ cando,
                                                          const int* __restrict__ rowptr,
                                                          const float* __restrict__ dinv,
                                                          long long* __restrict__ csr_rec,
                                                          int nch, int n) {
    __shared__ int cur[256];
    int b = blockIdx.x;
    int node0 = b << 8;
    int t = threadIdx.x;
    if (t < 256) {
        int nd = node0 + t;
        cur[t] = (nd < n) ? rowptr[nd] : 0;
    }
    __syncthreads();
    for (int c = t; c < nch; c += 512) {
        int2 co = cando[(size_t)c * NBKT + b];
        size_t base = (size_t)c * CHSZ + co.y;
        for (int k = 0; k < co.x; ++k) {
            long long rec = recs_bin[base + k];
            int d = (int)(rec >> 32);
            int s = (int)(unsigned)(rec & 0xffffffffLL);
            float w = dinv[s] * dinv[d];
            int pos = atomicAdd(&cur[d & 255], 1);
            csr_rec[pos] = ((long long)__float_as_int(w) << 32) | (unsigned)s;
        }
    }
}

// ---------------- weight prep: pack W (f32 row-major 128x128) into B-fragment-linear bf16 ----------------
__global__ __launch_bounds__(256) void wprep_kernel(const float* __restrict__ W1,
                                                    const float* __restrict__ W2,
                                                    const float* __restrict__ W3,
                                                    unsigned short* __restrict__ Wf) {
    int gid = blockIdx.x * 256 + threadIdx.x;   // 0..49151
    int w = gid >> 14;
    int o = gid & 16383;
    int j = o & 7, lane = (o >> 3) & 63, ct = (o >> 9) & 7, kt = o >> 12;
    int rk = kt * 32 + (lane >> 4) * 8 + j;
    int col = ct * 16 + (lane & 15);
    const float* W = (w == 0) ? W1 : ((w == 1) ? W2 : W3);
    Wf[gid] = f2b(W[rk * HIDF + col]);
}

// ---------------- MFMA GEMM: Hbf = f(X) @ W  (bf16 table out) ----------------
template <typename T>
__global__ __launch_bounds__(256) void mfma_gemm_kernel(const T* __restrict__ X,
                                                        const unsigned short* __restrict__ Wfrag,
                                                        const float* __restrict__ bias,
                                                        unsigned short* __restrict__ Hbf, int n) {
    __shared__ unsigned short wl[16384];   // 32 KB: full 128x128 bf16 W in fragment-linear layout
    {
        const uint4* wsrc = reinterpret_cast<const uint4*>(Wfrag);
        uint4* wdst = reinterpret_cast<uint4*>(wl);
        for (int i = threadIdx.x; i < 2048; i += 256) wdst[i] = wsrc[i];
    }
    __syncthreads();

    int wv = threadIdx.x >> 6;          // wave 0..3
    int l  = threadIdx.x & 63;          // lane
    int row = blockIdx.x * 64 + wv * 16 + (l & 15);
    int koff = (l >> 4) * 8;
    bool rowok = row < n;

    f32x4 acc[8] = {};
    #pragma unroll
    for (int kt = 0; kt < 4; ++kt) {
        int kbase = kt * 32 + koff;
        bf16x8 a;
        if constexpr (sizeof(T) == 4) {          // f32 input (layer 1, no bias)
            float4 x0 = {0,0,0,0}, x1 = {0,0,0,0};
            if (rowok) {
                x0 = *reinterpret_cast<const float4*>(&X[(size_t)row * HIDF + kbase]);
                x1 = *reinterpret_cast<const float4*>(&X[(size_t)row * HIDF + kbase + 4]);
            }
            a[0] = (short)f2b(x0.x); a[1] = (short)f2b(x0.y);
            a[2] = (short)f2b(x0.z); a[3] = (short)f2b(x0.w);
            a[4] = (short)f2b(x1.x); a[5] = (short)f2b(x1.y);
            a[6] = (short)f2b(x1.z); a[7] = (short)f2b(x1.w);
        } else {                                  // bf16 input (layers 2,3; +bias,relu)
            uint4 raw = {0,0,0,0};
            if (rowok) raw = *reinterpret_cast<const uint4*>(&X[(size_t)row * HIDF + kbase]);
            unsigned short* ru = reinterpret_cast<unsigned short*>(&raw);
            if (bias) {
                #pragma unroll
                for (int j = 0; j < 8; ++j) {
                    float v = b2f(ru[j]) + bias[kbase + j];
                    ru[j] = f2b(fmaxf(v, 0.f));
                }
            }
            a = *reinterpret_cast<bf16x8*>(&raw);
        }
        #pragma unroll
        for (int ct = 0; ct < 8; ++ct) {
            bf16x8 b = *reinterpret_cast<bf16x8*>(&wl[((kt * 8 + ct) * 64 + l) * 8]);
            acc[ct] = __builtin_amdgcn_mfma_f32_16x16x32_bf16(a, b, acc[ct], 0, 0, 0);
        }
    }
    int rbase = blockIdx.x * 64 + wv * 16 + ((l >> 4) << 2);
    int cbase = l & 15;
    #pragma unroll
    for (int ct = 0; ct < 8; ++ct) {
        #pragma unroll
        for (int r = 0; r < 4; ++r) {
            int gr = rbase + r;
            if (gr < n) Hbf[(size_t)gr * HIDF + ct * 16 + cbase] = f2b(acc[ct][r]);
        }
    }
}

// ---------------- gather aggregation: batched record load + broadcast (bf16 in, bf16 out) ----------------
__global__ __launch_bounds__(256) void gather_agg_kernel(const unsigned short* __restrict__ Hin,
                                                         const int* __restrict__ rowptr,
                                                         const long long* __restrict__ csr_rec,
                                                         const float* __restrict__ selfw,
                                                         unsigned short* __restrict__ Hout, int n) {
    int node = blockIdx.x * 8 + (threadIdx.x >> 5);
    if (node >= n) return;
    int lane = threadIdx.x & 31;
    ushort4 sv = *reinterpret_cast<const ushort4*>(&Hin[(size_t)node * HIDF + lane * 4]);
    float sw = selfw[node];
    float4 acc;
    acc.x = b2f(sv.x) * sw; acc.y = b2f(sv.y) * sw;
    acc.z = b2f(sv.z) * sw; acc.w = b2f(sv.w) * sw;
    int beg = rowptr[node], end = rowptr[node + 1];
    for (int base = beg; base < end; base += 32) {
        int m = end - base; if (m > 32) m = 32;
        long long rec = 0;
        if (base + lane < end) rec = csr_rec[base + lane];   // one coalesced 8B/lane load
        #pragma unroll 4
        for (int j = 0; j < m; ++j) {
            long long r = __shfl(rec, j, 32);                // register broadcast, no cache hop
            int sn = (int)(unsigned)(r & 0xffffffffLL);
            float w = __int_as_float((int)(r >> 32));
            ushort4 v = *reinterpret_cast<const ushort4*>(&Hin[(size_t)sn * HIDF + lane * 4]);
            acc.x += b2f(v.x) * w; acc.y += b2f(v.y) * w;
            acc.z += b2f(v.z) * w; acc.w += b2f(v.w) * w;
        }
    }
    ushort4 o;
    o.x = f2b(acc.x); o.y = f2b(acc.y); o.z = f2b(acc.z); o.w = f2b(acc.w);
    *reinterpret_cast<ushort4*>(&Hout[(size_t)node * HIDF + lane * 4]) = o;
}

// ---------------- mean pool via sorted-batch segment reduce (bf16 in) ----------------
__device__ __forceinline__ int lower_bound_i(const int* __restrict__ a, int n, int key) {
    int lo = 0, hi = n;
    while (lo < hi) { int mid = (lo + hi) >> 1; if (a[mid] < key) lo = mid + 1; else hi = mid; }
    return lo;
}

__global__ __launch_bounds__(128) void pool_kernel(const unsigned short* __restrict__ H,
                                                   const int* __restrict__ batch,
                                                   const float* __restrict__ b3,
                                                   float* __restrict__ gmean, int n) {
    int b = blockIdx.x;
    int f = threadIdx.x;
    int s = lower_bound_i(batch, n, b);
    int e = lower_bound_i(batch, n, b + 1);
    float sum = 0.f;
    for (int i = s; i < e; ++i) sum += b2f(H[(size_t)i * HIDF + f]);
    float cnt = fmaxf((float)(e - s), 1.0f);
    gmean[b * HIDF + f] = sum / cnt + b3[f];
}

// ---------------- centroid head: one wave per graph ----------------
__global__ __launch_bounds__(64) void final_kernel(const float* __restrict__ gmean,
                                                   const float* __restrict__ centroids,
                                                   const float* __restrict__ std_scale,
                                                   const float* __restrict__ ac_temp,
                                                   float* __restrict__ out) {
    int b = blockIdx.x;
    int lane = threadIdx.x;
    float g0 = gmean[b * HIDF + lane];
    float g1 = gmean[b * HIDF + 64 + lane];
    float mind = 1e30f;
    for (int c = 0; c < NCLS; ++c) {
        float dd[2];
        #pragma unroll
        for (int cent = 0; cent < 2; ++cent) {
            const float* cp = &centroids[(c * 2 + cent) * HIDF];
            float df0 = cp[lane] - g0;
            float df1 = cp[64 + lane] - g1;
            float p = df0 * df0 + df1 * df1;
            #pragma unroll
            for (int off = 32; off > 0; off >>= 1) p += __shfl_xor(p, off);
            dd[cent] = p;
        }
        float dist = fminf(sqrtf(dd[0]), sqrtf(dd[1]));
        mind = fminf(mind, dist);
        if (lane == 0) out[b * NCLS + c] = -dist;
    }
    if (lane == 0) {
        float ss = std_scale[0];
        float clipped = fminf(fmaxf(ss, 0.0f), 5.0f);
        float max_ac = 1.0f + clipped * 0.0f;      // RUNNING_MEAN=1, sqrt(RUNNING_VAR)=0
        float accept = max_ac - mind;
        float soft = 1.0f / (1.0f + expf(-accept / ac_temp[0]));
        out[NGR * NCLS + b] = soft;
    }
}

// ---------------- launch ----------------
extern "C" void kernel_launch(void* const* d_in, const int* in_sizes, int n_in,
                              void* d_out, int out_size, void* d_ws, size_t ws_size,
                              hipStream_t stream) {
    const float* x         = (const float*)d_in[0];
    const int*   edge      = (const int*)d_in[1];
    const int*   batch     = (const int*)d_in[2];
    const float* W1        = (const float*)d_in[3];
    const float* b1        = (const float*)d_in[4];
    const float* W2        = (const float*)d_in[5];
    const float* b2        = (const float*)d_in[6];
    const float* W3        = (const float*)d_in[7];
    const float* b3        = (const float*)d_in[8];
    const float* centroids = (const float*)d_in[9];
    const float* std_scale = (const float*)d_in[10];
    const float* ac_temp   = (const float*)d_in[11];
    float* out = (float*)d_out;

    const int n  = NN;
    const int nE = in_sizes[1] / 2;
    const int* srcp = edge;
    const int* dstp = edge + nE;
    const int nch = (nE + CHSZ - 1) / CHSZ;

    // workspace layout (256B aligned)
    char* ws = (char*)d_ws;
    size_t off = 0;
    auto alloc = [&](size_t bytes) { void* p = ws + off; off = (off + bytes + 255) & ~(size_t)255; return p; };
    unsigned short* hA = (unsigned short*)alloc((size_t)NN * HIDF * 2);  // bf16 GEMM output table
    unsigned short* hG = (unsigned short*)alloc((size_t)NN * HIDF * 2);  // bf16 gather output table
    unsigned short* Wf = (unsigned short*)alloc((size_t)3 * HIDF * HIDF * 2);
    float* dinv    = (float*)alloc((size_t)NN * 4);
    float* selfw   = (float*)alloc((size_t)NN * 4);
    int*   cnt     = (int*)  alloc((size_t)NN * 4);
    int*   rowptr  = (int*)  alloc((size_t)(NN + 1) * 4);
    long long* csr_rec  = (long long*)alloc((size_t)nE * 8);
    long long* recs_bin = (long long*)alloc((size_t)nE * 8);
    int2*  cando   = (int2*) alloc((size_t)nch * NBKT * 8);
    float* gmean   = (float*)alloc((size_t)NGR * HIDF * 4);
    int*   bsum    = (int*)  alloc((size_t)SB * 4);
    int*   boff    = (int*)  alloc((size_t)SB * 4);

    // ---- weight prep + CSR build (CSR reused by all 3 layers) ----
    wprep_kernel<<<192, 256, 0, stream>>>(W1, W2, W3, Wf);
    hipMemsetAsync(cnt, 0, (size_t)NN * 4, stream);
    bin_kernel<<<nch, 256, 0, stream>>>(srcp, dstp, recs_bin, cando, nE);
    count_deg_kernel<<<(nE + 255) / 256, 256, 0, stream>>>(dstp, cnt, nE);
    block_sum_kernel<<<SB, 256, 0, stream>>>(cnt, bsum, n);
    scan_bsum_kernel<<<1, 128, 0, stream>>>(bsum, boff, SB);
    scan_fill_kernel<<<SB, 256, 0, stream>>>(cnt, boff, rowptr, n, nE);
    node_prep_kernel<<<(n + 255) / 256, 256, 0, stream>>>(cnt, dinv, selfw, n);
    bucket_fill_kernel<<<NBKT, 512, 0, stream>>>(recs_bin, cando, rowptr, dinv, csr_rec, nch, n);

    int gemm_blocks   = (n + 63) / 64;
    int gather_blocks = (n + 7) / 8;

    // layer 1: x f32 -> hA; gather -> hG
    mfma_gemm_kernel<float><<<gemm_blocks, 256, 0, stream>>>(x, Wf, nullptr, hA, n);
    gather_agg_kernel<<<gather_blocks, 256, 0, stream>>>(hA, rowptr, csr_rec, selfw, hG, n);
    // layer 2: (+b1, relu) fused into A-load
    mfma_gemm_kernel<unsigned short><<<gemm_blocks, 256, 0, stream>>>(hG, Wf + 16384, b1, hA, n);
    gather_agg_kernel<<<gather_blocks, 256, 0, stream>>>(hA, rowptr, csr_rec, selfw, hG, n);
    // layer 3: (+b2, relu)
    mfma_gemm_kernel<unsigned short><<<gemm_blocks, 256, 0, stream>>>(hG, Wf + 32768, b2, hA, n);
    gather_agg_kernel<<<gather_blocks, 256, 0, stream>>>(hA, rowptr, csr_rec, selfw, hG, n);

    // mean pool (+b3 folded) — batch is sorted, no atomics
    pool_kernel<<<NGR, 128, 0, stream>>>(hG, batch, b3, gmean, n);
    final_kernel<<<NGR, 64, 0, stream>>>(gmean, centroids, std_scale, ac_temp, out);
}

// Round 8
// 420.144 us; speedup vs baseline: 20.5163x; 1.1371x over previous
//
#include <hip/hip_runtime.h>
#include <hip/hip_bf16.h>
#include <math.h>

#define NN 100000
#define NEDGE 1600000
#define HIDF 128
#define NCLS 18
#define NGR 512
#define SC 1024                       // elements per scan chunk
#define SB ((NN + SC - 1) / SC)       // 98 scan blocks
#define CHSZ 2048                     // edges per bin chunk
#define NBKT 391                      // ceil(NN/256) buckets of 256 nodes

using bf16x8 = __attribute__((ext_vector_type(8))) short;   // 8 bf16 in 4 VGPRs
using f32x4  = __attribute__((ext_vector_type(4))) float;

__device__ __forceinline__ float b2f(unsigned short u) {
    return __uint_as_float(((unsigned)u) << 16);
}
__device__ __forceinline__ unsigned short f2b(float f) {   // round-to-nearest-even
    unsigned u = __float_as_uint(f);
    unsigned r = (u + 0x7fffu + ((u >> 16) & 1u)) >> 16;
    return (unsigned short)r;
}

// ---------------- degree count ----------------
__global__ void count_deg_kernel(const int* __restrict__ dst, int* __restrict__ cnt, int nE) {
    int e = blockIdx.x * blockDim.x + threadIdx.x;
    if (e < nE) atomicAdd(&cnt[dst[e]], 1);
}

__global__ void node_prep_kernel(const int* __restrict__ cnt, float* __restrict__ dinv,
                                 float* __restrict__ selfw, int n) {
    int i = blockIdx.x * blockDim.x + threadIdx.x;
    if (i < n) {
        float deg = (float)cnt[i] + 1.0f;   // +1 self loop
        dinv[i]  = rsqrtf(deg);
        selfw[i] = 1.0f / deg;
    }
}

// ---------------- device-wide exclusive scan: 3 phases ----------------
__global__ __launch_bounds__(256) void block_sum_kernel(const int* __restrict__ cnt,
                                                        int* __restrict__ bsum, int n) {
    int base = blockIdx.x * SC;
    int sum = 0;
    for (int i = threadIdx.x; i < SC; i += 256) {
        int idx = base + i;
        if (idx < n) sum += cnt[idx];
    }
    #pragma unroll
    for (int off = 32; off > 0; off >>= 1) sum += __shfl_down(sum, off);
    __shared__ int wsum[4];
    if ((threadIdx.x & 63) == 0) wsum[threadIdx.x >> 6] = sum;
    __syncthreads();
    if (threadIdx.x == 0) bsum[blockIdx.x] = wsum[0] + wsum[1] + wsum[2] + wsum[3];
}

__global__ __launch_bounds__(128) void scan_bsum_kernel(const int* __restrict__ bsum,
                                                        int* __restrict__ boff, int nb) {
    __shared__ int t[128];
    int tid = threadIdx.x;
    t[tid] = (tid < nb) ? bsum[tid] : 0;
    __syncthreads();
    for (int off = 1; off < 128; off <<= 1) {
        int v = (tid >= off) ? t[tid - off] : 0;
        __syncthreads();
        t[tid] += v;
        __syncthreads();
    }
    if (tid < nb) boff[tid] = (tid == 0) ? 0 : t[tid - 1];
}

__global__ __launch_bounds__(256) void scan_fill_kernel(const int* __restrict__ cnt,
                                                        const int* __restrict__ boff,
                                                        int* __restrict__ rowptr, int n, int nE) {
    __shared__ int t[256];
    int base = blockIdx.x * SC;
    int s = base + threadIdx.x * 4;
    int v0 = 0, v1 = 0, v2 = 0, v3 = 0;
    if (s + 0 < n) v0 = cnt[s + 0];
    if (s + 1 < n) v1 = cnt[s + 1];
    if (s + 2 < n) v2 = cnt[s + 2];
    if (s + 3 < n) v3 = cnt[s + 3];
    int sum = v0 + v1 + v2 + v3;
    t[threadIdx.x] = sum;
    __syncthreads();
    for (int off = 1; off < 256; off <<= 1) {
        int v = (threadIdx.x >= off) ? t[threadIdx.x - off] : 0;
        __syncthreads();
        t[threadIdx.x] += v;
        __syncthreads();
    }
    int run = boff[blockIdx.x] + ((threadIdx.x == 0) ? 0 : t[threadIdx.x - 1]);
    if (s + 0 < n) { rowptr[s + 0] = run; run += v0; }
    if (s + 1 < n) { rowptr[s + 1] = run; run += v1; }
    if (s + 2 < n) { rowptr[s + 2] = run; run += v2; }
    if (s + 3 < n) { rowptr[s + 3] = run; run += v3; }
    if (blockIdx.x == 0 && threadIdx.x == 0) rowptr[n] = nE;
}

// ---------------- phase 1: bin edges into 256-node buckets, chunk-local, coalesced out ----------------
__global__ __launch_bounds__(256) void bin_kernel(const int* __restrict__ src,
                                                  const int* __restrict__ dst,
                                                  long long* __restrict__ recs_out,
                                                  int2* __restrict__ cando, int nE) {
    __shared__ int cnt[512];
    __shared__ int ssum[256];
    __shared__ long long recs[CHSZ];
    int c = blockIdx.x;
    int t = threadIdx.x;
    cnt[t] = 0; cnt[t + 256] = 0;
    __syncthreads();
    int e0 = c * CHSZ;
    int nv = nE - e0; if (nv > CHSZ) nv = CHSZ;
    int s8[8], d8[8];
    #pragma unroll
    for (int i = 0; i < 8; i++) {
        int li = t + i * 256;
        bool ok = li < nv;
        s8[i] = ok ? src[e0 + li] : -1;
        d8[i] = ok ? dst[e0 + li] : -1;
        if (ok) atomicAdd(&cnt[d8[i] >> 8], 1);
    }
    __syncthreads();
    int a = cnt[2 * t], b_ = cnt[2 * t + 1];
    ssum[t] = a + b_;
    __syncthreads();
    for (int off = 1; off < 256; off <<= 1) {       // Hillis-Steele inclusive over 256 pair-sums
        int v = (t >= off) ? ssum[t - off] : 0;
        __syncthreads();
        ssum[t] += v;
        __syncthreads();
    }
    int excl = ssum[t] - (a + b_);
    if (2 * t < NBKT)     cando[(size_t)c * NBKT + 2 * t]     = make_int2(a, excl);
    if (2 * t + 1 < NBKT) cando[(size_t)c * NBKT + 2 * t + 1] = make_int2(b_, excl + a);
    __syncthreads();
    cnt[2 * t] = excl; cnt[2 * t + 1] = excl + a;    // reuse as cursors
    __syncthreads();
    #pragma unroll
    for (int i = 0; i < 8; i++) {
        if (d8[i] >= 0) {
            int pos = atomicAdd(&cnt[d8[i] >> 8], 1);
            recs[pos] = ((long long)d8[i] << 32) | (unsigned)s8[i];
        }
    }
    __syncthreads();
    for (int j = t; j < nv; j += 256)
        recs_out[(size_t)e0 + j] = recs[j];          // fully coalesced 8B stores
}

// ---------------- phase 2: per-bucket fill of final CSR (L2-compact scatter region) ----------------
__global__ __launch_bounds__(512) void bucket_fill_kernel(const long long* __restrict__ recs_bin,
                                                          const int2* __restrict__ cando,
                                                          const int* __restrict__ rowptr,
                                                          const float* __restrict__ dinv,
                                                          long long* __restrict__ csr_rec,
                                                          int nch, int n) {
    __shared__ int cur[256];
    int b = blockIdx.x;
    int node0 = b << 8;
    int t = threadIdx.x;
    if (t < 256) {
        int nd = node0 + t;
        cur[t] = (nd < n) ? rowptr[nd] : 0;
    }
    __syncthreads();
    for (int c = t; c < nch; c += 512) {
        int2 co = cando[(size_t)c * NBKT + b];
        size_t base = (size_t)c * CHSZ + co.y;
        for (int k = 0; k < co.x; ++k) {
            long long rec = recs_bin[base + k];
            int d = (int)(rec >> 32);
            int s = (int)(unsigned)(rec & 0xffffffffLL);
            float w = dinv[s] * dinv[d];
            int pos = atomicAdd(&cur[d & 255], 1);
            csr_rec[pos] = ((long long)__float_as_int(w) << 32) | (unsigned)s;
        }
    }
}

// ---------------- weight prep: pack W (f32 row-major 128x128) into B-fragment-linear bf16 ----------------
__global__ __launch_bounds__(256) void wprep_kernel(const float* __restrict__ W1,
                                                    const float* __restrict__ W2,
                                                    const float* __restrict__ W3,
                                                    unsigned short* __restrict__ Wf) {
    int gid = blockIdx.x * 256 + threadIdx.x;   // 0..49151
    int w = gid >> 14;
    int o = gid & 16383;
    int j = o & 7, lane = (o >> 3) & 63, ct = (o >> 9) & 7, kt = o >> 12;
    int rk = kt * 32 + (lane >> 4) * 8 + j;
    int col = ct * 16 + (lane & 15);
    const float* W = (w == 0) ? W1 : ((w == 1) ? W2 : W3);
    Wf[gid] = f2b(W[rk * HIDF + col]);
}

// ---------------- MFMA GEMM: Hbf = f(X) @ W  (bf16 table out) ----------------
template <typename T>
__global__ __launch_bounds__(256) void mfma_gemm_kernel(const T* __restrict__ X,
                                                        const unsigned short* __restrict__ Wfrag,
                                                        const float* __restrict__ bias,
                                                        unsigned short* __restrict__ Hbf, int n) {
    __shared__ unsigned short wl[16384];   // 32 KB: full 128x128 bf16 W in fragment-linear layout
    {
        const uint4* wsrc = reinterpret_cast<const uint4*>(Wfrag);
        uint4* wdst = reinterpret_cast<uint4*>(wl);
        for (int i = threadIdx.x; i < 2048; i += 256) wdst[i] = wsrc[i];
    }
    __syncthreads();

    int wv = threadIdx.x >> 6;          // wave 0..3
    int l  = threadIdx.x & 63;          // lane
    int row = blockIdx.x * 64 + wv * 16 + (l & 15);
    int koff = (l >> 4) * 8;
    bool rowok = row < n;

    f32x4 acc[8] = {};
    #pragma unroll
    for (int kt = 0; kt < 4; ++kt) {
        int kbase = kt * 32 + koff;
        bf16x8 a;
        if constexpr (sizeof(T) == 4) {          // f32 input (layer 1, no bias)
            float4 x0 = {0,0,0,0}, x1 = {0,0,0,0};
            if (rowok) {
                x0 = *reinterpret_cast<const float4*>(&X[(size_t)row * HIDF + kbase]);
                x1 = *reinterpret_cast<const float4*>(&X[(size_t)row * HIDF + kbase + 4]);
            }
            a[0] = (short)f2b(x0.x); a[1] = (short)f2b(x0.y);
            a[2] = (short)f2b(x0.z); a[3] = (short)f2b(x0.w);
            a[4] = (short)f2b(x1.x); a[5] = (short)f2b(x1.y);
            a[6] = (short)f2b(x1.z); a[7] = (short)f2b(x1.w);
        } else {                                  // bf16 input (layers 2,3; +bias,relu)
            uint4 raw = {0,0,0,0};
            if (rowok) raw = *reinterpret_cast<const uint4*>(&X[(size_t)row * HIDF + kbase]);
            unsigned short* ru = reinterpret_cast<unsigned short*>(&raw);
            if (bias) {
                #pragma unroll
                for (int j = 0; j < 8; ++j) {
                    float v = b2f(ru[j]) + bias[kbase + j];
                    ru[j] = f2b(fmaxf(v, 0.f));
                }
            }
            a = *reinterpret_cast<bf16x8*>(&raw);
        }
        #pragma unroll
        for (int ct = 0; ct < 8; ++ct) {
            bf16x8 b = *reinterpret_cast<bf16x8*>(&wl[((kt * 8 + ct) * 64 + l) * 8]);
            acc[ct] = __builtin_amdgcn_mfma_f32_16x16x32_bf16(a, b, acc[ct], 0, 0, 0);
        }
    }
    int rbase = blockIdx.x * 64 + wv * 16 + ((l >> 4) << 2);
    int cbase = l & 15;
    #pragma unroll
    for (int ct = 0; ct < 8; ++ct) {
        #pragma unroll
        for (int r = 0; r < 4; ++r) {
            int gr = rbase + r;
            if (gr < n) Hbf[(size_t)gr * HIDF + ct * 16 + cbase] = f2b(acc[ct][r]);
        }
    }
}

// ---------------- gather aggregation: batched record load + broadcast (bf16 in, bf16 out) ----------------
__global__ __launch_bounds__(256) void gather_agg_kernel(const unsigned short* __restrict__ Hin,
                                                         const int* __restrict__ rowptr,
                                                         const long long* __restrict__ csr_rec,
                                                         const float* __restrict__ selfw,
                                                         unsigned short* __restrict__ Hout, int n) {
    int node = blockIdx.x * 8 + (threadIdx.x >> 5);
    if (node >= n) return;
    int lane = threadIdx.x & 31;
    ushort4 sv = *reinterpret_cast<const ushort4*>(&Hin[(size_t)node * HIDF + lane * 4]);
    float sw = selfw[node];
    float4 acc;
    acc.x = b2f(sv.x) * sw; acc.y = b2f(sv.y) * sw;
    acc.z = b2f(sv.z) * sw; acc.w = b2f(sv.w) * sw;
    int beg = rowptr[node], end = rowptr[node + 1];
    for (int base = beg; base < end; base += 32) {
        int m = end - base; if (m > 32) m = 32;
        long long rec = 0;
        if (base + lane < end) rec = csr_rec[base + lane];   // one coalesced 8B/lane load
        #pragma unroll 4
        for (int j = 0; j < m; ++j) {
            long long r = __shfl(rec, j, 32);                // register broadcast, no cache hop
            int sn = (int)(unsigned)(r & 0xffffffffLL);
            float w = __int_as_float((int)(r >> 32));
            ushort4 v = *reinterpret_cast<const ushort4*>(&Hin[(size_t)sn * HIDF + lane * 4]);
            acc.x += b2f(v.x) * w; acc.y += b2f(v.y) * w;
            acc.z += b2f(v.z) * w; acc.w += b2f(v.w) * w;
        }
    }
    ushort4 o;
    o.x = f2b(acc.x); o.y = f2b(acc.y); o.z = f2b(acc.z); o.w = f2b(acc.w);
    *reinterpret_cast<ushort4*>(&Hout[(size_t)node * HIDF + lane * 4]) = o;
}

// ---------------- mean pool: 8 row-groups x 32 lanes, coalesced ushort4 loads ----------------
__device__ __forceinline__ int lower_bound_i(const int* __restrict__ a, int n, int key) {
    int lo = 0, hi = n;
    while (lo < hi) { int mid = (lo + hi) >> 1; if (a[mid] < key) lo = mid + 1; else hi = mid; }
    return lo;
}

__global__ __launch_bounds__(256) void pool_kernel(const unsigned short* __restrict__ H,
                                                   const int* __restrict__ batch,
                                                   const float* __restrict__ b3,
                                                   float* __restrict__ gmean, int n) {
    __shared__ float part[8][HIDF];
    int b = blockIdx.x;
    int g = threadIdx.x >> 5;       // row group 0..7
    int lane = threadIdx.x & 31;    // feature quad: 4*lane .. 4*lane+3
    int s = lower_bound_i(batch, n, b);
    int e = lower_bound_i(batch, n, b + 1);
    float4 acc = {0.f, 0.f, 0.f, 0.f};
    for (int i = s + g; i < e; i += 8) {
        ushort4 v = *reinterpret_cast<const ushort4*>(&H[(size_t)i * HIDF + lane * 4]);
        acc.x += b2f(v.x); acc.y += b2f(v.y);
        acc.z += b2f(v.z); acc.w += b2f(v.w);
    }
    part[g][lane * 4 + 0] = acc.x;
    part[g][lane * 4 + 1] = acc.y;
    part[g][lane * 4 + 2] = acc.z;
    part[g][lane * 4 + 3] = acc.w;
    __syncthreads();
    if (threadIdx.x < HIDF) {
        int f = threadIdx.x;
        float sum = 0.f;
        #pragma unroll
        for (int gg = 0; gg < 8; ++gg) sum += part[gg][f];
        float cnt = fmaxf((float)(e - s), 1.0f);
        gmean[b * HIDF + f] = sum / cnt + b3[f];
    }
}

// ---------------- centroid head: one wave per graph ----------------
__global__ __launch_bounds__(64) void final_kernel(const float* __restrict__ gmean,
                                                   const float* __restrict__ centroids,
                                                   const float* __restrict__ std_scale,
                                                   const float* __restrict__ ac_temp,
                                                   float* __restrict__ out) {
    int b = blockIdx.x;
    int lane = threadIdx.x;
    float g0 = gmean[b * HIDF + lane];
    float g1 = gmean[b * HIDF + 64 + lane];
    float mind = 1e30f;
    for (int c = 0; c < NCLS; ++c) {
        float dd[2];
        #pragma unroll
        for (int cent = 0; cent < 2; ++cent) {
            const float* cp = &centroids[(c * 2 + cent) * HIDF];
            float df0 = cp[lane] - g0;
            float df1 = cp[64 + lane] - g1;
            float p = df0 * df0 + df1 * df1;
            #pragma unroll
            for (int off = 32; off > 0; off >>= 1) p += __shfl_xor(p, off);
            dd[cent] = p;
        }
        float dist = fminf(sqrtf(dd[0]), sqrtf(dd[1]));
        mind = fminf(mind, dist);
        if (lane == 0) out[b * NCLS + c] = -dist;
    }
    if (lane == 0) {
        float ss = std_scale[0];
        float clipped = fminf(fmaxf(ss, 0.0f), 5.0f);
        float max_ac = 1.0f + clipped * 0.0f;      // RUNNING_MEAN=1, sqrt(RUNNING_VAR)=0
        float accept = max_ac - mind;
        float soft = 1.0f / (1.0f + expf(-accept / ac_temp[0]));
        out[NGR * NCLS + b] = soft;
    }
}

// ---------------- launch ----------------
extern "C" void kernel_launch(void* const* d_in, const int* in_sizes, int n_in,
                              void* d_out, int out_size, void* d_ws, size_t ws_size,
                              hipStream_t stream) {
    const float* x         = (const float*)d_in[0];
    const int*   edge      = (const int*)d_in[1];
    const int*   batch     = (const int*)d_in[2];
    const float* W1        = (const float*)d_in[3];
    const float* b1        = (const float*)d_in[4];
    const float* W2        = (const float*)d_in[5];
    const float* b2        = (const float*)d_in[6];
    const float* W3        = (const float*)d_in[7];
    const float* b3        = (const float*)d_in[8];
    const float* centroids = (const float*)d_in[9];
    const float* std_scale = (const float*)d_in[10];
    const float* ac_temp   = (const float*)d_in[11];
    float* out = (float*)d_out;

    const int n  = NN;
    const int nE = in_sizes[1] / 2;
    const int* srcp = edge;
    const int* dstp = edge + nE;
    const int nch = (nE + CHSZ - 1) / CHSZ;

    // workspace layout (256B aligned)
    char* ws = (char*)d_ws;
    size_t off = 0;
    auto alloc = [&](size_t bytes) { void* p = ws + off; off = (off + bytes + 255) & ~(size_t)255; return p; };
    unsigned short* hA = (unsigned short*)alloc((size_t)NN * HIDF * 2);  // bf16 GEMM output table
    unsigned short* hG = (unsigned short*)alloc((size_t)NN * HIDF * 2);  // bf16 gather output table
    unsigned short* Wf = (unsigned short*)alloc((size_t)3 * HIDF * HIDF * 2);
    float* dinv    = (float*)alloc((size_t)NN * 4);
    float* selfw   = (float*)alloc((size_t)NN * 4);
    int*   cnt     = (int*)  alloc((size_t)NN * 4);
    int*   rowptr  = (int*)  alloc((size_t)(NN + 1) * 4);
    long long* csr_rec  = (long long*)alloc((size_t)nE * 8);
    long long* recs_bin = (long long*)alloc((size_t)nE * 8);
    int2*  cando   = (int2*) alloc((size_t)nch * NBKT * 8);
    float* gmean   = (float*)alloc((size_t)NGR * HIDF * 4);
    int*   bsum    = (int*)  alloc((size_t)SB * 4);
    int*   boff    = (int*)  alloc((size_t)SB * 4);

    // ---- weight prep + CSR build (CSR reused by all 3 layers) ----
    wprep_kernel<<<192, 256, 0, stream>>>(W1, W2, W3, Wf);
    hipMemsetAsync(cnt, 0, (size_t)NN * 4, stream);
    bin_kernel<<<nch, 256, 0, stream>>>(srcp, dstp, recs_bin, cando, nE);
    count_deg_kernel<<<(nE + 255) / 256, 256, 0, stream>>>(dstp, cnt, nE);
    block_sum_kernel<<<SB, 256, 0, stream>>>(cnt, bsum, n);
    scan_bsum_kernel<<<1, 128, 0, stream>>>(bsum, boff, SB);
    scan_fill_kernel<<<SB, 256, 0, stream>>>(cnt, boff, rowptr, n, nE);
    node_prep_kernel<<<(n + 255) / 256, 256, 0, stream>>>(cnt, dinv, selfw, n);
    bucket_fill_kernel<<<NBKT, 512, 0, stream>>>(recs_bin, cando, rowptr, dinv, csr_rec, nch, n);

    int gemm_blocks   = (n + 63) / 64;
    int gather_blocks = (n + 7) / 8;

    // layer 1: x f32 -> hA; gather -> hG
    mfma_gemm_kernel<float><<<gemm_blocks, 256, 0, stream>>>(x, Wf, nullptr, hA, n);
    gather_agg_kernel<<<gather_blocks, 256, 0, stream>>>(hA, rowptr, csr_rec, selfw, hG, n);
    // layer 2: (+b1, relu) fused into A-load
    mfma_gemm_kernel<unsigned short><<<gemm_blocks, 256, 0, stream>>>(hG, Wf + 16384, b1, hA, n);
    gather_agg_kernel<<<gather_blocks, 256, 0, stream>>>(hA, rowptr, csr_rec, selfw, hG, n);
    // layer 3: (+b2, relu)
    mfma_gemm_kernel<unsigned short><<<gemm_blocks, 256, 0, stream>>>(hG, Wf + 32768, b2, hA, n);
    gather_agg_kernel<<<gather_blocks, 256, 0, stream>>>(hA, rowptr, csr_rec, selfw, hG, n);

    // mean pool (+b3 folded) — batch is sorted, no atomics
    pool_kernel<<<NGR, 256, 0, stream>>>(hG, batch, b3, gmean, n);
    final_kernel<<<NGR, 64, 0, stream>>>(gmean, centroids, std_scale, ac_temp, out);
}

// Round 9
// 378.982 us; speedup vs baseline: 22.7446x; 1.1086x over previous
//
#include <hip/hip_runtime.h>
#include <hip/hip_bf16.h>
#include <math.h>

#define NN 100000
#define NEDGE 1600000
#define HIDF 128
#define NCLS 18
#define NGR 512
#define SC 1024                       // elements per scan chunk
#define SB ((NN + SC - 1) / SC)       // 98 scan blocks
#define CHSZ 2048                     // edges per bin chunk
#define NBKT 391                      // ceil(NN/256) buckets of 256 nodes

using bf16x8 = __attribute__((ext_vector_type(8))) short;   // 8 bf16 in 4 VGPRs
using f32x4  = __attribute__((ext_vector_type(4))) float;
using f32x2  = __attribute__((ext_vector_type(2))) float;

__device__ __forceinline__ float b2f(unsigned short u) {
    return __uint_as_float(((unsigned)u) << 16);
}
__device__ __forceinline__ unsigned short f2b(float f) {   // round-to-nearest-even
    unsigned u = __float_as_uint(f);
    unsigned r = (u + 0x7fffu + ((u >> 16) & 1u)) >> 16;
    return (unsigned short)r;
}
__device__ __forceinline__ unsigned char f2fp8(float f) {  // f32 -> OCP e4m3 (HW cvt)
    int p = __builtin_amdgcn_cvt_pk_fp8_f32(f, f, 0, false);
    return (unsigned char)(p & 0xff);
}

// ---------------- degree count ----------------
__global__ void count_deg_kernel(const int* __restrict__ dst, int* __restrict__ cnt, int nE) {
    int e = blockIdx.x * blockDim.x + threadIdx.x;
    if (e < nE) atomicAdd(&cnt[dst[e]], 1);
}

__global__ void node_prep_kernel(const int* __restrict__ cnt, float* __restrict__ dinv,
                                 float* __restrict__ selfw, int n) {
    int i = blockIdx.x * blockDim.x + threadIdx.x;
    if (i < n) {
        float deg = (float)cnt[i] + 1.0f;   // +1 self loop
        dinv[i]  = rsqrtf(deg);
        selfw[i] = 1.0f / deg;
    }
}

// ---------------- device-wide exclusive scan: 3 phases ----------------
__global__ __launch_bounds__(256) void block_sum_kernel(const int* __restrict__ cnt,
                                                        int* __restrict__ bsum, int n) {
    int base = blockIdx.x * SC;
    int sum = 0;
    for (int i = threadIdx.x; i < SC; i += 256) {
        int idx = base + i;
        if (idx < n) sum += cnt[idx];
    }
    #pragma unroll
    for (int off = 32; off > 0; off >>= 1) sum += __shfl_down(sum, off);
    __shared__ int wsum[4];
    if ((threadIdx.x & 63) == 0) wsum[threadIdx.x >> 6] = sum;
    __syncthreads();
    if (threadIdx.x == 0) bsum[blockIdx.x] = wsum[0] + wsum[1] + wsum[2] + wsum[3];
}

__global__ __launch_bounds__(128) void scan_bsum_kernel(const int* __restrict__ bsum,
                                                        int* __restrict__ boff, int nb) {
    __shared__ int t[128];
    int tid = threadIdx.x;
    t[tid] = (tid < nb) ? bsum[tid] : 0;
    __syncthreads();
    for (int off = 1; off < 128; off <<= 1) {
        int v = (tid >= off) ? t[tid - off] : 0;
        __syncthreads();
        t[tid] += v;
        __syncthreads();
    }
    if (tid < nb) boff[tid] = (tid == 0) ? 0 : t[tid - 1];
}

__global__ __launch_bounds__(256) void scan_fill_kernel(const int* __restrict__ cnt,
                                                        const int* __restrict__ boff,
                                                        int* __restrict__ rowptr, int n, int nE) {
    __shared__ int t[256];
    int base = blockIdx.x * SC;
    int s = base + threadIdx.x * 4;
    int v0 = 0, v1 = 0, v2 = 0, v3 = 0;
    if (s + 0 < n) v0 = cnt[s + 0];
    if (s + 1 < n) v1 = cnt[s + 1];
    if (s + 2 < n) v2 = cnt[s + 2];
    if (s + 3 < n) v3 = cnt[s + 3];
    int sum = v0 + v1 + v2 + v3;
    t[threadIdx.x] = sum;
    __syncthreads();
    for (int off = 1; off < 256; off <<= 1) {
        int v = (threadIdx.x >= off) ? t[threadIdx.x - off] : 0;
        __syncthreads();
        t[threadIdx.x] += v;
        __syncthreads();
    }
    int run = boff[blockIdx.x] + ((threadIdx.x == 0) ? 0 : t[threadIdx.x - 1]);
    if (s + 0 < n) { rowptr[s + 0] = run; run += v0; }
    if (s + 1 < n) { rowptr[s + 1] = run; run += v1; }
    if (s + 2 < n) { rowptr[s + 2] = run; run += v2; }
    if (s + 3 < n) { rowptr[s + 3] = run; run += v3; }
    if (blockIdx.x == 0 && threadIdx.x == 0) rowptr[n] = nE;
}

// ---------------- phase 1: bin edges into 256-node buckets, chunk-local, coalesced out ----------------
__global__ __launch_bounds__(256) void bin_kernel(const int* __restrict__ src,
                                                  const int* __restrict__ dst,
                                                  long long* __restrict__ recs_out,
                                                  int2* __restrict__ cando, int nE) {
    __shared__ int cnt[512];
    __shared__ int ssum[256];
    __shared__ long long recs[CHSZ];
    int c = blockIdx.x;
    int t = threadIdx.x;
    cnt[t] = 0; cnt[t + 256] = 0;
    __syncthreads();
    int e0 = c * CHSZ;
    int nv = nE - e0; if (nv > CHSZ) nv = CHSZ;
    int s8[8], d8[8];
    #pragma unroll
    for (int i = 0; i < 8; i++) {
        int li = t + i * 256;
        bool ok = li < nv;
        s8[i] = ok ? src[e0 + li] : -1;
        d8[i] = ok ? dst[e0 + li] : -1;
        if (ok) atomicAdd(&cnt[d8[i] >> 8], 1);
    }
    __syncthreads();
    int a = cnt[2 * t], b_ = cnt[2 * t + 1];
    ssum[t] = a + b_;
    __syncthreads();
    for (int off = 1; off < 256; off <<= 1) {       // Hillis-Steele inclusive over 256 pair-sums
        int v = (t >= off) ? ssum[t - off] : 0;
        __syncthreads();
        ssum[t] += v;
        __syncthreads();
    }
    int excl = ssum[t] - (a + b_);
    if (2 * t < NBKT)     cando[(size_t)c * NBKT + 2 * t]     = make_int2(a, excl);
    if (2 * t + 1 < NBKT) cando[(size_t)c * NBKT + 2 * t + 1] = make_int2(b_, excl + a);
    __syncthreads();
    cnt[2 * t] = excl; cnt[2 * t + 1] = excl + a;    // reuse as cursors
    __syncthreads();
    #pragma unroll
    for (int i = 0; i < 8; i++) {
        if (d8[i] >= 0) {
            int pos = atomicAdd(&cnt[d8[i] >> 8], 1);
            recs[pos] = ((long long)d8[i] << 32) | (unsigned)s8[i];
        }
    }
    __syncthreads();
    for (int j = t; j < nv; j += 256)
        recs_out[(size_t)e0 + j] = recs[j];          // fully coalesced 8B stores
}

// ---------------- phase 2: per-bucket fill of final CSR (L2-compact scatter region) ----------------
__global__ __launch_bounds__(512) void bucket_fill_kernel(const long long* __restrict__ recs_bin,
                                                          const int2* __restrict__ cando,
                                                          const int* __restrict__ rowptr,
                                                          const float* __restrict__ dinv,
                                                          long long* __restrict__ csr_rec,
                                                          int nch, int n) {
    __shared__ int cur[256];
    int b = blockIdx.x;
    int node0 = b << 8;
    int t = threadIdx.x;
    if (t < 256) {
        int nd = node0 + t;
        cur[t] = (nd < n) ? rowptr[nd] : 0;
    }
    __syncthreads();
    for (int c = t; c < nch; c += 512) {
        int2 co = cando[(size_t)c * NBKT + b];
        size_t base = (size_t)c * CHSZ + co.y;
        for (int k = 0; k < co.x; ++k) {
            long long rec = recs_bin[base + k];
            int d = (int)(rec >> 32);
            int s = (int)(unsigned)(rec & 0xffffffffLL);
            float w = dinv[s] * dinv[d];
            int pos = atomicAdd(&cur[d & 255], 1);
            csr_rec[pos] = ((long long)__float_as_int(w) << 32) | (unsigned)s;
        }
    }
}

// ---------------- weight prep: pack W (f32 row-major 128x128) into B-fragment-linear bf16 ----------------
__global__ __launch_bounds__(256) void wprep_kernel(const float* __restrict__ W1,
                                                    const float* __restrict__ W2,
                                                    const float* __restrict__ W3,
                                                    unsigned short* __restrict__ Wf) {
    int gid = blockIdx.x * 256 + threadIdx.x;   // 0..49151
    int w = gid >> 14;
    int o = gid & 16383;
    int j = o & 7, lane = (o >> 3) & 63, ct = (o >> 9) & 7, kt = o >> 12;
    int rk = kt * 32 + (lane >> 4) * 8 + j;
    int col = ct * 16 + (lane & 15);
    const float* W = (w == 0) ? W1 : ((w == 1) ? W2 : W3);
    Wf[gid] = f2b(W[rk * HIDF + col]);
}

// ---------------- MFMA GEMM: Hfp8 = f(X) @ W  (fp8 e4m3 table out) ----------------
template <typename T>
__global__ __launch_bounds__(256) void mfma_gemm_kernel(const T* __restrict__ X,
                                                        const unsigned short* __restrict__ Wfrag,
                                                        const float* __restrict__ bias,
                                                        unsigned char* __restrict__ Hfp8, int n) {
    __shared__ unsigned short wl[16384];   // 32 KB: full 128x128 bf16 W in fragment-linear layout
    {
        const uint4* wsrc = reinterpret_cast<const uint4*>(Wfrag);
        uint4* wdst = reinterpret_cast<uint4*>(wl);
        for (int i = threadIdx.x; i < 2048; i += 256) wdst[i] = wsrc[i];
    }
    __syncthreads();

    int wv = threadIdx.x >> 6;          // wave 0..3
    int l  = threadIdx.x & 63;          // lane
    int row = blockIdx.x * 64 + wv * 16 + (l & 15);
    int koff = (l >> 4) * 8;
    bool rowok = row < n;

    f32x4 acc[8] = {};
    #pragma unroll
    for (int kt = 0; kt < 4; ++kt) {
        int kbase = kt * 32 + koff;
        bf16x8 a;
        if constexpr (sizeof(T) == 4) {          // f32 input (layer 1, no bias)
            float4 x0 = {0,0,0,0}, x1 = {0,0,0,0};
            if (rowok) {
                x0 = *reinterpret_cast<const float4*>(&X[(size_t)row * HIDF + kbase]);
                x1 = *reinterpret_cast<const float4*>(&X[(size_t)row * HIDF + kbase + 4]);
            }
            a[0] = (short)f2b(x0.x); a[1] = (short)f2b(x0.y);
            a[2] = (short)f2b(x0.z); a[3] = (short)f2b(x0.w);
            a[4] = (short)f2b(x1.x); a[5] = (short)f2b(x1.y);
            a[6] = (short)f2b(x1.z); a[7] = (short)f2b(x1.w);
        } else {                                  // bf16 input (layers 2,3; +bias,relu)
            uint4 raw = {0,0,0,0};
            if (rowok) raw = *reinterpret_cast<const uint4*>(&X[(size_t)row * HIDF + kbase]);
            unsigned short* ru = reinterpret_cast<unsigned short*>(&raw);
            if (bias) {
                #pragma unroll
                for (int j = 0; j < 8; ++j) {
                    float v = b2f(ru[j]) + bias[kbase + j];
                    ru[j] = f2b(fmaxf(v, 0.f));
                }
            }
            a = *reinterpret_cast<bf16x8*>(&raw);
        }
        #pragma unroll
        for (int ct = 0; ct < 8; ++ct) {
            bf16x8 b = *reinterpret_cast<bf16x8*>(&wl[((kt * 8 + ct) * 64 + l) * 8]);
            acc[ct] = __builtin_amdgcn_mfma_f32_16x16x32_bf16(a, b, acc[ct], 0, 0, 0);
        }
    }
    int rbase = blockIdx.x * 64 + wv * 16 + ((l >> 4) << 2);
    int cbase = l & 15;
    #pragma unroll
    for (int ct = 0; ct < 8; ++ct) {
        #pragma unroll
        for (int r = 0; r < 4; ++r) {
            int gr = rbase + r;
            if (gr < n) Hfp8[(size_t)gr * HIDF + ct * 16 + cbase] = f2fp8(acc[ct][r]);
        }
    }
}

// ---------------- gather aggregation over fp8 table (f32 acc, bf16 out) ----------------
__global__ __launch_bounds__(256) void gather_agg_kernel(const unsigned char* __restrict__ Hin,
                                                         const int* __restrict__ rowptr,
                                                         const long long* __restrict__ csr_rec,
                                                         const float* __restrict__ selfw,
                                                         unsigned short* __restrict__ Hout, int n) {
    int node = blockIdx.x * 8 + (threadIdx.x >> 5);
    if (node >= n) return;
    int lane = threadIdx.x & 31;
    unsigned sw32 = *reinterpret_cast<const unsigned*>(&Hin[(size_t)node * HIDF + lane * 4]);
    float sw = selfw[node];
    f32x2 slo = __builtin_amdgcn_cvt_pk_f32_fp8((int)sw32, false);
    f32x2 shi = __builtin_amdgcn_cvt_pk_f32_fp8((int)sw32, true);
    float4 acc;
    acc.x = slo[0] * sw; acc.y = slo[1] * sw;
    acc.z = shi[0] * sw; acc.w = shi[1] * sw;
    int beg = rowptr[node], end = rowptr[node + 1];
    for (int base = beg; base < end; base += 32) {
        int m = end - base; if (m > 32) m = 32;
        long long rec = 0;
        if (base + lane < end) rec = csr_rec[base + lane];   // one coalesced 8B/lane load
        #pragma unroll 4
        for (int j = 0; j < m; ++j) {
            long long r = __shfl(rec, j, 32);                // register broadcast, no cache hop
            int sn = (int)(unsigned)(r & 0xffffffffLL);
            float w = __int_as_float((int)(r >> 32));
            unsigned v32 = *reinterpret_cast<const unsigned*>(&Hin[(size_t)sn * HIDF + lane * 4]);
            f32x2 lo = __builtin_amdgcn_cvt_pk_f32_fp8((int)v32, false);
            f32x2 hi = __builtin_amdgcn_cvt_pk_f32_fp8((int)v32, true);
            acc.x += lo[0] * w; acc.y += lo[1] * w;
            acc.z += hi[0] * w; acc.w += hi[1] * w;
        }
    }
    ushort4 o;
    o.x = f2b(acc.x); o.y = f2b(acc.y); o.z = f2b(acc.z); o.w = f2b(acc.w);
    *reinterpret_cast<ushort4*>(&Hout[(size_t)node * HIDF + lane * 4]) = o;
}

// ---------------- mean pool: 8 row-groups x 32 lanes, coalesced ushort4 loads ----------------
__device__ __forceinline__ int lower_bound_i(const int* __restrict__ a, int n, int key) {
    int lo = 0, hi = n;
    while (lo < hi) { int mid = (lo + hi) >> 1; if (a[mid] < key) lo = mid + 1; else hi = mid; }
    return lo;
}

__global__ __launch_bounds__(256) void pool_kernel(const unsigned short* __restrict__ H,
                                                   const int* __restrict__ batch,
                                                   const float* __restrict__ b3,
                                                   float* __restrict__ gmean, int n) {
    __shared__ float part[8][HIDF];
    int b = blockIdx.x;
    int g = threadIdx.x >> 5;       // row group 0..7
    int lane = threadIdx.x & 31;    // feature quad: 4*lane .. 4*lane+3
    int s = lower_bound_i(batch, n, b);
    int e = lower_bound_i(batch, n, b + 1);
    float4 acc = {0.f, 0.f, 0.f, 0.f};
    for (int i = s + g; i < e; i += 8) {
        ushort4 v = *reinterpret_cast<const ushort4*>(&H[(size_t)i * HIDF + lane * 4]);
        acc.x += b2f(v.x); acc.y += b2f(v.y);
        acc.z += b2f(v.z); acc.w += b2f(v.w);
    }
    part[g][lane * 4 + 0] = acc.x;
    part[g][lane * 4 + 1] = acc.y;
    part[g][lane * 4 + 2] = acc.z;
    part[g][lane * 4 + 3] = acc.w;
    __syncthreads();
    if (threadIdx.x < HIDF) {
        int f = threadIdx.x;
        float sum = 0.f;
        #pragma unroll
        for (int gg = 0; gg < 8; ++gg) sum += part[gg][f];
        float cnt = fmaxf((float)(e - s), 1.0f);
        gmean[b * HIDF + f] = sum / cnt + b3[f];
    }
}

// ---------------- centroid head: one wave per graph ----------------
__global__ __launch_bounds__(64) void final_kernel(const float* __restrict__ gmean,
                                                   const float* __restrict__ centroids,
                                                   const float* __restrict__ std_scale,
                                                   const float* __restrict__ ac_temp,
                                                   float* __restrict__ out) {
    int b = blockIdx.x;
    int lane = threadIdx.x;
    float g0 = gmean[b * HIDF + lane];
    float g1 = gmean[b * HIDF + 64 + lane];
    float mind = 1e30f;
    for (int c = 0; c < NCLS; ++c) {
        float dd[2];
        #pragma unroll
        for (int cent = 0; cent < 2; ++cent) {
            const float* cp = &centroids[(c * 2 + cent) * HIDF];
            float df0 = cp[lane] - g0;
            float df1 = cp[64 + lane] - g1;
            float p = df0 * df0 + df1 * df1;
            #pragma unroll
            for (int off = 32; off > 0; off >>= 1) p += __shfl_xor(p, off);
            dd[cent] = p;
        }
        float dist = fminf(sqrtf(dd[0]), sqrtf(dd[1]));
        mind = fminf(mind, dist);
        if (lane == 0) out[b * NCLS + c] = -dist;
    }
    if (lane == 0) {
        float ss = std_scale[0];
        float clipped = fminf(fmaxf(ss, 0.0f), 5.0f);
        float max_ac = 1.0f + clipped * 0.0f;      // RUNNING_MEAN=1, sqrt(RUNNING_VAR)=0
        float accept = max_ac - mind;
        float soft = 1.0f / (1.0f + expf(-accept / ac_temp[0]));
        out[NGR * NCLS + b] = soft;
    }
}

// ---------------- launch ----------------
extern "C" void kernel_launch(void* const* d_in, const int* in_sizes, int n_in,
                              void* d_out, int out_size, void* d_ws, size_t ws_size,
                              hipStream_t stream) {
    const float* x         = (const float*)d_in[0];
    const int*   edge      = (const int*)d_in[1];
    const int*   batch     = (const int*)d_in[2];
    const float* W1        = (const float*)d_in[3];
    const float* b1        = (const float*)d_in[4];
    const float* W2        = (const float*)d_in[5];
    const float* b2        = (const float*)d_in[6];
    const float* W3        = (const float*)d_in[7];
    const float* b3        = (const float*)d_in[8];
    const float* centroids = (const float*)d_in[9];
    const float* std_scale = (const float*)d_in[10];
    const float* ac_temp   = (const float*)d_in[11];
    float* out = (float*)d_out;

    const int n  = NN;
    const int nE = in_sizes[1] / 2;
    const int* srcp = edge;
    const int* dstp = edge + nE;
    const int nch = (nE + CHSZ - 1) / CHSZ;

    // workspace layout (256B aligned)
    char* ws = (char*)d_ws;
    size_t off = 0;
    auto alloc = [&](size_t bytes) { void* p = ws + off; off = (off + bytes + 255) & ~(size_t)255; return p; };
    unsigned char*  hA = (unsigned char*) alloc((size_t)NN * HIDF);      // fp8 GEMM output table
    unsigned short* hG = (unsigned short*)alloc((size_t)NN * HIDF * 2);  // bf16 gather output table
    unsigned short* Wf = (unsigned short*)alloc((size_t)3 * HIDF * HIDF * 2);
    float* dinv    = (float*)alloc((size_t)NN * 4);
    float* selfw   = (float*)alloc((size_t)NN * 4);
    int*   cnt     = (int*)  alloc((size_t)NN * 4);
    int*   rowptr  = (int*)  alloc((size_t)(NN + 1) * 4);
    long long* csr_rec  = (long long*)alloc((size_t)nE * 8);
    long long* recs_bin = (long long*)alloc((size_t)nE * 8);
    int2*  cando   = (int2*) alloc((size_t)nch * NBKT * 8);
    float* gmean   = (float*)alloc((size_t)NGR * HIDF * 4);
    int*   bsum    = (int*)  alloc((size_t)SB * 4);
    int*   boff    = (int*)  alloc((size_t)SB * 4);

    // ---- weight prep + CSR build (CSR reused by all 3 layers) ----
    wprep_kernel<<<192, 256, 0, stream>>>(W1, W2, W3, Wf);
    hipMemsetAsync(cnt, 0, (size_t)NN * 4, stream);
    bin_kernel<<<nch, 256, 0, stream>>>(srcp, dstp, recs_bin, cando, nE);
    count_deg_kernel<<<(nE + 255) / 256, 256, 0, stream>>>(dstp, cnt, nE);
    block_sum_kernel<<<SB, 256, 0, stream>>>(cnt, bsum, n);
    scan_bsum_kernel<<<1, 128, 0, stream>>>(bsum, boff, SB);
    scan_fill_kernel<<<SB, 256, 0, stream>>>(cnt, boff, rowptr, n, nE);
    node_prep_kernel<<<(n + 255) / 256, 256, 0, stream>>>(cnt, dinv, selfw, n);
    bucket_fill_kernel<<<NBKT, 512, 0, stream>>>(recs_bin, cando, rowptr, dinv, csr_rec, nch, n);

    int gemm_blocks   = (n + 63) / 64;
    int gather_blocks = (n + 7) / 8;

    // layer 1: x f32 -> hA (fp8); gather -> hG (bf16)
    mfma_gemm_kernel<float><<<gemm_blocks, 256, 0, stream>>>(x, Wf, nullptr, hA, n);
    gather_agg_kernel<<<gather_blocks, 256, 0, stream>>>(hA, rowptr, csr_rec, selfw, hG, n);
    // layer 2: (+b1, relu) fused into A-load
    mfma_gemm_kernel<unsigned short><<<gemm_blocks, 256, 0, stream>>>(hG, Wf + 16384, b1, hA, n);
    gather_agg_kernel<<<gather_blocks, 256, 0, stream>>>(hA, rowptr, csr_rec, selfw, hG, n);
    // layer 3: (+b2, relu)
    mfma_gemm_kernel<unsigned short><<<gemm_blocks, 256, 0, stream>>>(hG, Wf + 32768, b2, hA, n);
    gather_agg_kernel<<<gather_blocks, 256, 0, stream>>>(hA, rowptr, csr_rec, selfw, hG, n);

    // mean pool (+b3 folded) — batch is sorted, no atomics
    pool_kernel<<<NGR, 256, 0, stream>>>(hG, batch, b3, gmean, n);
    final_kernel<<<NGR, 64, 0, stream>>>(gmean, centroids, std_scale, ac_temp, out);
}

// Round 10
// 327.573 us; speedup vs baseline: 26.3141x; 1.1569x over previous
//
#include <hip/hip_runtime.h>
#include <hip/hip_bf16.h>
#include <math.h>

#define NN 100000
#define NEDGE 1600000
#define HIDF 128
#define NCLS 18
#define NGR 512
#define SC 1024                       // elements per scan chunk
#define SB ((NN + SC - 1) / SC)       // 98 scan blocks
#define CHSZ 2048                     // edges per bin chunk
#define NBKT 391                      // ceil(NN/256) buckets of 256 nodes

using bf16x8 = __attribute__((ext_vector_type(8))) short;   // 8 bf16 in 4 VGPRs
using f32x4  = __attribute__((ext_vector_type(4))) float;
using f32x2  = __attribute__((ext_vector_type(2))) float;

__device__ __forceinline__ float b2f(unsigned short u) {
    return __uint_as_float(((unsigned)u) << 16);
}
__device__ __forceinline__ unsigned short f2b(float f) {   // round-to-nearest-even
    unsigned u = __float_as_uint(f);
    unsigned r = (u + 0x7fffu + ((u >> 16) & 1u)) >> 16;
    return (unsigned short)r;
}
__device__ __forceinline__ unsigned char f2fp8(float f) {  // f32 -> OCP e4m3 (HW cvt)
    int p = __builtin_amdgcn_cvt_pk_fp8_f32(f, f, 0, false);
    return (unsigned char)(p & 0xff);
}

__global__ void node_prep_kernel(const int* __restrict__ cnt, float* __restrict__ dinv,
                                 float* __restrict__ selfw, int n) {
    int i = blockIdx.x * blockDim.x + threadIdx.x;
    if (i < n) {
        float deg = (float)cnt[i] + 1.0f;   // +1 self loop
        dinv[i]  = rsqrtf(deg);
        selfw[i] = 1.0f / deg;
    }
}

// ---------------- device-wide exclusive scan: 3 phases ----------------
__global__ __launch_bounds__(256) void block_sum_kernel(const int* __restrict__ cnt,
                                                        int* __restrict__ bsum, int n) {
    int base = blockIdx.x * SC;
    int sum = 0;
    for (int i = threadIdx.x; i < SC; i += 256) {
        int idx = base + i;
        if (idx < n) sum += cnt[idx];
    }
    #pragma unroll
    for (int off = 32; off > 0; off >>= 1) sum += __shfl_down(sum, off);
    __shared__ int wsum[4];
    if ((threadIdx.x & 63) == 0) wsum[threadIdx.x >> 6] = sum;
    __syncthreads();
    if (threadIdx.x == 0) bsum[blockIdx.x] = wsum[0] + wsum[1] + wsum[2] + wsum[3];
}

__global__ __launch_bounds__(128) void scan_bsum_kernel(const int* __restrict__ bsum,
                                                        int* __restrict__ boff, int nb) {
    __shared__ int t[128];
    int tid = threadIdx.x;
    t[tid] = (tid < nb) ? bsum[tid] : 0;
    __syncthreads();
    for (int off = 1; off < 128; off <<= 1) {
        int v = (tid >= off) ? t[tid - off] : 0;
        __syncthreads();
        t[tid] += v;
        __syncthreads();
    }
    if (tid < nb) boff[tid] = (tid == 0) ? 0 : t[tid - 1];
}

__global__ __launch_bounds__(256) void scan_fill_kernel(const int* __restrict__ cnt,
                                                        const int* __restrict__ boff,
                                                        int* __restrict__ rowptr, int n, int nE) {
    __shared__ int t[256];
    int base = blockIdx.x * SC;
    int s = base + threadIdx.x * 4;
    int v0 = 0, v1 = 0, v2 = 0, v3 = 0;
    if (s + 0 < n) v0 = cnt[s + 0];
    if (s + 1 < n) v1 = cnt[s + 1];
    if (s + 2 < n) v2 = cnt[s + 2];
    if (s + 3 < n) v3 = cnt[s + 3];
    int sum = v0 + v1 + v2 + v3;
    t[threadIdx.x] = sum;
    __syncthreads();
    for (int off = 1; off < 256; off <<= 1) {
        int v = (threadIdx.x >= off) ? t[threadIdx.x - off] : 0;
        __syncthreads();
        t[threadIdx.x] += v;
        __syncthreads();
    }
    int run = boff[blockIdx.x] + ((threadIdx.x == 0) ? 0 : t[threadIdx.x - 1]);
    if (s + 0 < n) { rowptr[s + 0] = run; run += v0; }
    if (s + 1 < n) { rowptr[s + 1] = run; run += v1; }
    if (s + 2 < n) { rowptr[s + 2] = run; run += v2; }
    if (s + 3 < n) { rowptr[s + 3] = run; run += v3; }
    if (blockIdx.x == 0 && threadIdx.x == 0) rowptr[n] = nE;
}

// ---------------- phase 1: bin edges into 256-node buckets, chunk-local, coalesced out ----------------
__global__ __launch_bounds__(256) void bin_kernel(const int* __restrict__ src,
                                                  const int* __restrict__ dst,
                                                  long long* __restrict__ recs_out,
                                                  int2* __restrict__ cando, int nE) {
    __shared__ int cnt[512];
    __shared__ int ssum[256];
    __shared__ long long recs[CHSZ];
    int c = blockIdx.x;
    int t = threadIdx.x;
    cnt[t] = 0; cnt[t + 256] = 0;
    __syncthreads();
    int e0 = c * CHSZ;
    int nv = nE - e0; if (nv > CHSZ) nv = CHSZ;
    int s8[8], d8[8];
    #pragma unroll
    for (int i = 0; i < 8; i++) {
        int li = t + i * 256;
        bool ok = li < nv;
        s8[i] = ok ? src[e0 + li] : -1;
        d8[i] = ok ? dst[e0 + li] : -1;
        if (ok) atomicAdd(&cnt[d8[i] >> 8], 1);
    }
    __syncthreads();
    int a = cnt[2 * t], b_ = cnt[2 * t + 1];
    ssum[t] = a + b_;
    __syncthreads();
    for (int off = 1; off < 256; off <<= 1) {       // Hillis-Steele inclusive over 256 pair-sums
        int v = (t >= off) ? ssum[t - off] : 0;
        __syncthreads();
        ssum[t] += v;
        __syncthreads();
    }
    int excl = ssum[t] - (a + b_);
    if (2 * t < NBKT)     cando[(size_t)c * NBKT + 2 * t]     = make_int2(a, excl);
    if (2 * t + 1 < NBKT) cando[(size_t)c * NBKT + 2 * t + 1] = make_int2(b_, excl + a);
    __syncthreads();
    cnt[2 * t] = excl; cnt[2 * t + 1] = excl + a;    // reuse as cursors
    __syncthreads();
    #pragma unroll
    for (int i = 0; i < 8; i++) {
        if (d8[i] >= 0) {
            int pos = atomicAdd(&cnt[d8[i] >> 8], 1);
            recs[pos] = ((long long)d8[i] << 32) | (unsigned)s8[i];
        }
    }
    __syncthreads();
    for (int j = t; j < nv; j += 256)
        recs_out[(size_t)e0 + j] = recs[j];          // fully coalesced 8B stores
}

// ---------------- per-bucket degree count: LDS histogram, coalesced out (no global atomics) ----------------
__global__ __launch_bounds__(512) void bucket_count_kernel(const long long* __restrict__ recs_bin,
                                                           const int2* __restrict__ cando,
                                                           int* __restrict__ cnt, int nch, int n) {
    __shared__ int c256[256];
    int b = blockIdx.x;
    int t = threadIdx.x;
    if (t < 256) c256[t] = 0;
    __syncthreads();
    for (int c = t; c < nch; c += 512) {
        int2 co = cando[(size_t)c * NBKT + b];
        size_t base = (size_t)c * CHSZ + co.y;
        for (int k = 0; k < co.x; ++k) {
            long long rec = recs_bin[base + k];
            int d = (int)(rec >> 32);
            atomicAdd(&c256[d & 255], 1);
        }
    }
    __syncthreads();
    int node = (b << 8) + t;
    if (t < 256 && node < n) cnt[node] = c256[t];
}

// ---------------- phase 2: per-bucket fill of final CSR (L2-compact scatter region) ----------------
__global__ __launch_bounds__(512) void bucket_fill_kernel(const long long* __restrict__ recs_bin,
                                                          const int2* __restrict__ cando,
                                                          const int* __restrict__ rowptr,
                                                          const float* __restrict__ dinv,
                                                          long long* __restrict__ csr_rec,
                                                          int nch, int n) {
    __shared__ int cur[256];
    int b = blockIdx.x;
    int node0 = b << 8;
    int t = threadIdx.x;
    if (t < 256) {
        int nd = node0 + t;
        cur[t] = (nd < n) ? rowptr[nd] : 0;
    }
    __syncthreads();
    for (int c = t; c < nch; c += 512) {
        int2 co = cando[(size_t)c * NBKT + b];
        size_t base = (size_t)c * CHSZ + co.y;
        for (int k = 0; k < co.x; ++k) {
            long long rec = recs_bin[base + k];
            int d = (int)(rec >> 32);
            int s = (int)(unsigned)(rec & 0xffffffffLL);
            float w = dinv[s] * dinv[d];
            int pos = atomicAdd(&cur[d & 255], 1);
            csr_rec[pos] = ((long long)__float_as_int(w) << 32) | (unsigned)s;
        }
    }
}

// ---------------- weight prep: pack W (f32 row-major 128x128) into B-fragment-linear bf16 ----------------
__global__ __launch_bounds__(256) void wprep_kernel(const float* __restrict__ W1,
                                                    const float* __restrict__ W2,
                                                    const float* __restrict__ W3,
                                                    unsigned short* __restrict__ Wf) {
    int gid = blockIdx.x * 256 + threadIdx.x;   // 0..49151
    int w = gid >> 14;
    int o = gid & 16383;
    int j = o & 7, lane = (o >> 3) & 63, ct = (o >> 9) & 7, kt = o >> 12;
    int rk = kt * 32 + (lane >> 4) * 8 + j;
    int col = ct * 16 + (lane & 15);
    const float* W = (w == 0) ? W1 : ((w == 1) ? W2 : W3);
    Wf[gid] = f2b(W[rk * HIDF + col]);
}

// ---------------- MFMA GEMM: Hfp8 = f(X) @ W  (fp8 e4m3 table out) ----------------
template <typename T>
__global__ __launch_bounds__(256) void mfma_gemm_kernel(const T* __restrict__ X,
                                                        const unsigned short* __restrict__ Wfrag,
                                                        const float* __restrict__ bias,
                                                        unsigned char* __restrict__ Hfp8, int n) {
    __shared__ unsigned short wl[16384];   // 32 KB: full 128x128 bf16 W in fragment-linear layout
    {
        const uint4* wsrc = reinterpret_cast<const uint4*>(Wfrag);
        uint4* wdst = reinterpret_cast<uint4*>(wl);
        for (int i = threadIdx.x; i < 2048; i += 256) wdst[i] = wsrc[i];
    }
    __syncthreads();

    int wv = threadIdx.x >> 6;          // wave 0..3
    int l  = threadIdx.x & 63;          // lane
    int row = blockIdx.x * 64 + wv * 16 + (l & 15);
    int koff = (l >> 4) * 8;
    bool rowok = row < n;

    f32x4 acc[8] = {};
    #pragma unroll
    for (int kt = 0; kt < 4; ++kt) {
        int kbase = kt * 32 + koff;
        bf16x8 a;
        if constexpr (sizeof(T) == 4) {          // f32 input (layer 1, no bias)
            float4 x0 = {0,0,0,0}, x1 = {0,0,0,0};
            if (rowok) {
                x0 = *reinterpret_cast<const float4*>(&X[(size_t)row * HIDF + kbase]);
                x1 = *reinterpret_cast<const float4*>(&X[(size_t)row * HIDF + kbase + 4]);
            }
            a[0] = (short)f2b(x0.x); a[1] = (short)f2b(x0.y);
            a[2] = (short)f2b(x0.z); a[3] = (short)f2b(x0.w);
            a[4] = (short)f2b(x1.x); a[5] = (short)f2b(x1.y);
            a[6] = (short)f2b(x1.z); a[7] = (short)f2b(x1.w);
        } else {                                  // bf16 input (layers 2,3; +bias,relu)
            uint4 raw = {0,0,0,0};
            if (rowok) raw = *reinterpret_cast<const uint4*>(&X[(size_t)row * HIDF + kbase]);
            unsigned short* ru = reinterpret_cast<unsigned short*>(&raw);
            if (bias) {
                #pragma unroll
                for (int j = 0; j < 8; ++j) {
                    float v = b2f(ru[j]) + bias[kbase + j];
                    ru[j] = f2b(fmaxf(v, 0.f));
                }
            }
            a = *reinterpret_cast<bf16x8*>(&raw);
        }
        #pragma unroll
        for (int ct = 0; ct < 8; ++ct) {
            bf16x8 b = *reinterpret_cast<bf16x8*>(&wl[((kt * 8 + ct) * 64 + l) * 8]);
            acc[ct] = __builtin_amdgcn_mfma_f32_16x16x32_bf16(a, b, acc[ct], 0, 0, 0);
        }
    }
    int rbase = blockIdx.x * 64 + wv * 16 + ((l >> 4) << 2);
    int cbase = l & 15;
    #pragma unroll
    for (int ct = 0; ct < 8; ++ct) {
        #pragma unroll
        for (int r = 0; r < 4; ++r) {
            int gr = rbase + r;
            if (gr < n) Hfp8[(size_t)gr * HIDF + ct * 16 + cbase] = f2fp8(acc[ct][r]);
        }
    }
}

// ---------------- gather aggregation over fp8 table (f32 acc, bf16 out) ----------------
__global__ __launch_bounds__(256) void gather_agg_kernel(const unsigned char* __restrict__ Hin,
                                                         const int* __restrict__ rowptr,
                                                         const long long* __restrict__ csr_rec,
                                                         const float* __restrict__ selfw,
                                                         unsigned short* __restrict__ Hout, int n) {
    int node = blockIdx.x * 8 + (threadIdx.x >> 5);
    if (node >= n) return;
    int lane = threadIdx.x & 31;
    unsigned sw32 = *reinterpret_cast<const unsigned*>(&Hin[(size_t)node * HIDF + lane * 4]);
    float sw = selfw[node];
    f32x2 slo = __builtin_amdgcn_cvt_pk_f32_fp8((int)sw32, false);
    f32x2 shi = __builtin_amdgcn_cvt_pk_f32_fp8((int)sw32, true);
    float4 acc;
    acc.x = slo[0] * sw; acc.y = slo[1] * sw;
    acc.z = shi[0] * sw; acc.w = shi[1] * sw;
    int beg = rowptr[node], end = rowptr[node + 1];
    for (int base = beg; base < end; base += 32) {
        int m = end - base; if (m > 32) m = 32;
        long long rec = 0;
        if (base + lane < end) rec = csr_rec[base + lane];   // one coalesced 8B/lane load
        #pragma unroll 4
        for (int j = 0; j < m; ++j) {
            long long r = __shfl(rec, j, 32);                // register broadcast, no cache hop
            int sn = (int)(unsigned)(r & 0xffffffffLL);
            float w = __int_as_float((int)(r >> 32));
            unsigned v32 = *reinterpret_cast<const unsigned*>(&Hin[(size_t)sn * HIDF + lane * 4]);
            f32x2 lo = __builtin_amdgcn_cvt_pk_f32_fp8((int)v32, false);
            f32x2 hi = __builtin_amdgcn_cvt_pk_f32_fp8((int)v32, true);
            acc.x += lo[0] * w; acc.y += lo[1] * w;
            acc.z += hi[0] * w; acc.w += hi[1] * w;
        }
    }
    ushort4 o;
    o.x = f2b(acc.x); o.y = f2b(acc.y); o.z = f2b(acc.z); o.w = f2b(acc.w);
    *reinterpret_cast<ushort4*>(&Hout[(size_t)node * HIDF + lane * 4]) = o;
}

// ---------------- mean pool: 8 row-groups x 32 lanes, coalesced ushort4 loads ----------------
__device__ __forceinline__ int lower_bound_i(const int* __restrict__ a, int n, int key) {
    int lo = 0, hi = n;
    while (lo < hi) { int mid = (lo + hi) >> 1; if (a[mid] < key) lo = mid + 1; else hi = mid; }
    return lo;
}

__global__ __launch_bounds__(256) void pool_kernel(const unsigned short* __restrict__ H,
                                                   const int* __restrict__ batch,
                                                   const float* __restrict__ b3,
                                                   float* __restrict__ gmean, int n) {
    __shared__ float part[8][HIDF];
    int b = blockIdx.x;
    int g = threadIdx.x >> 5;       // row group 0..7
    int lane = threadIdx.x & 31;    // feature quad: 4*lane .. 4*lane+3
    int s = lower_bound_i(batch, n, b);
    int e = lower_bound_i(batch, n, b + 1);
    float4 acc = {0.f, 0.f, 0.f, 0.f};
    for (int i = s + g; i < e; i += 8) {
        ushort4 v = *reinterpret_cast<const ushort4*>(&H[(size_t)i * HIDF + lane * 4]);
        acc.x += b2f(v.x); acc.y += b2f(v.y);
        acc.z += b2f(v.z); acc.w += b2f(v.w);
    }
    part[g][lane * 4 + 0] = acc.x;
    part[g][lane * 4 + 1] = acc.y;
    part[g][lane * 4 + 2] = acc.z;
    part[g][lane * 4 + 3] = acc.w;
    __syncthreads();
    if (threadIdx.x < HIDF) {
        int f = threadIdx.x;
        float sum = 0.f;
        #pragma unroll
        for (int gg = 0; gg < 8; ++gg) sum += part[gg][f];
        float cnt = fmaxf((float)(e - s), 1.0f);
        gmean[b * HIDF + f] = sum / cnt + b3[f];
    }
}

// ---------------- centroid head: one wave per graph ----------------
__global__ __launch_bounds__(64) void final_kernel(const float* __restrict__ gmean,
                                                   const float* __restrict__ centroids,
                                                   const float* __restrict__ std_scale,
                                                   const float* __restrict__ ac_temp,
                                                   float* __restrict__ out) {
    int b = blockIdx.x;
    int lane = threadIdx.x;
    float g0 = gmean[b * HIDF + lane];
    float g1 = gmean[b * HIDF + 64 + lane];
    float mind = 1e30f;
    for (int c = 0; c < NCLS; ++c) {
        float dd[2];
        #pragma unroll
        for (int cent = 0; cent < 2; ++cent) {
            const float* cp = &centroids[(c * 2 + cent) * HIDF];
            float df0 = cp[lane] - g0;
            float df1 = cp[64 + lane] - g1;
            float p = df0 * df0 + df1 * df1;
            #pragma unroll
            for (int off = 32; off > 0; off >>= 1) p += __shfl_xor(p, off);
            dd[cent] = p;
        }
        float dist = fminf(sqrtf(dd[0]), sqrtf(dd[1]));
        mind = fminf(mind, dist);
        if (lane == 0) out[b * NCLS + c] = -dist;
    }
    if (lane == 0) {
        float ss = std_scale[0];
        float clipped = fminf(fmaxf(ss, 0.0f), 5.0f);
        float max_ac = 1.0f + clipped * 0.0f;      // RUNNING_MEAN=1, sqrt(RUNNING_VAR)=0
        float accept = max_ac - mind;
        float soft = 1.0f / (1.0f + expf(-accept / ac_temp[0]));
        out[NGR * NCLS + b] = soft;
    }
}

// ---------------- launch ----------------
extern "C" void kernel_launch(void* const* d_in, const int* in_sizes, int n_in,
                              void* d_out, int out_size, void* d_ws, size_t ws_size,
                              hipStream_t stream) {
    const float* x         = (const float*)d_in[0];
    const int*   edge      = (const int*)d_in[1];
    const int*   batch     = (const int*)d_in[2];
    const float* W1        = (const float*)d_in[3];
    const float* b1        = (const float*)d_in[4];
    const float* W2        = (const float*)d_in[5];
    const float* b2        = (const float*)d_in[6];
    const float* W3        = (const float*)d_in[7];
    const float* b3        = (const float*)d_in[8];
    const float* centroids = (const float*)d_in[9];
    const float* std_scale = (const float*)d_in[10];
    const float* ac_temp   = (const float*)d_in[11];
    float* out = (float*)d_out;

    const int n  = NN;
    const int nE = in_sizes[1] / 2;
    const int* srcp = edge;
    const int* dstp = edge + nE;
    const int nch = (nE + CHSZ - 1) / CHSZ;

    // workspace layout (256B aligned)
    char* ws = (char*)d_ws;
    size_t off = 0;
    auto alloc = [&](size_t bytes) { void* p = ws + off; off = (off + bytes + 255) & ~(size_t)255; return p; };
    unsigned char*  hA = (unsigned char*) alloc((size_t)NN * HIDF);      // fp8 GEMM output table
    unsigned short* hG = (unsigned short*)alloc((size_t)NN * HIDF * 2);  // bf16 gather output table
    unsigned short* Wf = (unsigned short*)alloc((size_t)3 * HIDF * HIDF * 2);
    float* dinv    = (float*)alloc((size_t)NN * 4);
    float* selfw   = (float*)alloc((size_t)NN * 4);
    int*   cnt     = (int*)  alloc((size_t)NN * 4);
    int*   rowptr  = (int*)  alloc((size_t)(NN + 1) * 4);
    long long* csr_rec  = (long long*)alloc((size_t)nE * 8);
    long long* recs_bin = (long long*)alloc((size_t)nE * 8);
    int2*  cando   = (int2*) alloc((size_t)nch * NBKT * 8);
    float* gmean   = (float*)alloc((size_t)NGR * HIDF * 4);
    int*   bsum    = (int*)  alloc((size_t)SB * 4);
    int*   boff    = (int*)  alloc((size_t)SB * 4);

    // ---- weight prep + CSR build (CSR reused by all 3 layers) ----
    wprep_kernel<<<192, 256, 0, stream>>>(W1, W2, W3, Wf);
    bin_kernel<<<nch, 256, 0, stream>>>(srcp, dstp, recs_bin, cando, nE);
    bucket_count_kernel<<<NBKT, 512, 0, stream>>>(recs_bin, cando, cnt, nch, n);
    block_sum_kernel<<<SB, 256, 0, stream>>>(cnt, bsum, n);
    scan_bsum_kernel<<<1, 128, 0, stream>>>(bsum, boff, SB);
    scan_fill_kernel<<<SB, 256, 0, stream>>>(cnt, boff, rowptr, n, nE);
    node_prep_kernel<<<(n + 255) / 256, 256, 0, stream>>>(cnt, dinv, selfw, n);
    bucket_fill_kernel<<<NBKT, 512, 0, stream>>>(recs_bin, cando, rowptr, dinv, csr_rec, nch, n);

    int gemm_blocks   = (n + 63) / 64;
    int gather_blocks = (n + 7) / 8;

    // layer 1: x f32 -> hA (fp8); gather -> hG (bf16)
    mfma_gemm_kernel<float><<<gemm_blocks, 256, 0, stream>>>(x, Wf, nullptr, hA, n);
    gather_agg_kernel<<<gather_blocks, 256, 0, stream>>>(hA, rowptr, csr_rec, selfw, hG, n);
    // layer 2: (+b1, relu) fused into A-load
    mfma_gemm_kernel<unsigned short><<<gemm_blocks, 256, 0, stream>>>(hG, Wf + 16384, b1, hA, n);
    gather_agg_kernel<<<gather_blocks, 256, 0, stream>>>(hA, rowptr, csr_rec, selfw, hG, n);
    // layer 3: (+b2, relu)
    mfma_gemm_kernel<unsigned short><<<gemm_blocks, 256, 0, stream>>>(hG, Wf + 32768, b2, hA, n);
    gather_agg_kernel<<<gather_blocks, 256, 0, stream>>>(hA, rowptr, csr_rec, selfw, hG, n);

    // mean pool (+b3 folded) — batch is sorted, no atomics
    pool_kernel<<<NGR, 256, 0, stream>>>(hG, batch, b3, gmean, n);
    final_kernel<<<NGR, 64, 0, stream>>>(gmean, centroids, std_scale, ac_temp, out);
}

// Round 11
// 265.383 us; speedup vs baseline: 32.4806x; 1.2343x over previous
//
#include <hip/hip_runtime.h>
#include <hip/hip_bf16.h>
#include <math.h>

#define NN 100000
#define NEDGE 1600000
#define HIDF 128
#define NCLS 18
#define NGR 512
#define SC 1024                       // elements per scan chunk
#define SB ((NN + SC - 1) / SC)       // 98 scan blocks
#define CHSZ 2048                     // edges per bin chunk
#define NBKT 391                      // ceil(NN/256) buckets of 256 nodes

using bf16x8  = __attribute__((ext_vector_type(8))) short;   // 8 bf16 in 4 VGPRs
using ushort8 = __attribute__((ext_vector_type(8))) unsigned short;
using f32x4   = __attribute__((ext_vector_type(4))) float;
using f32x2   = __attribute__((ext_vector_type(2))) float;

__device__ __forceinline__ float b2f(unsigned short u) {
    return __uint_as_float(((unsigned)u) << 16);
}
__device__ __forceinline__ unsigned short f2b(float f) {   // round-to-nearest-even
    unsigned u = __float_as_uint(f);
    unsigned r = (u + 0x7fffu + ((u >> 16) & 1u)) >> 16;
    return (unsigned short)r;
}
__device__ __forceinline__ unsigned char f2fp8(float f) {  // f32 -> OCP e4m3 (HW cvt)
    int p = __builtin_amdgcn_cvt_pk_fp8_f32(f, f, 0, false);
    return (unsigned char)(p & 0xff);
}

__global__ void node_prep_kernel(const int* __restrict__ cnt, float* __restrict__ dinv,
                                 float* __restrict__ selfw, int n) {
    int i = blockIdx.x * blockDim.x + threadIdx.x;
    if (i < n) {
        float deg = (float)cnt[i] + 1.0f;   // +1 self loop
        dinv[i]  = rsqrtf(deg);
        selfw[i] = 1.0f / deg;
    }
}

// ---------------- device-wide exclusive scan: 3 phases ----------------
__global__ __launch_bounds__(256) void block_sum_kernel(const int* __restrict__ cnt,
                                                        int* __restrict__ bsum, int n) {
    int base = blockIdx.x * SC;
    int sum = 0;
    for (int i = threadIdx.x; i < SC; i += 256) {
        int idx = base + i;
        if (idx < n) sum += cnt[idx];
    }
    #pragma unroll
    for (int off = 32; off > 0; off >>= 1) sum += __shfl_down(sum, off);
    __shared__ int wsum[4];
    if ((threadIdx.x & 63) == 0) wsum[threadIdx.x >> 6] = sum;
    __syncthreads();
    if (threadIdx.x == 0) bsum[blockIdx.x] = wsum[0] + wsum[1] + wsum[2] + wsum[3];
}

__global__ __launch_bounds__(128) void scan_bsum_kernel(const int* __restrict__ bsum,
                                                        int* __restrict__ boff, int nb) {
    __shared__ int t[128];
    int tid = threadIdx.x;
    t[tid] = (tid < nb) ? bsum[tid] : 0;
    __syncthreads();
    for (int off = 1; off < 128; off <<= 1) {
        int v = (tid >= off) ? t[tid - off] : 0;
        __syncthreads();
        t[tid] += v;
        __syncthreads();
    }
    if (tid < nb) boff[tid] = (tid == 0) ? 0 : t[tid - 1];
}

__global__ __launch_bounds__(256) void scan_fill_kernel(const int* __restrict__ cnt,
                                                        const int* __restrict__ boff,
                                                        int* __restrict__ rowptr, int n, int nE) {
    __shared__ int t[256];
    int base = blockIdx.x * SC;
    int s = base + threadIdx.x * 4;
    int v0 = 0, v1 = 0, v2 = 0, v3 = 0;
    if (s + 0 < n) v0 = cnt[s + 0];
    if (s + 1 < n) v1 = cnt[s + 1];
    if (s + 2 < n) v2 = cnt[s + 2];
    if (s + 3 < n) v3 = cnt[s + 3];
    int sum = v0 + v1 + v2 + v3;
    t[threadIdx.x] = sum;
    __syncthreads();
    for (int off = 1; off < 256; off <<= 1) {
        int v = (threadIdx.x >= off) ? t[threadIdx.x - off] : 0;
        __syncthreads();
        t[threadIdx.x] += v;
        __syncthreads();
    }
    int run = boff[blockIdx.x] + ((threadIdx.x == 0) ? 0 : t[threadIdx.x - 1]);
    if (s + 0 < n) { rowptr[s + 0] = run; run += v0; }
    if (s + 1 < n) { rowptr[s + 1] = run; run += v1; }
    if (s + 2 < n) { rowptr[s + 2] = run; run += v2; }
    if (s + 3 < n) { rowptr[s + 3] = run; run += v3; }
    if (blockIdx.x == 0 && threadIdx.x == 0) rowptr[n] = nE;
}

// ---------------- phase 1: bin edges into 256-node buckets, chunk-local, coalesced out ----------------
__global__ __launch_bounds__(256) void bin_kernel(const int* __restrict__ src,
                                                  const int* __restrict__ dst,
                                                  long long* __restrict__ recs_out,
                                                  int2* __restrict__ cando, int nE) {
    __shared__ int cnt[512];
    __shared__ int ssum[256];
    __shared__ long long recs[CHSZ];
    int c = blockIdx.x;
    int t = threadIdx.x;
    cnt[t] = 0; cnt[t + 256] = 0;
    __syncthreads();
    int e0 = c * CHSZ;
    int nv = nE - e0; if (nv > CHSZ) nv = CHSZ;
    int s8[8], d8[8];
    #pragma unroll
    for (int i = 0; i < 8; i++) {
        int li = t + i * 256;
        bool ok = li < nv;
        s8[i] = ok ? src[e0 + li] : -1;
        d8[i] = ok ? dst[e0 + li] : -1;
        if (ok) atomicAdd(&cnt[d8[i] >> 8], 1);
    }
    __syncthreads();
    int a = cnt[2 * t], b_ = cnt[2 * t + 1];
    ssum[t] = a + b_;
    __syncthreads();
    for (int off = 1; off < 256; off <<= 1) {       // Hillis-Steele inclusive over 256 pair-sums
        int v = (t >= off) ? ssum[t - off] : 0;
        __syncthreads();
        ssum[t] += v;
        __syncthreads();
    }
    int excl = ssum[t] - (a + b_);
    if (2 * t < NBKT)     cando[(size_t)c * NBKT + 2 * t]     = make_int2(a, excl);
    if (2 * t + 1 < NBKT) cando[(size_t)c * NBKT + 2 * t + 1] = make_int2(b_, excl + a);
    __syncthreads();
    cnt[2 * t] = excl; cnt[2 * t + 1] = excl + a;    // reuse as cursors
    __syncthreads();
    #pragma unroll
    for (int i = 0; i < 8; i++) {
        if (d8[i] >= 0) {
            int pos = atomicAdd(&cnt[d8[i] >> 8], 1);
            recs[pos] = ((long long)d8[i] << 32) | (unsigned)s8[i];
        }
    }
    __syncthreads();
    for (int j = t; j < nv; j += 256)
        recs_out[(size_t)e0 + j] = recs[j];          // fully coalesced 8B stores
}

// ---------------- per-bucket degree count: LDS histogram, coalesced out (no global atomics) ----------------
__global__ __launch_bounds__(512) void bucket_count_kernel(const long long* __restrict__ recs_bin,
                                                           const int2* __restrict__ cando,
                                                           int* __restrict__ cnt, int nch, int n) {
    __shared__ int c256[256];
    int b = blockIdx.x;
    int t = threadIdx.x;
    if (t < 256) c256[t] = 0;
    __syncthreads();
    for (int c = t; c < nch; c += 512) {
        int2 co = cando[(size_t)c * NBKT + b];
        size_t base = (size_t)c * CHSZ + co.y;
        for (int k = 0; k < co.x; ++k) {
            long long rec = recs_bin[base + k];
            int d = (int)(rec >> 32);
            atomicAdd(&c256[d & 255], 1);
        }
    }
    __syncthreads();
    int node = (b << 8) + t;
    if (t < 256 && node < n) cnt[node] = c256[t];
}

// ---------------- phase 2: per-bucket fill of final CSR (L2-compact scatter region) ----------------
__global__ __launch_bounds__(512) void bucket_fill_kernel(const long long* __restrict__ recs_bin,
                                                          const int2* __restrict__ cando,
                                                          const int* __restrict__ rowptr,
                                                          const float* __restrict__ dinv,
                                                          long long* __restrict__ csr_rec,
                                                          int nch, int n) {
    __shared__ int cur[256];
    int b = blockIdx.x;
    int node0 = b << 8;
    int t = threadIdx.x;
    if (t < 256) {
        int nd = node0 + t;
        cur[t] = (nd < n) ? rowptr[nd] : 0;
    }
    __syncthreads();
    for (int c = t; c < nch; c += 512) {
        int2 co = cando[(size_t)c * NBKT + b];
        size_t base = (size_t)c * CHSZ + co.y;
        for (int k = 0; k < co.x; ++k) {
            long long rec = recs_bin[base + k];
            int d = (int)(rec >> 32);
            int s = (int)(unsigned)(rec & 0xffffffffLL);
            float w = dinv[s] * dinv[d];
            int pos = atomicAdd(&cur[d & 255], 1);
            csr_rec[pos] = ((long long)__float_as_int(w) << 32) | (unsigned)s;
        }
    }
}

// ---------------- weight prep: pack W (f32 row-major 128x128) into B-fragment-linear bf16 ----------------
__global__ __launch_bounds__(256) void wprep_kernel(const float* __restrict__ W1,
                                                    const float* __restrict__ W2,
                                                    const float* __restrict__ W3,
                                                    unsigned short* __restrict__ Wf) {
    int gid = blockIdx.x * 256 + threadIdx.x;   // 0..49151
    int w = gid >> 14;
    int o = gid & 16383;
    int j = o & 7, lane = (o >> 3) & 63, ct = (o >> 9) & 7, kt = o >> 12;
    int rk = kt * 32 + (lane >> 4) * 8 + j;
    int col = ct * 16 + (lane & 15);
    const float* W = (w == 0) ? W1 : ((w == 1) ? W2 : W3);
    Wf[gid] = f2b(W[rk * HIDF + col]);
}

// ---------------- MFMA GEMM: Hfp8 = f(X) @ W  (fp8 e4m3 table out) ----------------
template <typename T>
__global__ __launch_bounds__(256) void mfma_gemm_kernel(const T* __restrict__ X,
                                                        const unsigned short* __restrict__ Wfrag,
                                                        const float* __restrict__ bias,
                                                        unsigned char* __restrict__ Hfp8, int n) {
    __shared__ unsigned short wl[16384];   // 32 KB: full 128x128 bf16 W in fragment-linear layout
    {
        const uint4* wsrc = reinterpret_cast<const uint4*>(Wfrag);
        uint4* wdst = reinterpret_cast<uint4*>(wl);
        for (int i = threadIdx.x; i < 2048; i += 256) wdst[i] = wsrc[i];
    }
    __syncthreads();

    int wv = threadIdx.x >> 6;          // wave 0..3
    int l  = threadIdx.x & 63;          // lane
    int row = blockIdx.x * 64 + wv * 16 + (l & 15);
    int koff = (l >> 4) * 8;
    bool rowok = row < n;

    f32x4 acc[8] = {};
    #pragma unroll
    for (int kt = 0; kt < 4; ++kt) {
        int kbase = kt * 32 + koff;
        bf16x8 a;
        if constexpr (sizeof(T) == 4) {          // f32 input (layer 1, no bias)
            float4 x0 = {0,0,0,0}, x1 = {0,0,0,0};
            if (rowok) {
                x0 = *reinterpret_cast<const float4*>(&X[(size_t)row * HIDF + kbase]);
                x1 = *reinterpret_cast<const float4*>(&X[(size_t)row * HIDF + kbase + 4]);
            }
            a[0] = (short)f2b(x0.x); a[1] = (short)f2b(x0.y);
            a[2] = (short)f2b(x0.z); a[3] = (short)f2b(x0.w);
            a[4] = (short)f2b(x1.x); a[5] = (short)f2b(x1.y);
            a[6] = (short)f2b(x1.z); a[7] = (short)f2b(x1.w);
        } else {                                  // bf16 input (layers 2,3; +bias,relu)
            uint4 raw = {0,0,0,0};
            if (rowok) raw = *reinterpret_cast<const uint4*>(&X[(size_t)row * HIDF + kbase]);
            unsigned short* ru = reinterpret_cast<unsigned short*>(&raw);
            if (bias) {
                #pragma unroll
                for (int j = 0; j < 8; ++j) {
                    float v = b2f(ru[j]) + bias[kbase + j];
                    ru[j] = f2b(fmaxf(v, 0.f));
                }
            }
            a = *reinterpret_cast<bf16x8*>(&raw);
        }
        #pragma unroll
        for (int ct = 0; ct < 8; ++ct) {
            bf16x8 b = *reinterpret_cast<bf16x8*>(&wl[((kt * 8 + ct) * 64 + l) * 8]);
            acc[ct] = __builtin_amdgcn_mfma_f32_16x16x32_bf16(a, b, acc[ct], 0, 0, 0);
        }
    }
    int rbase = blockIdx.x * 64 + wv * 16 + ((l >> 4) << 2);
    int cbase = l & 15;
    #pragma unroll
    for (int ct = 0; ct < 8; ++ct) {
        #pragma unroll
        for (int r = 0; r < 4; ++r) {
            int gr = rbase + r;
            if (gr < n) Hfp8[(size_t)gr * HIDF + ct * 16 + cbase] = f2fp8(acc[ct][r]);
        }
    }
}

// ---------------- gather aggregation over fp8 table: 8-lane groups, 16B/lane rows ----------------
// 8 nodes per wave -> 8 independent row-gathers per load instruction (4x MLP vs 32-lane groups)
__global__ __launch_bounds__(256) void gather_agg_kernel(const unsigned char* __restrict__ Hin,
                                                         const int* __restrict__ rowptr,
                                                         const long long* __restrict__ csr_rec,
                                                         const float* __restrict__ selfw,
                                                         unsigned short* __restrict__ Hout, int n) {
    int node = blockIdx.x * 32 + (threadIdx.x >> 3);
    if (node >= n) return;
    int lane = threadIdx.x & 7;          // lane's row segment: fp8 features [lane*16, lane*16+16)
    float acc[16];
    {
        uint4 sv = *reinterpret_cast<const uint4*>(Hin + (size_t)node * HIDF + lane * 16);
        const unsigned* svw = reinterpret_cast<const unsigned*>(&sv);
        float sw = selfw[node];
        #pragma unroll
        for (int d = 0; d < 4; ++d) {
            f32x2 lo = __builtin_amdgcn_cvt_pk_f32_fp8((int)svw[d], false);
            f32x2 hi = __builtin_amdgcn_cvt_pk_f32_fp8((int)svw[d], true);
            acc[d * 4 + 0] = lo[0] * sw; acc[d * 4 + 1] = lo[1] * sw;
            acc[d * 4 + 2] = hi[0] * sw; acc[d * 4 + 3] = hi[1] * sw;
        }
    }
    int beg = rowptr[node], end = rowptr[node + 1];
    for (int base = beg; base < end; base += 8) {
        int m = end - base; if (m > 8) m = 8;
        long long rec = 0;
        if (base + lane < end) rec = csr_rec[base + lane];   // 64B coalesced per group
        #pragma unroll 4
        for (int j = 0; j < m; ++j) {
            long long r = __shfl(rec, j, 8);                 // broadcast within 8-lane group
            int sn = (int)(unsigned)(r & 0xffffffffLL);
            float w = __int_as_float((int)(r >> 32));
            uint4 v = *reinterpret_cast<const uint4*>(Hin + (size_t)sn * HIDF + lane * 16);
            const unsigned* vw = reinterpret_cast<const unsigned*>(&v);
            #pragma unroll
            for (int d = 0; d < 4; ++d) {
                f32x2 lo = __builtin_amdgcn_cvt_pk_f32_fp8((int)vw[d], false);
                f32x2 hi = __builtin_amdgcn_cvt_pk_f32_fp8((int)vw[d], true);
                acc[d * 4 + 0] += lo[0] * w; acc[d * 4 + 1] += lo[1] * w;
                acc[d * 4 + 2] += hi[0] * w; acc[d * 4 + 3] += hi[1] * w;
            }
        }
    }
    ushort8 o0, o1;
    #pragma unroll
    for (int i = 0; i < 8; ++i) o0[i] = f2b(acc[i]);
    #pragma unroll
    for (int i = 0; i < 8; ++i) o1[i] = f2b(acc[8 + i]);
    unsigned short* op = Hout + (size_t)node * HIDF + lane * 16;
    *reinterpret_cast<ushort8*>(op) = o0;
    *reinterpret_cast<ushort8*>(op + 8) = o1;
}

// ---------------- mean pool: 8 row-groups x 32 lanes, coalesced ushort4 loads ----------------
__device__ __forceinline__ int lower_bound_i(const int* __restrict__ a, int n, int key) {
    int lo = 0, hi = n;
    while (lo < hi) { int mid = (lo + hi) >> 1; if (a[mid] < key) lo = mid + 1; else hi = mid; }
    return lo;
}

__global__ __launch_bounds__(256) void pool_kernel(const unsigned short* __restrict__ H,
                                                   const int* __restrict__ batch,
                                                   const float* __restrict__ b3,
                                                   float* __restrict__ gmean, int n) {
    __shared__ float part[8][HIDF];
    int b = blockIdx.x;
    int g = threadIdx.x >> 5;       // row group 0..7
    int lane = threadIdx.x & 31;    // feature quad: 4*lane .. 4*lane+3
    int s = lower_bound_i(batch, n, b);
    int e = lower_bound_i(batch, n, b + 1);
    float4 acc = {0.f, 0.f, 0.f, 0.f};
    for (int i = s + g; i < e; i += 8) {
        ushort4 v = *reinterpret_cast<const ushort4*>(&H[(size_t)i * HIDF + lane * 4]);
        acc.x += b2f(v.x); acc.y += b2f(v.y);
        acc.z += b2f(v.z); acc.w += b2f(v.w);
    }
    part[g][lane * 4 + 0] = acc.x;
    part[g][lane * 4 + 1] = acc.y;
    part[g][lane * 4 + 2] = acc.z;
    part[g][lane * 4 + 3] = acc.w;
    __syncthreads();
    if (threadIdx.x < HIDF) {
        int f = threadIdx.x;
        float sum = 0.f;
        #pragma unroll
        for (int gg = 0; gg < 8; ++gg) sum += part[gg][f];
        float cnt = fmaxf((float)(e - s), 1.0f);
        gmean[b * HIDF + f] = sum / cnt + b3[f];
    }
}

// ---------------- centroid head: one wave per graph ----------------
__global__ __launch_bounds__(64) void final_kernel(const float* __restrict__ gmean,
                                                   const float* __restrict__ centroids,
                                                   const float* __restrict__ std_scale,
                                                   const float* __restrict__ ac_temp,
                                                   float* __restrict__ out) {
    int b = blockIdx.x;
    int lane = threadIdx.x;
    float g0 = gmean[b * HIDF + lane];
    float g1 = gmean[b * HIDF + 64 + lane];
    float mind = 1e30f;
    for (int c = 0; c < NCLS; ++c) {
        float dd[2];
        #pragma unroll
        for (int cent = 0; cent < 2; ++cent) {
            const float* cp = &centroids[(c * 2 + cent) * HIDF];
            float df0 = cp[lane] - g0;
            float df1 = cp[64 + lane] - g1;
            float p = df0 * df0 + df1 * df1;
            #pragma unroll
            for (int off = 32; off > 0; off >>= 1) p += __shfl_xor(p, off);
            dd[cent] = p;
        }
        float dist = fminf(sqrtf(dd[0]), sqrtf(dd[1]));
        mind = fminf(mind, dist);
        if (lane == 0) out[b * NCLS + c] = -dist;
    }
    if (lane == 0) {
        float ss = std_scale[0];
        float clipped = fminf(fmaxf(ss, 0.0f), 5.0f);
        float max_ac = 1.0f + clipped * 0.0f;      // RUNNING_MEAN=1, sqrt(RUNNING_VAR)=0
        float accept = max_ac - mind;
        float soft = 1.0f / (1.0f + expf(-accept / ac_temp[0]));
        out[NGR * NCLS + b] = soft;
    }
}

// ---------------- launch ----------------
extern "C" void kernel_launch(void* const* d_in, const int* in_sizes, int n_in,
                              void* d_out, int out_size, void* d_ws, size_t ws_size,
                              hipStream_t stream) {
    const float* x         = (const float*)d_in[0];
    const int*   edge      = (const int*)d_in[1];
    const int*   batch     = (const int*)d_in[2];
    const float* W1        = (const float*)d_in[3];
    const float* b1        = (const float*)d_in[4];
    const float* W2        = (const float*)d_in[5];
    const float* b2        = (const float*)d_in[6];
    const float* W3        = (const float*)d_in[7];
    const float* b3        = (const float*)d_in[8];
    const float* centroids = (const float*)d_in[9];
    const float* std_scale = (const float*)d_in[10];
    const float* ac_temp   = (const float*)d_in[11];
    float* out = (float*)d_out;

    const int n  = NN;
    const int nE = in_sizes[1] / 2;
    const int* srcp = edge;
    const int* dstp = edge + nE;
    const int nch = (nE + CHSZ - 1) / CHSZ;

    // workspace layout (256B aligned)
    char* ws = (char*)d_ws;
    size_t off = 0;
    auto alloc = [&](size_t bytes) { void* p = ws + off; off = (off + bytes + 255) & ~(size_t)255; return p; };
    unsigned char*  hA = (unsigned char*) alloc((size_t)NN * HIDF);      // fp8 GEMM output table
    unsigned short* hG = (unsigned short*)alloc((size_t)NN * HIDF * 2);  // bf16 gather output table
    unsigned short* Wf = (unsigned short*)alloc((size_t)3 * HIDF * HIDF * 2);
    float* dinv    = (float*)alloc((size_t)NN * 4);
    float* selfw   = (float*)alloc((size_t)NN * 4);
    int*   cnt     = (int*)  alloc((size_t)NN * 4);
    int*   rowptr  = (int*)  alloc((size_t)(NN + 1) * 4);
    long long* csr_rec  = (long long*)alloc((size_t)nE * 8);
    long long* recs_bin = (long long*)alloc((size_t)nE * 8);
    int2*  cando   = (int2*) alloc((size_t)nch * NBKT * 8);
    float* gmean   = (float*)alloc((size_t)NGR * HIDF * 4);
    int*   bsum    = (int*)  alloc((size_t)SB * 4);
    int*   boff    = (int*)  alloc((size_t)SB * 4);

    // ---- weight prep + CSR build (CSR reused by all 3 layers) ----
    wprep_kernel<<<192, 256, 0, stream>>>(W1, W2, W3, Wf);
    bin_kernel<<<nch, 256, 0, stream>>>(srcp, dstp, recs_bin, cando, nE);
    bucket_count_kernel<<<NBKT, 512, 0, stream>>>(recs_bin, cando, cnt, nch, n);
    block_sum_kernel<<<SB, 256, 0, stream>>>(cnt, bsum, n);
    scan_bsum_kernel<<<1, 128, 0, stream>>>(bsum, boff, SB);
    scan_fill_kernel<<<SB, 256, 0, stream>>>(cnt, boff, rowptr, n, nE);
    node_prep_kernel<<<(n + 255) / 256, 256, 0, stream>>>(cnt, dinv, selfw, n);
    bucket_fill_kernel<<<NBKT, 512, 0, stream>>>(recs_bin, cando, rowptr, dinv, csr_rec, nch, n);

    int gemm_blocks   = (n + 63) / 64;
    int gather_blocks = (n + 31) / 32;

    // layer 1: x f32 -> hA (fp8); gather -> hG (bf16)
    mfma_gemm_kernel<float><<<gemm_blocks, 256, 0, stream>>>(x, Wf, nullptr, hA, n);
    gather_agg_kernel<<<gather_blocks, 256, 0, stream>>>(hA, rowptr, csr_rec, selfw, hG, n);
    // layer 2: (+b1, relu) fused into A-load
    mfma_gemm_kernel<unsigned short><<<gemm_blocks, 256, 0, stream>>>(hG, Wf + 16384, b1, hA, n);
    gather_agg_kernel<<<gather_blocks, 256, 0, stream>>>(hA, rowptr, csr_rec, selfw, hG, n);
    // layer 3: (+b2, relu)
    mfma_gemm_kernel<unsigned short><<<gemm_blocks, 256, 0, stream>>>(hG, Wf + 32768, b2, hA, n);
    gather_agg_kernel<<<gather_blocks, 256, 0, stream>>>(hA, rowptr, csr_rec, selfw, hG, n);

    // mean pool (+b3 folded) — batch is sorted, no atomics
    pool_kernel<<<NGR, 256, 0, stream>>>(hG, batch, b3, gmean, n);
    final_kernel<<<NGR, 64, 0, stream>>>(gmean, centroids, std_scale, ac_temp, out);
}

// Round 12
// 259.927 us; speedup vs baseline: 33.1624x; 1.0210x over previous
//
#include <hip/hip_runtime.h>
#include <hip/hip_bf16.h>
#include <math.h>

#define NN 100000
#define NEDGE 1600000
#define HIDF 128
#define NCLS 18
#define NGR 512
#define SC 1024                       // elements per scan chunk
#define SB ((NN + SC - 1) / SC)       // 98 scan blocks
#define CHSZ 2048                     // edges per bin chunk
#define NBKT 391                      // ceil(NN/256) buckets of 256 nodes

using bf16x8  = __attribute__((ext_vector_type(8))) short;   // 8 bf16 in 4 VGPRs
using ushort8 = __attribute__((ext_vector_type(8))) unsigned short;
using f32x4   = __attribute__((ext_vector_type(4))) float;
using f32x2   = __attribute__((ext_vector_type(2))) float;

__device__ __forceinline__ float b2f(unsigned short u) {
    return __uint_as_float(((unsigned)u) << 16);
}
__device__ __forceinline__ unsigned short f2b(float f) {   // round-to-nearest-even
    unsigned u = __float_as_uint(f);
    unsigned r = (u + 0x7fffu + ((u >> 16) & 1u)) >> 16;
    return (unsigned short)r;
}
__device__ __forceinline__ unsigned char f2fp8(float f) {  // f32 -> OCP e4m3 (HW cvt)
    int p = __builtin_amdgcn_cvt_pk_fp8_f32(f, f, 0, false);
    return (unsigned char)(p & 0xff);
}

__global__ void node_prep_kernel(const int* __restrict__ cnt, float* __restrict__ dinv,
                                 float* __restrict__ selfw, int n) {
    int i = blockIdx.x * blockDim.x + threadIdx.x;
    if (i < n) {
        float deg = (float)cnt[i] + 1.0f;   // +1 self loop
        dinv[i]  = rsqrtf(deg);
        selfw[i] = 1.0f / deg;
    }
}

// ---------------- device-wide exclusive scan: 3 phases ----------------
__global__ __launch_bounds__(256) void block_sum_kernel(const int* __restrict__ cnt,
                                                        int* __restrict__ bsum, int n) {
    int base = blockIdx.x * SC;
    int sum = 0;
    for (int i = threadIdx.x; i < SC; i += 256) {
        int idx = base + i;
        if (idx < n) sum += cnt[idx];
    }
    #pragma unroll
    for (int off = 32; off > 0; off >>= 1) sum += __shfl_down(sum, off);
    __shared__ int wsum[4];
    if ((threadIdx.x & 63) == 0) wsum[threadIdx.x >> 6] = sum;
    __syncthreads();
    if (threadIdx.x == 0) bsum[blockIdx.x] = wsum[0] + wsum[1] + wsum[2] + wsum[3];
}

__global__ __launch_bounds__(128) void scan_bsum_kernel(const int* __restrict__ bsum,
                                                        int* __restrict__ boff, int nb) {
    __shared__ int t[128];
    int tid = threadIdx.x;
    t[tid] = (tid < nb) ? bsum[tid] : 0;
    __syncthreads();
    for (int off = 1; off < 128; off <<= 1) {
        int v = (tid >= off) ? t[tid - off] : 0;
        __syncthreads();
        t[tid] += v;
        __syncthreads();
    }
    if (tid < nb) boff[tid] = (tid == 0) ? 0 : t[tid - 1];
}

__global__ __launch_bounds__(256) void scan_fill_kernel(const int* __restrict__ cnt,
                                                        const int* __restrict__ boff,
                                                        int* __restrict__ rowptr, int n, int nE) {
    __shared__ int t[256];
    int base = blockIdx.x * SC;
    int s = base + threadIdx.x * 4;
    int v0 = 0, v1 = 0, v2 = 0, v3 = 0;
    if (s + 0 < n) v0 = cnt[s + 0];
    if (s + 1 < n) v1 = cnt[s + 1];
    if (s + 2 < n) v2 = cnt[s + 2];
    if (s + 3 < n) v3 = cnt[s + 3];
    int sum = v0 + v1 + v2 + v3;
    t[threadIdx.x] = sum;
    __syncthreads();
    for (int off = 1; off < 256; off <<= 1) {
        int v = (threadIdx.x >= off) ? t[threadIdx.x - off] : 0;
        __syncthreads();
        t[threadIdx.x] += v;
        __syncthreads();
    }
    int run = boff[blockIdx.x] + ((threadIdx.x == 0) ? 0 : t[threadIdx.x - 1]);
    if (s + 0 < n) { rowptr[s + 0] = run; run += v0; }
    if (s + 1 < n) { rowptr[s + 1] = run; run += v1; }
    if (s + 2 < n) { rowptr[s + 2] = run; run += v2; }
    if (s + 3 < n) { rowptr[s + 3] = run; run += v3; }
    if (blockIdx.x == 0 && threadIdx.x == 0) rowptr[n] = nE;
}

// ---------------- phase 1: bin edges into 256-node buckets, chunk-local, coalesced out ----------------
__global__ __launch_bounds__(256) void bin_kernel(const int* __restrict__ src,
                                                  const int* __restrict__ dst,
                                                  long long* __restrict__ recs_out,
                                                  int2* __restrict__ cando, int nE) {
    __shared__ int cnt[512];
    __shared__ int ssum[256];
    __shared__ long long recs[CHSZ];
    int c = blockIdx.x;
    int t = threadIdx.x;
    cnt[t] = 0; cnt[t + 256] = 0;
    __syncthreads();
    int e0 = c * CHSZ;
    int nv = nE - e0; if (nv > CHSZ) nv = CHSZ;
    int s8[8], d8[8];
    #pragma unroll
    for (int i = 0; i < 8; i++) {
        int li = t + i * 256;
        bool ok = li < nv;
        s8[i] = ok ? src[e0 + li] : -1;
        d8[i] = ok ? dst[e0 + li] : -1;
        if (ok) atomicAdd(&cnt[d8[i] >> 8], 1);
    }
    __syncthreads();
    int a = cnt[2 * t], b_ = cnt[2 * t + 1];
    ssum[t] = a + b_;
    __syncthreads();
    for (int off = 1; off < 256; off <<= 1) {       // Hillis-Steele inclusive over 256 pair-sums
        int v = (t >= off) ? ssum[t - off] : 0;
        __syncthreads();
        ssum[t] += v;
        __syncthreads();
    }
    int excl = ssum[t] - (a + b_);
    if (2 * t < NBKT)     cando[(size_t)c * NBKT + 2 * t]     = make_int2(a, excl);
    if (2 * t + 1 < NBKT) cando[(size_t)c * NBKT + 2 * t + 1] = make_int2(b_, excl + a);
    __syncthreads();
    cnt[2 * t] = excl; cnt[2 * t + 1] = excl + a;    // reuse as cursors
    __syncthreads();
    #pragma unroll
    for (int i = 0; i < 8; i++) {
        if (d8[i] >= 0) {
            int pos = atomicAdd(&cnt[d8[i] >> 8], 1);
            recs[pos] = ((long long)d8[i] << 32) | (unsigned)s8[i];
        }
    }
    __syncthreads();
    for (int j = t; j < nv; j += 256)
        recs_out[(size_t)e0 + j] = recs[j];          // fully coalesced 8B stores
}

// ---------------- per-bucket degree count: LDS histogram, coalesced out (no global atomics) ----------------
__global__ __launch_bounds__(512) void bucket_count_kernel(const long long* __restrict__ recs_bin,
                                                           const int2* __restrict__ cando,
                                                           int* __restrict__ cnt, int nch, int n) {
    __shared__ int c256[256];
    int b = blockIdx.x;
    int t = threadIdx.x;
    if (t < 256) c256[t] = 0;
    __syncthreads();
    for (int c = t; c < nch; c += 512) {
        int2 co = cando[(size_t)c * NBKT + b];
        size_t base = (size_t)c * CHSZ + co.y;
        for (int k = 0; k < co.x; ++k) {
            long long rec = recs_bin[base + k];
            int d = (int)(rec >> 32);
            atomicAdd(&c256[d & 255], 1);
        }
    }
    __syncthreads();
    int node = (b << 8) + t;
    if (t < 256 && node < n) cnt[node] = c256[t];
}

// ---------------- phase 2: per-bucket fill of final CSR (L2-compact scatter region) ----------------
__global__ __launch_bounds__(512) void bucket_fill_kernel(const long long* __restrict__ recs_bin,
                                                          const int2* __restrict__ cando,
                                                          const int* __restrict__ rowptr,
                                                          const float* __restrict__ dinv,
                                                          long long* __restrict__ csr_rec,
                                                          int nch, int n) {
    __shared__ int cur[256];
    int b = blockIdx.x;
    int node0 = b << 8;
    int t = threadIdx.x;
    if (t < 256) {
        int nd = node0 + t;
        cur[t] = (nd < n) ? rowptr[nd] : 0;
    }
    __syncthreads();
    for (int c = t; c < nch; c += 512) {
        int2 co = cando[(size_t)c * NBKT + b];
        size_t base = (size_t)c * CHSZ + co.y;
        for (int k = 0; k < co.x; ++k) {
            long long rec = recs_bin[base + k];
            int d = (int)(rec >> 32);
            int s = (int)(unsigned)(rec & 0xffffffffLL);
            float w = dinv[s] * dinv[d];
            int pos = atomicAdd(&cur[d & 255], 1);
            csr_rec[pos] = ((long long)__float_as_int(w) << 32) | (unsigned)s;
        }
    }
}

// ---------------- weight prep: pack W (f32 row-major 128x128) into B-fragment-linear bf16 ----------------
__global__ __launch_bounds__(256) void wprep_kernel(const float* __restrict__ W1,
                                                    const float* __restrict__ W2,
                                                    const float* __restrict__ W3,
                                                    unsigned short* __restrict__ Wf) {
    int gid = blockIdx.x * 256 + threadIdx.x;   // 0..49151
    int w = gid >> 14;
    int o = gid & 16383;
    int j = o & 7, lane = (o >> 3) & 63, ct = (o >> 9) & 7, kt = o >> 12;
    int rk = kt * 32 + (lane >> 4) * 8 + j;
    int col = ct * 16 + (lane & 15);
    const float* W = (w == 0) ? W1 : ((w == 1) ? W2 : W3);
    Wf[gid] = f2b(W[rk * HIDF + col]);
}

// ---------------- MFMA GEMM: Hfp8 = f(X) @ W  (fp8 e4m3 table out) ----------------
template <typename T>
__global__ __launch_bounds__(256) void mfma_gemm_kernel(const T* __restrict__ X,
                                                        const unsigned short* __restrict__ Wfrag,
                                                        const float* __restrict__ bias,
                                                        unsigned char* __restrict__ Hfp8, int n) {
    __shared__ unsigned short wl[16384];   // 32 KB: full 128x128 bf16 W in fragment-linear layout
    {
        const uint4* wsrc = reinterpret_cast<const uint4*>(Wfrag);
        uint4* wdst = reinterpret_cast<uint4*>(wl);
        for (int i = threadIdx.x; i < 2048; i += 256) wdst[i] = wsrc[i];
    }
    __syncthreads();

    int wv = threadIdx.x >> 6;          // wave 0..3
    int l  = threadIdx.x & 63;          // lane
    int row = blockIdx.x * 64 + wv * 16 + (l & 15);
    int koff = (l >> 4) * 8;
    bool rowok = row < n;

    f32x4 acc[8] = {};
    #pragma unroll
    for (int kt = 0; kt < 4; ++kt) {
        int kbase = kt * 32 + koff;
        bf16x8 a;
        if constexpr (sizeof(T) == 4) {          // f32 input (layer 1, no bias)
            float4 x0 = {0,0,0,0}, x1 = {0,0,0,0};
            if (rowok) {
                x0 = *reinterpret_cast<const float4*>(&X[(size_t)row * HIDF + kbase]);
                x1 = *reinterpret_cast<const float4*>(&X[(size_t)row * HIDF + kbase + 4]);
            }
            a[0] = (short)f2b(x0.x); a[1] = (short)f2b(x0.y);
            a[2] = (short)f2b(x0.z); a[3] = (short)f2b(x0.w);
            a[4] = (short)f2b(x1.x); a[5] = (short)f2b(x1.y);
            a[6] = (short)f2b(x1.z); a[7] = (short)f2b(x1.w);
        } else {                                  // bf16 input (layers 2,3; +bias,relu)
            uint4 raw = {0,0,0,0};
            if (rowok) raw = *reinterpret_cast<const uint4*>(&X[(size_t)row * HIDF + kbase]);
            unsigned short* ru = reinterpret_cast<unsigned short*>(&raw);
            if (bias) {
                #pragma unroll
                for (int j = 0; j < 8; ++j) {
                    float v = b2f(ru[j]) + bias[kbase + j];
                    ru[j] = f2b(fmaxf(v, 0.f));
                }
            }
            a = *reinterpret_cast<bf16x8*>(&raw);
        }
        #pragma unroll
        for (int ct = 0; ct < 8; ++ct) {
            bf16x8 b = *reinterpret_cast<bf16x8*>(&wl[((kt * 8 + ct) * 64 + l) * 8]);
            acc[ct] = __builtin_amdgcn_mfma_f32_16x16x32_bf16(a, b, acc[ct], 0, 0, 0);
        }
    }
    int rbase = blockIdx.x * 64 + wv * 16 + ((l >> 4) << 2);
    int cbase = l & 15;
    #pragma unroll
    for (int ct = 0; ct < 8; ++ct) {
        #pragma unroll
        for (int r = 0; r < 4; ++r) {
            int gr = rbase + r;
            if (gr < n) Hfp8[(size_t)gr * HIDF + ct * 16 + cbase] = f2fp8(acc[ct][r]);
        }
    }
}

// ---------------- gather aggregation over fp8 table: 8-lane groups, batched 8-row pipeline ----------------
// Full batches: 8 independent dwordx4 row loads issued back-to-back into v[8] (64 rows in
// flight per wave) before the convert/FMA chain consumes them. Summation order identical.
__global__ __launch_bounds__(256) void gather_agg_kernel(const unsigned char* __restrict__ Hin,
                                                         const int* __restrict__ rowptr,
                                                         const long long* __restrict__ csr_rec,
                                                         const float* __restrict__ selfw,
                                                         unsigned short* __restrict__ Hout, int n) {
    int node = blockIdx.x * 32 + (threadIdx.x >> 3);
    if (node >= n) return;
    int lane = threadIdx.x & 7;          // lane's row segment: fp8 features [lane*16, lane*16+16)
    float acc[16];
    {
        uint4 sv = *reinterpret_cast<const uint4*>(Hin + (size_t)node * HIDF + lane * 16);
        const unsigned* svw = reinterpret_cast<const unsigned*>(&sv);
        float sw = selfw[node];
        #pragma unroll
        for (int d = 0; d < 4; ++d) {
            f32x2 lo = __builtin_amdgcn_cvt_pk_f32_fp8((int)svw[d], false);
            f32x2 hi = __builtin_amdgcn_cvt_pk_f32_fp8((int)svw[d], true);
            acc[d * 4 + 0] = lo[0] * sw; acc[d * 4 + 1] = lo[1] * sw;
            acc[d * 4 + 2] = hi[0] * sw; acc[d * 4 + 3] = hi[1] * sw;
        }
    }
    int beg = rowptr[node], end = rowptr[node + 1];
    int nfull = (end - beg) >> 3;
    int base = beg;
    for (int fb = 0; fb < nfull; ++fb, base += 8) {
        long long rec = csr_rec[base + lane];            // 64B coalesced per group
        uint4 v[8];
        float w[8];
        #pragma unroll
        for (int j = 0; j < 8; ++j) {                    // issue 8 independent row loads
            long long r = __shfl(rec, j, 8);
            int sn = (int)(unsigned)(r & 0xffffffffLL);
            w[j] = __int_as_float((int)(r >> 32));
            v[j] = *reinterpret_cast<const uint4*>(Hin + (size_t)sn * HIDF + lane * 16);
        }
        #pragma unroll
        for (int j = 0; j < 8; ++j) {                    // consume
            const unsigned* vw = reinterpret_cast<const unsigned*>(&v[j]);
            #pragma unroll
            for (int d = 0; d < 4; ++d) {
                f32x2 lo = __builtin_amdgcn_cvt_pk_f32_fp8((int)vw[d], false);
                f32x2 hi = __builtin_amdgcn_cvt_pk_f32_fp8((int)vw[d], true);
                acc[d * 4 + 0] += lo[0] * w[j]; acc[d * 4 + 1] += lo[1] * w[j];
                acc[d * 4 + 2] += hi[0] * w[j]; acc[d * 4 + 3] += hi[1] * w[j];
            }
        }
    }
    int m = end - base;                                  // tail < 8
    if (m > 0) {
        long long rec = (base + lane < end) ? csr_rec[base + lane] : 0;
        for (int j = 0; j < m; ++j) {
            long long r = __shfl(rec, j, 8);
            int sn = (int)(unsigned)(r & 0xffffffffLL);
            float w = __int_as_float((int)(r >> 32));
            uint4 v = *reinterpret_cast<const uint4*>(Hin + (size_t)sn * HIDF + lane * 16);
            const unsigned* vw = reinterpret_cast<const unsigned*>(&v);
            #pragma unroll
            for (int d = 0; d < 4; ++d) {
                f32x2 lo = __builtin_amdgcn_cvt_pk_f32_fp8((int)vw[d], false);
                f32x2 hi = __builtin_amdgcn_cvt_pk_f32_fp8((int)vw[d], true);
                acc[d * 4 + 0] += lo[0] * w; acc[d * 4 + 1] += lo[1] * w;
                acc[d * 4 + 2] += hi[0] * w; acc[d * 4 + 3] += hi[1] * w;
            }
        }
    }
    ushort8 o0, o1;
    #pragma unroll
    for (int i = 0; i < 8; ++i) o0[i] = f2b(acc[i]);
    #pragma unroll
    for (int i = 0; i < 8; ++i) o1[i] = f2b(acc[8 + i]);
    unsigned short* op = Hout + (size_t)node * HIDF + lane * 16;
    *reinterpret_cast<ushort8*>(op) = o0;
    *reinterpret_cast<ushort8*>(op + 8) = o1;
}

// ---------------- mean pool: 8 row-groups x 32 lanes, coalesced ushort4 loads ----------------
__device__ __forceinline__ int lower_bound_i(const int* __restrict__ a, int n, int key) {
    int lo = 0, hi = n;
    while (lo < hi) { int mid = (lo + hi) >> 1; if (a[mid] < key) lo = mid + 1; else hi = mid; }
    return lo;
}

__global__ __launch_bounds__(256) void pool_kernel(const unsigned short* __restrict__ H,
                                                   const int* __restrict__ batch,
                                                   const float* __restrict__ b3,
                                                   float* __restrict__ gmean, int n) {
    __shared__ float part[8][HIDF];
    int b = blockIdx.x;
    int g = threadIdx.x >> 5;       // row group 0..7
    int lane = threadIdx.x & 31;    // feature quad: 4*lane .. 4*lane+3
    int s = lower_bound_i(batch, n, b);
    int e = lower_bound_i(batch, n, b + 1);
    float4 acc = {0.f, 0.f, 0.f, 0.f};
    for (int i = s + g; i < e; i += 8) {
        ushort4 v = *reinterpret_cast<const ushort4*>(&H[(size_t)i * HIDF + lane * 4]);
        acc.x += b2f(v.x); acc.y += b2f(v.y);
        acc.z += b2f(v.z); acc.w += b2f(v.w);
    }
    part[g][lane * 4 + 0] = acc.x;
    part[g][lane * 4 + 1] = acc.y;
    part[g][lane * 4 + 2] = acc.z;
    part[g][lane * 4 + 3] = acc.w;
    __syncthreads();
    if (threadIdx.x < HIDF) {
        int f = threadIdx.x;
        float sum = 0.f;
        #pragma unroll
        for (int gg = 0; gg < 8; ++gg) sum += part[gg][f];
        float cnt = fmaxf((float)(e - s), 1.0f);
        gmean[b * HIDF + f] = sum / cnt + b3[f];
    }
}

// ---------------- centroid head: one wave per graph ----------------
__global__ __launch_bounds__(64) void final_kernel(const float* __restrict__ gmean,
                                                   const float* __restrict__ centroids,
                                                   const float* __restrict__ std_scale,
                                                   const float* __restrict__ ac_temp,
                                                   float* __restrict__ out) {
    int b = blockIdx.x;
    int lane = threadIdx.x;
    float g0 = gmean[b * HIDF + lane];
    float g1 = gmean[b * HIDF + 64 + lane];
    float mind = 1e30f;
    for (int c = 0; c < NCLS; ++c) {
        float dd[2];
        #pragma unroll
        for (int cent = 0; cent < 2; ++cent) {
            const float* cp = &centroids[(c * 2 + cent) * HIDF];
            float df0 = cp[lane] - g0;
            float df1 = cp[64 + lane] - g1;
            float p = df0 * df0 + df1 * df1;
            #pragma unroll
            for (int off = 32; off > 0; off >>= 1) p += __shfl_xor(p, off);
            dd[cent] = p;
        }
        float dist = fminf(sqrtf(dd[0]), sqrtf(dd[1]));
        mind = fminf(mind, dist);
        if (lane == 0) out[b * NCLS + c] = -dist;
    }
    if (lane == 0) {
        float ss = std_scale[0];
        float clipped = fminf(fmaxf(ss, 0.0f), 5.0f);
        float max_ac = 1.0f + clipped * 0.0f;      // RUNNING_MEAN=1, sqrt(RUNNING_VAR)=0
        float accept = max_ac - mind;
        float soft = 1.0f / (1.0f + expf(-accept / ac_temp[0]));
        out[NGR * NCLS + b] = soft;
    }
}

// ---------------- launch ----------------
extern "C" void kernel_launch(void* const* d_in, const int* in_sizes, int n_in,
                              void* d_out, int out_size, void* d_ws, size_t ws_size,
                              hipStream_t stream) {
    const float* x         = (const float*)d_in[0];
    const int*   edge      = (const int*)d_in[1];
    const int*   batch     = (const int*)d_in[2];
    const float* W1        = (const float*)d_in[3];
    const float* b1        = (const float*)d_in[4];
    const float* W2        = (const float*)d_in[5];
    const float* b2        = (const float*)d_in[6];
    const float* W3        = (const float*)d_in[7];
    const float* b3        = (const float*)d_in[8];
    const float* centroids = (const float*)d_in[9];
    const float* std_scale = (const float*)d_in[10];
    const float* ac_temp   = (const float*)d_in[11];
    float* out = (float*)d_out;

    const int n  = NN;
    const int nE = in_sizes[1] / 2;
    const int* srcp = edge;
    const int* dstp = edge + nE;
    const int nch = (nE + CHSZ - 1) / CHSZ;

    // workspace layout (256B aligned)
    char* ws = (char*)d_ws;
    size_t off = 0;
    auto alloc = [&](size_t bytes) { void* p = ws + off; off = (off + bytes + 255) & ~(size_t)255; return p; };
    unsigned char*  hA = (unsigned char*) alloc((size_t)NN * HIDF);      // fp8 GEMM output table
    unsigned short* hG = (unsigned short*)alloc((size_t)NN * HIDF * 2);  // bf16 gather output table
    unsigned short* Wf = (unsigned short*)alloc((size_t)3 * HIDF * HIDF * 2);
    float* dinv    = (float*)alloc((size_t)NN * 4);
    float* selfw   = (float*)alloc((size_t)NN * 4);
    int*   cnt     = (int*)  alloc((size_t)NN * 4);
    int*   rowptr  = (int*)  alloc((size_t)(NN + 1) * 4);
    long long* csr_rec  = (long long*)alloc((size_t)nE * 8);
    long long* recs_bin = (long long*)alloc((size_t)nE * 8);
    int2*  cando   = (int2*) alloc((size_t)nch * NBKT * 8);
    float* gmean   = (float*)alloc((size_t)NGR * HIDF * 4);
    int*   bsum    = (int*)  alloc((size_t)SB * 4);
    int*   boff    = (int*)  alloc((size_t)SB * 4);

    // ---- weight prep + CSR build (CSR reused by all 3 layers) ----
    wprep_kernel<<<192, 256, 0, stream>>>(W1, W2, W3, Wf);
    bin_kernel<<<nch, 256, 0, stream>>>(srcp, dstp, recs_bin, cando, nE);
    bucket_count_kernel<<<NBKT, 512, 0, stream>>>(recs_bin, cando, cnt, nch, n);
    block_sum_kernel<<<SB, 256, 0, stream>>>(cnt, bsum, n);
    scan_bsum_kernel<<<1, 128, 0, stream>>>(bsum, boff, SB);
    scan_fill_kernel<<<SB, 256, 0, stream>>>(cnt, boff, rowptr, n, nE);
    node_prep_kernel<<<(n + 255) / 256, 256, 0, stream>>>(cnt, dinv, selfw, n);
    bucket_fill_kernel<<<NBKT, 512, 0, stream>>>(recs_bin, cando, rowptr, dinv, csr_rec, nch, n);

    int gemm_blocks   = (n + 63) / 64;
    int gather_blocks = (n + 31) / 32;

    // layer 1: x f32 -> hA (fp8); gather -> hG (bf16)
    mfma_gemm_kernel<float><<<gemm_blocks, 256, 0, stream>>>(x, Wf, nullptr, hA, n);
    gather_agg_kernel<<<gather_blocks, 256, 0, stream>>>(hA, rowptr, csr_rec, selfw, hG, n);
    // layer 2: (+b1, relu) fused into A-load
    mfma_gemm_kernel<unsigned short><<<gemm_blocks, 256, 0, stream>>>(hG, Wf + 16384, b1, hA, n);
    gather_agg_kernel<<<gather_blocks, 256, 0, stream>>>(hA, rowptr, csr_rec, selfw, hG, n);
    // layer 3: (+b2, relu)
    mfma_gemm_kernel<unsigned short><<<gemm_blocks, 256, 0, stream>>>(hG, Wf + 32768, b2, hA, n);
    gather_agg_kernel<<<gather_blocks, 256, 0, stream>>>(hA, rowptr, csr_rec, selfw, hG, n);

    // mean pool (+b3 folded) — batch is sorted, no atomics
    pool_kernel<<<NGR, 256, 0, stream>>>(hG, batch, b3, gmean, n);
    final_kernel<<<NGR, 64, 0, stream>>>(gmean, centroids, std_scale, ac_temp, out);
}

// Round 13
// 250.350 us; speedup vs baseline: 34.4310x; 1.0383x over previous
//
#include <hip/hip_runtime.h>
#include <hip/hip_bf16.h>
#include <math.h>

#define NN 100000
#define NEDGE 1600000
#define HIDF 128
#define NCLS 18
#define NGR 512
#define CHSZ 2048                     // edges per bin chunk
#define NBKT 391                      // ceil(NN/256) buckets of 256 nodes

using bf16x8  = __attribute__((ext_vector_type(8))) short;   // 8 bf16 in 4 VGPRs
using ushort8 = __attribute__((ext_vector_type(8))) unsigned short;
using f32x4   = __attribute__((ext_vector_type(4))) float;
using f32x2   = __attribute__((ext_vector_type(2))) float;

__device__ __forceinline__ float b2f(unsigned short u) {
    return __uint_as_float(((unsigned)u) << 16);
}
__device__ __forceinline__ unsigned short f2b(float f) {   // round-to-nearest-even
    unsigned u = __float_as_uint(f);
    unsigned r = (u + 0x7fffu + ((u >> 16) & 1u)) >> 16;
    return (unsigned short)r;
}
__device__ __forceinline__ unsigned char f2fp8(float f) {  // f32 -> OCP e4m3 (HW cvt)
    int p = __builtin_amdgcn_cvt_pk_fp8_f32(f, f, 0, false);
    return (unsigned char)(p & 0xff);
}

// ---------------- phase 1: bin edges into 256-node buckets, chunk-local, coalesced out ----------------
__global__ __launch_bounds__(256) void bin_kernel(const int* __restrict__ src,
                                                  const int* __restrict__ dst,
                                                  long long* __restrict__ recs_out,
                                                  int2* __restrict__ cando, int nE) {
    __shared__ int cnt[512];
    __shared__ int ssum[256];
    __shared__ long long recs[CHSZ];
    int c = blockIdx.x;
    int t = threadIdx.x;
    cnt[t] = 0; cnt[t + 256] = 0;
    __syncthreads();
    int e0 = c * CHSZ;
    int nv = nE - e0; if (nv > CHSZ) nv = CHSZ;
    int s8[8], d8[8];
    #pragma unroll
    for (int i = 0; i < 8; i++) {
        int li = t + i * 256;
        bool ok = li < nv;
        s8[i] = ok ? src[e0 + li] : -1;
        d8[i] = ok ? dst[e0 + li] : -1;
        if (ok) atomicAdd(&cnt[d8[i] >> 8], 1);
    }
    __syncthreads();
    int a = cnt[2 * t], b_ = cnt[2 * t + 1];
    ssum[t] = a + b_;
    __syncthreads();
    for (int off = 1; off < 256; off <<= 1) {       // Hillis-Steele inclusive over 256 pair-sums
        int v = (t >= off) ? ssum[t - off] : 0;
        __syncthreads();
        ssum[t] += v;
        __syncthreads();
    }
    int excl = ssum[t] - (a + b_);
    if (2 * t < NBKT)     cando[(size_t)c * NBKT + 2 * t]     = make_int2(a, excl);
    if (2 * t + 1 < NBKT) cando[(size_t)c * NBKT + 2 * t + 1] = make_int2(b_, excl + a);
    __syncthreads();
    cnt[2 * t] = excl; cnt[2 * t + 1] = excl + a;    // reuse as cursors
    __syncthreads();
    #pragma unroll
    for (int i = 0; i < 8; i++) {
        if (d8[i] >= 0) {
            int pos = atomicAdd(&cnt[d8[i] >> 8], 1);
            recs[pos] = ((long long)d8[i] << 32) | (unsigned)s8[i];
        }
    }
    __syncthreads();
    for (int j = t; j < nv; j += 256)
        recs_out[(size_t)e0 + j] = recs[j];          // fully coalesced 8B stores
}

// ---------------- per-bucket degree count + node prep + bucket totals (fused) ----------------
__global__ __launch_bounds__(512) void bucket_count_kernel(const long long* __restrict__ recs_bin,
                                                           const int2* __restrict__ cando,
                                                           int* __restrict__ cnt,
                                                           int* __restrict__ bktsum,
                                                           float* __restrict__ dinv,
                                                           float* __restrict__ selfw,
                                                           int nch, int n) {
    __shared__ int c256[256];
    __shared__ int wsum[4];
    int b = blockIdx.x;
    int t = threadIdx.x;
    if (t < 256) c256[t] = 0;
    __syncthreads();
    for (int c = t; c < nch; c += 512) {
        int2 co = cando[(size_t)c * NBKT + b];
        size_t base = (size_t)c * CHSZ + co.y;
        for (int k = 0; k < co.x; ++k) {
            long long rec = recs_bin[base + k];
            int d = (int)(rec >> 32);
            atomicAdd(&c256[d & 255], 1);
        }
    }
    __syncthreads();
    int node = (b << 8) + t;
    int cv = 0;
    if (t < 256) {
        cv = c256[t];
        if (node < n) {
            cnt[node] = cv;
            float deg = (float)cv + 1.0f;   // +1 self loop
            dinv[node]  = rsqrtf(deg);
            selfw[node] = 1.0f / deg;
        }
    }
    // bucket total (first 4 waves reduce 256 values)
    if (t < 256) {
        int s = cv;
        #pragma unroll
        for (int off = 32; off > 0; off >>= 1) s += __shfl_down(s, off);
        if ((t & 63) == 0) wsum[t >> 6] = s;
    }
    __syncthreads();
    if (t == 0) bktsum[b] = wsum[0] + wsum[1] + wsum[2] + wsum[3];
}

// ---------------- scan of 391 bucket sums (one tiny block) ----------------
__global__ __launch_bounds__(512) void scan_bkt_kernel(const int* __restrict__ bktsum,
                                                       int* __restrict__ bktoff, int nb) {
    __shared__ int t512[512];
    int t = threadIdx.x;
    t512[t] = (t < nb) ? bktsum[t] : 0;
    __syncthreads();
    for (int off = 1; off < 512; off <<= 1) {
        int v = (t >= off) ? t512[t - off] : 0;
        __syncthreads();
        t512[t] += v;
        __syncthreads();
    }
    if (t < nb) bktoff[t] = (t == 0) ? 0 : t512[t - 1];
}

// ---------------- phase 2: per-bucket CSR fill + rowptr write (fused) ----------------
__global__ __launch_bounds__(512) void bucket_fill_kernel(const long long* __restrict__ recs_bin,
                                                          const int2* __restrict__ cando,
                                                          const int* __restrict__ cnt,
                                                          const int* __restrict__ bktoff,
                                                          const float* __restrict__ dinv,
                                                          int* __restrict__ rowptr,
                                                          long long* __restrict__ csr_rec,
                                                          int nch, int n, int nE) {
    __shared__ int cur[256];
    __shared__ int scn[256];
    int b = blockIdx.x;
    int node0 = b << 8;
    int t = threadIdx.x;
    int cv = 0;
    if (t < 256) {
        int nd = node0 + t;
        cv = (nd < n) ? cnt[nd] : 0;
        scn[t] = cv;
    }
    __syncthreads();
    for (int off = 1; off < 256; off <<= 1) {     // inclusive scan over this bucket's 256 counts
        int v = (t < 256 && t >= off) ? scn[t - off] : 0;
        __syncthreads();
        if (t < 256) scn[t] += v;
        __syncthreads();
    }
    if (t < 256) {
        int nd = node0 + t;
        int excl = bktoff[b] + scn[t] - cv;       // exclusive prefix = global row start
        if (nd < n) { rowptr[nd] = excl; cur[t] = excl; }
    }
    if (b == NBKT - 1 && t == 0) rowptr[n] = nE;
    __syncthreads();
    for (int c = t; c < nch; c += 512) {
        int2 co = cando[(size_t)c * NBKT + b];
        size_t base = (size_t)c * CHSZ + co.y;
        for (int k = 0; k < co.x; ++k) {
            long long rec = recs_bin[base + k];
            int d = (int)(rec >> 32);
            int s = (int)(unsigned)(rec & 0xffffffffLL);
            float w = dinv[s] * dinv[d];
            int pos = atomicAdd(&cur[d & 255], 1);
            csr_rec[pos] = ((long long)__float_as_int(w) << 32) | (unsigned)s;
        }
    }
}

// ---------------- weight prep: pack W (f32 row-major 128x128) into B-fragment-linear bf16 ----------------
__global__ __launch_bounds__(256) void wprep_kernel(const float* __restrict__ W1,
                                                    const float* __restrict__ W2,
                                                    const float* __restrict__ W3,
                                                    unsigned short* __restrict__ Wf) {
    int gid = blockIdx.x * 256 + threadIdx.x;   // 0..49151
    int w = gid >> 14;
    int o = gid & 16383;
    int j = o & 7, lane = (o >> 3) & 63, ct = (o >> 9) & 7, kt = o >> 12;
    int rk = kt * 32 + (lane >> 4) * 8 + j;
    int col = ct * 16 + (lane & 15);
    const float* W = (w == 0) ? W1 : ((w == 1) ? W2 : W3);
    Wf[gid] = f2b(W[rk * HIDF + col]);
}

// ---------------- MFMA GEMM: Hfp8 = f(X) @ W  (fp8 e4m3 table out) ----------------
template <typename T>
__global__ __launch_bounds__(256) void mfma_gemm_kernel(const T* __restrict__ X,
                                                        const unsigned short* __restrict__ Wfrag,
                                                        const float* __restrict__ bias,
                                                        unsigned char* __restrict__ Hfp8, int n) {
    __shared__ unsigned short wl[16384];   // 32 KB: full 128x128 bf16 W in fragment-linear layout
    {
        const uint4* wsrc = reinterpret_cast<const uint4*>(Wfrag);
        uint4* wdst = reinterpret_cast<uint4*>(wl);
        for (int i = threadIdx.x; i < 2048; i += 256) wdst[i] = wsrc[i];
    }
    __syncthreads();

    int wv = threadIdx.x >> 6;          // wave 0..3
    int l  = threadIdx.x & 63;          // lane
    int row = blockIdx.x * 64 + wv * 16 + (l & 15);
    int koff = (l >> 4) * 8;
    bool rowok = row < n;

    f32x4 acc[8] = {};
    #pragma unroll
    for (int kt = 0; kt < 4; ++kt) {
        int kbase = kt * 32 + koff;
        bf16x8 a;
        if constexpr (sizeof(T) == 4) {          // f32 input (layer 1, no bias)
            float4 x0 = {0,0,0,0}, x1 = {0,0,0,0};
            if (rowok) {
                x0 = *reinterpret_cast<const float4*>(&X[(size_t)row * HIDF + kbase]);
                x1 = *reinterpret_cast<const float4*>(&X[(size_t)row * HIDF + kbase + 4]);
            }
            a[0] = (short)f2b(x0.x); a[1] = (short)f2b(x0.y);
            a[2] = (short)f2b(x0.z); a[3] = (short)f2b(x0.w);
            a[4] = (short)f2b(x1.x); a[5] = (short)f2b(x1.y);
            a[6] = (short)f2b(x1.z); a[7] = (short)f2b(x1.w);
        } else {                                  // bf16 input (layers 2,3; +bias,relu)
            uint4 raw = {0,0,0,0};
            if (rowok) raw = *reinterpret_cast<const uint4*>(&X[(size_t)row * HIDF + kbase]);
            unsigned short* ru = reinterpret_cast<unsigned short*>(&raw);
            if (bias) {
                #pragma unroll
                for (int j = 0; j < 8; ++j) {
                    float v = b2f(ru[j]) + bias[kbase + j];
                    ru[j] = f2b(fmaxf(v, 0.f));
                }
            }
            a = *reinterpret_cast<bf16x8*>(&raw);
        }
        #pragma unroll
        for (int ct = 0; ct < 8; ++ct) {
            bf16x8 b = *reinterpret_cast<bf16x8*>(&wl[((kt * 8 + ct) * 64 + l) * 8]);
            acc[ct] = __builtin_amdgcn_mfma_f32_16x16x32_bf16(a, b, acc[ct], 0, 0, 0);
        }
    }
    int rbase = blockIdx.x * 64 + wv * 16 + ((l >> 4) << 2);
    int cbase = l & 15;
    #pragma unroll
    for (int ct = 0; ct < 8; ++ct) {
        #pragma unroll
        for (int r = 0; r < 4; ++r) {
            int gr = rbase + r;
            if (gr < n) Hfp8[(size_t)gr * HIDF + ct * 16 + cbase] = f2fp8(acc[ct][r]);
        }
    }
}

// ---------------- gather aggregation over fp8 table: 8-lane groups, batched 8-row pipeline ----------------
__global__ __launch_bounds__(256) void gather_agg_kernel(const unsigned char* __restrict__ Hin,
                                                         const int* __restrict__ rowptr,
                                                         const long long* __restrict__ csr_rec,
                                                         const float* __restrict__ selfw,
                                                         unsigned short* __restrict__ Hout, int n) {
    int node = blockIdx.x * 32 + (threadIdx.x >> 3);
    if (node >= n) return;
    int lane = threadIdx.x & 7;          // lane's row segment: fp8 features [lane*16, lane*16+16)
    float acc[16];
    {
        uint4 sv = *reinterpret_cast<const uint4*>(Hin + (size_t)node * HIDF + lane * 16);
        const unsigned* svw = reinterpret_cast<const unsigned*>(&sv);
        float sw = selfw[node];
        #pragma unroll
        for (int d = 0; d < 4; ++d) {
            f32x2 lo = __builtin_amdgcn_cvt_pk_f32_fp8((int)svw[d], false);
            f32x2 hi = __builtin_amdgcn_cvt_pk_f32_fp8((int)svw[d], true);
            acc[d * 4 + 0] = lo[0] * sw; acc[d * 4 + 1] = lo[1] * sw;
            acc[d * 4 + 2] = hi[0] * sw; acc[d * 4 + 3] = hi[1] * sw;
        }
    }
    int beg = rowptr[node], end = rowptr[node + 1];
    int nfull = (end - beg) >> 3;
    int base = beg;
    for (int fb = 0; fb < nfull; ++fb, base += 8) {
        long long rec = csr_rec[base + lane];            // 64B coalesced per group
        uint4 v[8];
        float w[8];
        #pragma unroll
        for (int j = 0; j < 8; ++j) {                    // issue 8 independent row loads
            long long r = __shfl(rec, j, 8);
            int sn = (int)(unsigned)(r & 0xffffffffLL);
            w[j] = __int_as_float((int)(r >> 32));
            v[j] = *reinterpret_cast<const uint4*>(Hin + (size_t)sn * HIDF + lane * 16);
        }
        #pragma unroll
        for (int j = 0; j < 8; ++j) {                    // consume
            const unsigned* vw = reinterpret_cast<const unsigned*>(&v[j]);
            #pragma unroll
            for (int d = 0; d < 4; ++d) {
                f32x2 lo = __builtin_amdgcn_cvt_pk_f32_fp8((int)vw[d], false);
                f32x2 hi = __builtin_amdgcn_cvt_pk_f32_fp8((int)vw[d], true);
                acc[d * 4 + 0] += lo[0] * w[j]; acc[d * 4 + 1] += lo[1] * w[j];
                acc[d * 4 + 2] += hi[0] * w[j]; acc[d * 4 + 3] += hi[1] * w[j];
            }
        }
    }
    int m = end - base;                                  // tail < 8
    if (m > 0) {
        long long rec = (base + lane < end) ? csr_rec[base + lane] : 0;
        for (int j = 0; j < m; ++j) {
            long long r = __shfl(rec, j, 8);
            int sn = (int)(unsigned)(r & 0xffffffffLL);
            float w = __int_as_float((int)(r >> 32));
            uint4 v = *reinterpret_cast<const uint4*>(Hin + (size_t)sn * HIDF + lane * 16);
            const unsigned* vw = reinterpret_cast<const unsigned*>(&v);
            #pragma unroll
            for (int d = 0; d < 4; ++d) {
                f32x2 lo = __builtin_amdgcn_cvt_pk_f32_fp8((int)vw[d], false);
                f32x2 hi = __builtin_amdgcn_cvt_pk_f32_fp8((int)vw[d], true);
                acc[d * 4 + 0] += lo[0] * w; acc[d * 4 + 1] += lo[1] * w;
                acc[d * 4 + 2] += hi[0] * w; acc[d * 4 + 3] += hi[1] * w;
            }
        }
    }
    ushort8 o0, o1;
    #pragma unroll
    for (int i = 0; i < 8; ++i) o0[i] = f2b(acc[i]);
    #pragma unroll
    for (int i = 0; i < 8; ++i) o1[i] = f2b(acc[8 + i]);
    unsigned short* op = Hout + (size_t)node * HIDF + lane * 16;
    *reinterpret_cast<ushort8*>(op) = o0;
    *reinterpret_cast<ushort8*>(op + 8) = o1;
}

// ---------------- fused mean pool + centroid head: one block per graph ----------------
__device__ __forceinline__ int lower_bound_i(const int* __restrict__ a, int n, int key) {
    int lo = 0, hi = n;
    while (lo < hi) { int mid = (lo + hi) >> 1; if (a[mid] < key) lo = mid + 1; else hi = mid; }
    return lo;
}

__global__ __launch_bounds__(256) void pool_final_kernel(const unsigned short* __restrict__ H,
                                                         const int* __restrict__ batch,
                                                         const float* __restrict__ b3,
                                                         const float* __restrict__ centroids,
                                                         const float* __restrict__ std_scale,
                                                         const float* __restrict__ ac_temp,
                                                         float* __restrict__ out, int n) {
    __shared__ float part[8][HIDF];
    __shared__ float gm[HIDF];
    int b = blockIdx.x;
    int g = threadIdx.x >> 5;       // row group 0..7
    int lane = threadIdx.x & 31;    // feature quad: 4*lane .. 4*lane+3
    int s = lower_bound_i(batch, n, b);
    int e = lower_bound_i(batch, n, b + 1);
    float4 acc = {0.f, 0.f, 0.f, 0.f};
    for (int i = s + g; i < e; i += 8) {
        ushort4 v = *reinterpret_cast<const ushort4*>(&H[(size_t)i * HIDF + lane * 4]);
        acc.x += b2f(v.x); acc.y += b2f(v.y);
        acc.z += b2f(v.z); acc.w += b2f(v.w);
    }
    part[g][lane * 4 + 0] = acc.x;
    part[g][lane * 4 + 1] = acc.y;
    part[g][lane * 4 + 2] = acc.z;
    part[g][lane * 4 + 3] = acc.w;
    __syncthreads();
    if (threadIdx.x < HIDF) {
        int f = threadIdx.x;
        float sum = 0.f;
        #pragma unroll
        for (int gg = 0; gg < 8; ++gg) sum += part[gg][f];
        float cnt = fmaxf((float)(e - s), 1.0f);
        gm[f] = sum / cnt + b3[f];
    }
    __syncthreads();
    if (threadIdx.x < 64) {
        int l = threadIdx.x;
        float g0 = gm[l];
        float g1 = gm[64 + l];
        float mind = 1e30f;
        for (int c = 0; c < NCLS; ++c) {
            float dd[2];
            #pragma unroll
            for (int cent = 0; cent < 2; ++cent) {
                const float* cp = &centroids[(c * 2 + cent) * HIDF];
                float df0 = cp[l] - g0;
                float df1 = cp[64 + l] - g1;
                float p = df0 * df0 + df1 * df1;
                #pragma unroll
                for (int off = 32; off > 0; off >>= 1) p += __shfl_xor(p, off);
                dd[cent] = p;
            }
            float dist = fminf(sqrtf(dd[0]), sqrtf(dd[1]));
            mind = fminf(mind, dist);
            if (l == 0) out[b * NCLS + c] = -dist;
        }
        if (l == 0) {
            float ss = std_scale[0];
            float clipped = fminf(fmaxf(ss, 0.0f), 5.0f);
            float max_ac = 1.0f + clipped * 0.0f;      // RUNNING_MEAN=1, sqrt(RUNNING_VAR)=0
            float accept = max_ac - mind;
            float soft = 1.0f / (1.0f + expf(-accept / ac_temp[0]));
            out[NGR * NCLS + b] = soft;
        }
    }
}

// ---------------- launch ----------------
extern "C" void kernel_launch(void* const* d_in, const int* in_sizes, int n_in,
                              void* d_out, int out_size, void* d_ws, size_t ws_size,
                              hipStream_t stream) {
    const float* x         = (const float*)d_in[0];
    const int*   edge      = (const int*)d_in[1];
    const int*   batch     = (const int*)d_in[2];
    const float* W1        = (const float*)d_in[3];
    const float* b1        = (const float*)d_in[4];
    const float* W2        = (const float*)d_in[5];
    const float* b2        = (const float*)d_in[6];
    const float* W3        = (const float*)d_in[7];
    const float* b3        = (const float*)d_in[8];
    const float* centroids = (const float*)d_in[9];
    const float* std_scale = (const float*)d_in[10];
    const float* ac_temp   = (const float*)d_in[11];
    float* out = (float*)d_out;

    const int n  = NN;
    const int nE = in_sizes[1] / 2;
    const int* srcp = edge;
    const int* dstp = edge + nE;
    const int nch = (nE + CHSZ - 1) / CHSZ;

    // workspace layout (256B aligned)
    char* ws = (char*)d_ws;
    size_t off = 0;
    auto alloc = [&](size_t bytes) { void* p = ws + off; off = (off + bytes + 255) & ~(size_t)255; return p; };
    unsigned char*  hA = (unsigned char*) alloc((size_t)NN * HIDF);      // fp8 GEMM output table
    unsigned short* hG = (unsigned short*)alloc((size_t)NN * HIDF * 2);  // bf16 gather output table
    unsigned short* Wf = (unsigned short*)alloc((size_t)3 * HIDF * HIDF * 2);
    float* dinv    = (float*)alloc((size_t)NN * 4);
    float* selfw   = (float*)alloc((size_t)NN * 4);
    int*   cnt     = (int*)  alloc((size_t)NN * 4);
    int*   rowptr  = (int*)  alloc((size_t)(NN + 1) * 4);
    long long* csr_rec  = (long long*)alloc((size_t)nE * 8);
    long long* recs_bin = (long long*)alloc((size_t)nE * 8);
    int2*  cando   = (int2*) alloc((size_t)nch * NBKT * 8);
    int*   bktsum  = (int*)  alloc((size_t)NBKT * 4);
    int*   bktoff  = (int*)  alloc((size_t)NBKT * 4);

    // ---- weight prep + CSR build (CSR reused by all 3 layers) ----
    wprep_kernel<<<192, 256, 0, stream>>>(W1, W2, W3, Wf);
    bin_kernel<<<nch, 256, 0, stream>>>(srcp, dstp, recs_bin, cando, nE);
    bucket_count_kernel<<<NBKT, 512, 0, stream>>>(recs_bin, cando, cnt, bktsum, dinv, selfw, nch, n);
    scan_bkt_kernel<<<1, 512, 0, stream>>>(bktsum, bktoff, NBKT);
    bucket_fill_kernel<<<NBKT, 512, 0, stream>>>(recs_bin, cando, cnt, bktoff, dinv, rowptr, csr_rec, nch, n, nE);

    int gemm_blocks   = (n + 63) / 64;
    int gather_blocks = (n + 31) / 32;

    // layer 1: x f32 -> hA (fp8); gather -> hG (bf16)
    mfma_gemm_kernel<float><<<gemm_blocks, 256, 0, stream>>>(x, Wf, nullptr, hA, n);
    gather_agg_kernel<<<gather_blocks, 256, 0, stream>>>(hA, rowptr, csr_rec, selfw, hG, n);
    // layer 2: (+b1, relu) fused into A-load
    mfma_gemm_kernel<unsigned short><<<gemm_blocks, 256, 0, stream>>>(hG, Wf + 16384, b1, hA, n);
    gather_agg_kernel<<<gather_blocks, 256, 0, stream>>>(hA, rowptr, csr_rec, selfw, hG, n);
    // layer 3: (+b2, relu)
    mfma_gemm_kernel<unsigned short><<<gemm_blocks, 256, 0, stream>>>(hG, Wf + 32768, b2, hA, n);
    gather_agg_kernel<<<gather_blocks, 256, 0, stream>>>(hA, rowptr, csr_rec, selfw, hG, n);

    // fused mean pool (+b3) + centroid head — batch is sorted, no atomics
    pool_final_kernel<<<NGR, 256, 0, stream>>>(hG, batch, b3, centroids, std_scale, ac_temp, out, n);
}

// Round 14
// 244.040 us; speedup vs baseline: 35.3213x; 1.0259x over previous
//
#include <hip/hip_runtime.h>
#include <hip/hip_bf16.h>
#include <math.h>

#define NN 100000
#define NEDGE 1600000
#define HIDF 128
#define NCLS 18
#define NGR 512
#define CHSZ 2048                     // edges per bin chunk
#define NBKT 391                      // ceil(NN/256) buckets of 256 nodes

using bf16x8  = __attribute__((ext_vector_type(8))) short;   // 8 bf16 in 4 VGPRs
using ushort8 = __attribute__((ext_vector_type(8))) unsigned short;
using f32x4   = __attribute__((ext_vector_type(4))) float;
using f32x2   = __attribute__((ext_vector_type(2))) float;

__device__ __forceinline__ float b2f(unsigned short u) {
    return __uint_as_float(((unsigned)u) << 16);
}
__device__ __forceinline__ unsigned short f2b(float f) {   // round-to-nearest-even
    unsigned u = __float_as_uint(f);
    unsigned r = (u + 0x7fffu + ((u >> 16) & 1u)) >> 16;
    return (unsigned short)r;
}
__device__ __forceinline__ unsigned char f2fp8(float f) {  // f32 -> OCP e4m3 (HW cvt)
    int p = __builtin_amdgcn_cvt_pk_fp8_f32(f, f, 0, false);
    return (unsigned char)(p & 0xff);
}

// ---------------- phase 1: bin edges into 256-node buckets, chunk-local, coalesced out ----------------
__global__ __launch_bounds__(256) void bin_kernel(const int* __restrict__ src,
                                                  const int* __restrict__ dst,
                                                  long long* __restrict__ recs_out,
                                                  int2* __restrict__ cando, int nE) {
    __shared__ int cnt[512];
    __shared__ int ssum[256];
    __shared__ long long recs[CHSZ];
    int c = blockIdx.x;
    int t = threadIdx.x;
    cnt[t] = 0; cnt[t + 256] = 0;
    __syncthreads();
    int e0 = c * CHSZ;
    int nv = nE - e0; if (nv > CHSZ) nv = CHSZ;
    int s8[8], d8[8];
    #pragma unroll
    for (int i = 0; i < 8; i++) {
        int li = t + i * 256;
        bool ok = li < nv;
        s8[i] = ok ? src[e0 + li] : -1;
        d8[i] = ok ? dst[e0 + li] : -1;
        if (ok) atomicAdd(&cnt[d8[i] >> 8], 1);
    }
    __syncthreads();
    int a = cnt[2 * t], b_ = cnt[2 * t + 1];
    ssum[t] = a + b_;
    __syncthreads();
    for (int off = 1; off < 256; off <<= 1) {       // Hillis-Steele inclusive over 256 pair-sums
        int v = (t >= off) ? ssum[t - off] : 0;
        __syncthreads();
        ssum[t] += v;
        __syncthreads();
    }
    int excl = ssum[t] - (a + b_);
    if (2 * t < NBKT)     cando[(size_t)c * NBKT + 2 * t]     = make_int2(a, excl);
    if (2 * t + 1 < NBKT) cando[(size_t)c * NBKT + 2 * t + 1] = make_int2(b_, excl + a);
    __syncthreads();
    cnt[2 * t] = excl; cnt[2 * t + 1] = excl + a;    // reuse as cursors
    __syncthreads();
    #pragma unroll
    for (int i = 0; i < 8; i++) {
        if (d8[i] >= 0) {
            int pos = atomicAdd(&cnt[d8[i] >> 8], 1);
            recs[pos] = ((long long)d8[i] << 32) | (unsigned)s8[i];
        }
    }
    __syncthreads();
    for (int j = t; j < nv; j += 256)
        recs_out[(size_t)e0 + j] = recs[j];          // fully coalesced 8B stores
}

// ---------------- per-bucket degree count + node prep + bucket totals (fused) ----------------
__global__ __launch_bounds__(512) void bucket_count_kernel(const long long* __restrict__ recs_bin,
                                                           const int2* __restrict__ cando,
                                                           int* __restrict__ cnt,
                                                           int* __restrict__ bktsum,
                                                           float* __restrict__ dinv,
                                                           float* __restrict__ selfw,
                                                           int nch, int n) {
    __shared__ int c256[256];
    __shared__ int wsum[4];
    int b = blockIdx.x;
    int t = threadIdx.x;
    if (t < 256) c256[t] = 0;
    __syncthreads();
    for (int c = t; c < nch; c += 512) {
        int2 co = cando[(size_t)c * NBKT + b];
        size_t base = (size_t)c * CHSZ + co.y;
        for (int k = 0; k < co.x; ++k) {
            long long rec = recs_bin[base + k];
            int d = (int)(rec >> 32);
            atomicAdd(&c256[d & 255], 1);
        }
    }
    __syncthreads();
    int node = (b << 8) + t;
    int cv = 0;
    if (t < 256) {
        cv = c256[t];
        if (node < n) {
            cnt[node] = cv;
            float deg = (float)cv + 1.0f;   // +1 self loop
            dinv[node]  = rsqrtf(deg);
            selfw[node] = 1.0f / deg;
        }
    }
    if (t < 256) {
        int s = cv;
        #pragma unroll
        for (int off = 32; off > 0; off >>= 1) s += __shfl_down(s, off);
        if ((t & 63) == 0) wsum[t >> 6] = s;
    }
    __syncthreads();
    if (t == 0) bktsum[b] = wsum[0] + wsum[1] + wsum[2] + wsum[3];
}

// ---------------- scan of 391 bucket sums (one tiny block) ----------------
__global__ __launch_bounds__(512) void scan_bkt_kernel(const int* __restrict__ bktsum,
                                                       int* __restrict__ bktoff, int nb) {
    __shared__ int t512[512];
    int t = threadIdx.x;
    t512[t] = (t < nb) ? bktsum[t] : 0;
    __syncthreads();
    for (int off = 1; off < 512; off <<= 1) {
        int v = (t >= off) ? t512[t - off] : 0;
        __syncthreads();
        t512[t] += v;
        __syncthreads();
    }
    if (t < nb) bktoff[t] = (t == 0) ? 0 : t512[t - 1];
}

// ---------------- phase 2: per-bucket CSR fill + rowptr write (fused) ----------------
__global__ __launch_bounds__(512) void bucket_fill_kernel(const long long* __restrict__ recs_bin,
                                                          const int2* __restrict__ cando,
                                                          const int* __restrict__ cnt,
                                                          const int* __restrict__ bktoff,
                                                          const float* __restrict__ dinv,
                                                          int* __restrict__ rowptr,
                                                          long long* __restrict__ csr_rec,
                                                          int nch, int n, int nE) {
    __shared__ int cur[256];
    __shared__ int scn[256];
    int b = blockIdx.x;
    int node0 = b << 8;
    int t = threadIdx.x;
    int cv = 0;
    if (t < 256) {
        int nd = node0 + t;
        cv = (nd < n) ? cnt[nd] : 0;
        scn[t] = cv;
    }
    __syncthreads();
    for (int off = 1; off < 256; off <<= 1) {     // inclusive scan over this bucket's 256 counts
        int v = (t < 256 && t >= off) ? scn[t - off] : 0;
        __syncthreads();
        if (t < 256) scn[t] += v;
        __syncthreads();
    }
    if (t < 256) {
        int nd = node0 + t;
        int excl = bktoff[b] + scn[t] - cv;       // exclusive prefix = global row start
        if (nd < n) { rowptr[nd] = excl; cur[t] = excl; }
    }
    if (b == NBKT - 1 && t == 0) rowptr[n] = nE;
    __syncthreads();
    for (int c = t; c < nch; c += 512) {
        int2 co = cando[(size_t)c * NBKT + b];
        size_t base = (size_t)c * CHSZ + co.y;
        for (int k = 0; k < co.x; ++k) {
            long long rec = recs_bin[base + k];
            int d = (int)(rec >> 32);
            int s = (int)(unsigned)(rec & 0xffffffffLL);
            float w = dinv[s] * dinv[d];
            int pos = atomicAdd(&cur[d & 255], 1);
            csr_rec[pos] = ((long long)__float_as_int(w) << 32) | (unsigned)s;
        }
    }
}

// ---------------- weight prep: pack W (f32 row-major 128x128) into B-fragment-linear bf16 ----------------
__global__ __launch_bounds__(256) void wprep_kernel(const float* __restrict__ W1,
                                                    const float* __restrict__ W2,
                                                    const float* __restrict__ W3,
                                                    unsigned short* __restrict__ Wf) {
    int gid = blockIdx.x * 256 + threadIdx.x;   // 0..49151
    int w = gid >> 14;
    int o = gid & 16383;
    int j = o & 7, lane = (o >> 3) & 63, ct = (o >> 9) & 7, kt = o >> 12;
    int rk = kt * 32 + (lane >> 4) * 8 + j;
    int col = ct * 16 + (lane & 15);
    const float* W = (w == 0) ? W1 : ((w == 1) ? W2 : W3);
    Wf[gid] = f2b(W[rk * HIDF + col]);
}

// ---------------- MFMA GEMM (layer 1): Hfp8 = x @ W1  (f32 in, fp8 out) ----------------
__global__ __launch_bounds__(256) void mfma_gemm_kernel(const float* __restrict__ X,
                                                        const unsigned short* __restrict__ Wfrag,
                                                        unsigned char* __restrict__ Hfp8, int n) {
    __shared__ unsigned short wl[16384];   // 32 KB: full 128x128 bf16 W in fragment-linear layout
    {
        const uint4* wsrc = reinterpret_cast<const uint4*>(Wfrag);
        uint4* wdst = reinterpret_cast<uint4*>(wl);
        for (int i = threadIdx.x; i < 2048; i += 256) wdst[i] = wsrc[i];
    }
    __syncthreads();

    int wv = threadIdx.x >> 6;          // wave 0..3
    int l  = threadIdx.x & 63;          // lane
    int row = blockIdx.x * 64 + wv * 16 + (l & 15);
    int koff = (l >> 4) * 8;
    bool rowok = row < n;

    f32x4 acc[8] = {};
    #pragma unroll
    for (int kt = 0; kt < 4; ++kt) {
        int kbase = kt * 32 + koff;
        bf16x8 a;
        float4 x0 = {0,0,0,0}, x1 = {0,0,0,0};
        if (rowok) {
            x0 = *reinterpret_cast<const float4*>(&X[(size_t)row * HIDF + kbase]);
            x1 = *reinterpret_cast<const float4*>(&X[(size_t)row * HIDF + kbase + 4]);
        }
        a[0] = (short)f2b(x0.x); a[1] = (short)f2b(x0.y);
        a[2] = (short)f2b(x0.z); a[3] = (short)f2b(x0.w);
        a[4] = (short)f2b(x1.x); a[5] = (short)f2b(x1.y);
        a[6] = (short)f2b(x1.z); a[7] = (short)f2b(x1.w);
        #pragma unroll
        for (int ct = 0; ct < 8; ++ct) {
            bf16x8 b = *reinterpret_cast<bf16x8*>(&wl[((kt * 8 + ct) * 64 + l) * 8]);
            acc[ct] = __builtin_amdgcn_mfma_f32_16x16x32_bf16(a, b, acc[ct], 0, 0, 0);
        }
    }
    int rbase = blockIdx.x * 64 + wv * 16 + ((l >> 4) << 2);
    int cbase = l & 15;
    #pragma unroll
    for (int ct = 0; ct < 8; ++ct) {
        #pragma unroll
        for (int r = 0; r < 4; ++r) {
            int gr = rbase + r;
            if (gr < n) Hfp8[(size_t)gr * HIDF + ct * 16 + cbase] = f2fp8(acc[ct][r]);
        }
    }
}

// ---------------- FUSED gather + next-layer GEMM ----------------
// 512 threads = 8 waves, 64 nodes/block. Phase A: batched fp8 gather (8-lane groups) ->
// bias+relu -> bf16 A-tile in padded LDS. Phase B: MFMA vs W (fragment-linear LDS) -> fp8 out.
__global__ __launch_bounds__(512) void fused_gather_gemm_kernel(
        const unsigned char* __restrict__ Hin,
        const int* __restrict__ rowptr,
        const long long* __restrict__ csr_rec,
        const float* __restrict__ selfw,
        const float* __restrict__ bias,
        const unsigned short* __restrict__ Wfrag,
        unsigned char* __restrict__ Hout, int n) {
    __shared__ unsigned short wl[16384];     // 32 KB W fragment-linear
    __shared__ unsigned short agg[64][136];  // 64 rows x 128 bf16, +8 pad (272B stride, 16B-aligned)
    {
        const uint4* wsrc = reinterpret_cast<const uint4*>(Wfrag);
        uint4* wdst = reinterpret_cast<uint4*>(wl);
        for (int i = threadIdx.x; i < 2048; i += 512) wdst[i] = wsrc[i];
    }
    int node0 = blockIdx.x * 64;
    int nl   = threadIdx.x >> 3;         // node-local 0..63
    int node = node0 + nl;
    int lane = threadIdx.x & 7;          // feature segment [lane*16, lane*16+16)
    if (node < n) {
        float acc[16];
        {
            uint4 sv = *reinterpret_cast<const uint4*>(Hin + (size_t)node * HIDF + lane * 16);
            const unsigned* svw = reinterpret_cast<const unsigned*>(&sv);
            float sw = selfw[node];
            #pragma unroll
            for (int d = 0; d < 4; ++d) {
                f32x2 lo = __builtin_amdgcn_cvt_pk_f32_fp8((int)svw[d], false);
                f32x2 hi = __builtin_amdgcn_cvt_pk_f32_fp8((int)svw[d], true);
                acc[d * 4 + 0] = lo[0] * sw; acc[d * 4 + 1] = lo[1] * sw;
                acc[d * 4 + 2] = hi[0] * sw; acc[d * 4 + 3] = hi[1] * sw;
            }
        }
        int beg = rowptr[node], end = rowptr[node + 1];
        int nfull = (end - beg) >> 3;
        int base = beg;
        for (int fb = 0; fb < nfull; ++fb, base += 8) {
            long long rec = csr_rec[base + lane];
            uint4 v[8];
            float w[8];
            #pragma unroll
            for (int j = 0; j < 8; ++j) {                    // 8 independent row loads in flight
                long long r = __shfl(rec, j, 8);
                int sn = (int)(unsigned)(r & 0xffffffffLL);
                w[j] = __int_as_float((int)(r >> 32));
                v[j] = *reinterpret_cast<const uint4*>(Hin + (size_t)sn * HIDF + lane * 16);
            }
            #pragma unroll
            for (int j = 0; j < 8; ++j) {
                const unsigned* vw = reinterpret_cast<const unsigned*>(&v[j]);
                #pragma unroll
                for (int d = 0; d < 4; ++d) {
                    f32x2 lo = __builtin_amdgcn_cvt_pk_f32_fp8((int)vw[d], false);
                    f32x2 hi = __builtin_amdgcn_cvt_pk_f32_fp8((int)vw[d], true);
                    acc[d * 4 + 0] += lo[0] * w[j]; acc[d * 4 + 1] += lo[1] * w[j];
                    acc[d * 4 + 2] += hi[0] * w[j]; acc[d * 4 + 3] += hi[1] * w[j];
                }
            }
        }
        int m = end - base;
        if (m > 0) {
            long long rec = (base + lane < end) ? csr_rec[base + lane] : 0;
            for (int j = 0; j < m; ++j) {
                long long r = __shfl(rec, j, 8);
                int sn = (int)(unsigned)(r & 0xffffffffLL);
                float w = __int_as_float((int)(r >> 32));
                uint4 v = *reinterpret_cast<const uint4*>(Hin + (size_t)sn * HIDF + lane * 16);
                const unsigned* vw = reinterpret_cast<const unsigned*>(&v);
                #pragma unroll
                for (int d = 0; d < 4; ++d) {
                    f32x2 lo = __builtin_amdgcn_cvt_pk_f32_fp8((int)vw[d], false);
                    f32x2 hi = __builtin_amdgcn_cvt_pk_f32_fp8((int)vw[d], true);
                    acc[d * 4 + 0] += lo[0] * w; acc[d * 4 + 1] += lo[1] * w;
                    acc[d * 4 + 2] += hi[0] * w; acc[d * 4 + 3] += hi[1] * w;
                }
            }
        }
        // bias + relu (f32, single round) -> bf16 A-tile
        #pragma unroll
        for (int i = 0; i < 16; ++i) {
            float vb = acc[i] + bias[lane * 16 + i];
            agg[nl][lane * 16 + i] = f2b(fmaxf(vb, 0.f));
        }
    } else {
        #pragma unroll
        for (int i = 0; i < 16; ++i) agg[nl][lane * 16 + i] = 0;
    }
    __syncthreads();
    // Phase B: MFMA. wave wv: row tile mt = wv>>1 (16 rows), col tiles ct0..ct0+3
    int wv = threadIdx.x >> 6;
    int l  = threadIdx.x & 63;
    int mt  = wv >> 1;
    int ct0 = (wv & 1) * 4;
    int arow = mt * 16 + (l & 15);
    int koff = (l >> 4) * 8;
    f32x4 acc4[4] = {};
    #pragma unroll
    for (int kt = 0; kt < 4; ++kt) {
        int kbase = kt * 32 + koff;
        bf16x8 a = *reinterpret_cast<bf16x8*>(&agg[arow][kbase]);
        #pragma unroll
        for (int c = 0; c < 4; ++c) {
            int ct = ct0 + c;
            bf16x8 b = *reinterpret_cast<bf16x8*>(&wl[((kt * 8 + ct) * 64 + l) * 8]);
            acc4[c] = __builtin_amdgcn_mfma_f32_16x16x32_bf16(a, b, acc4[c], 0, 0, 0);
        }
    }
    int rloc = mt * 16 + ((l >> 4) << 2);
    int cbase = l & 15;
    #pragma unroll
    for (int c = 0; c < 4; ++c) {
        int ct = ct0 + c;
        #pragma unroll
        for (int r = 0; r < 4; ++r) {
            int gr = node0 + rloc + r;
            if (gr < n) Hout[(size_t)gr * HIDF + ct * 16 + cbase] = f2fp8(acc4[c][r]);
        }
    }
}

// ---------------- gather aggregation (final layer): fp8 table in, bf16 out ----------------
__global__ __launch_bounds__(256) void gather_agg_kernel(const unsigned char* __restrict__ Hin,
                                                         const int* __restrict__ rowptr,
                                                         const long long* __restrict__ csr_rec,
                                                         const float* __restrict__ selfw,
                                                         unsigned short* __restrict__ Hout, int n) {
    int node = blockIdx.x * 32 + (threadIdx.x >> 3);
    if (node >= n) return;
    int lane = threadIdx.x & 7;
    float acc[16];
    {
        uint4 sv = *reinterpret_cast<const uint4*>(Hin + (size_t)node * HIDF + lane * 16);
        const unsigned* svw = reinterpret_cast<const unsigned*>(&sv);
        float sw = selfw[node];
        #pragma unroll
        for (int d = 0; d < 4; ++d) {
            f32x2 lo = __builtin_amdgcn_cvt_pk_f32_fp8((int)svw[d], false);
            f32x2 hi = __builtin_amdgcn_cvt_pk_f32_fp8((int)svw[d], true);
            acc[d * 4 + 0] = lo[0] * sw; acc[d * 4 + 1] = lo[1] * sw;
            acc[d * 4 + 2] = hi[0] * sw; acc[d * 4 + 3] = hi[1] * sw;
        }
    }
    int beg = rowptr[node], end = rowptr[node + 1];
    int nfull = (end - beg) >> 3;
    int base = beg;
    for (int fb = 0; fb < nfull; ++fb, base += 8) {
        long long rec = csr_rec[base + lane];
        uint4 v[8];
        float w[8];
        #pragma unroll
        for (int j = 0; j < 8; ++j) {
            long long r = __shfl(rec, j, 8);
            int sn = (int)(unsigned)(r & 0xffffffffLL);
            w[j] = __int_as_float((int)(r >> 32));
            v[j] = *reinterpret_cast<const uint4*>(Hin + (size_t)sn * HIDF + lane * 16);
        }
        #pragma unroll
        for (int j = 0; j < 8; ++j) {
            const unsigned* vw = reinterpret_cast<const unsigned*>(&v[j]);
            #pragma unroll
            for (int d = 0; d < 4; ++d) {
                f32x2 lo = __builtin_amdgcn_cvt_pk_f32_fp8((int)vw[d], false);
                f32x2 hi = __builtin_amdgcn_cvt_pk_f32_fp8((int)vw[d], true);
                acc[d * 4 + 0] += lo[0] * w[j]; acc[d * 4 + 1] += lo[1] * w[j];
                acc[d * 4 + 2] += hi[0] * w[j]; acc[d * 4 + 3] += hi[1] * w[j];
            }
        }
    }
    int m = end - base;
    if (m > 0) {
        long long rec = (base + lane < end) ? csr_rec[base + lane] : 0;
        for (int j = 0; j < m; ++j) {
            long long r = __shfl(rec, j, 8);
            int sn = (int)(unsigned)(r & 0xffffffffLL);
            float w = __int_as_float((int)(r >> 32));
            uint4 v = *reinterpret_cast<const uint4*>(Hin + (size_t)sn * HIDF + lane * 16);
            const unsigned* vw = reinterpret_cast<const unsigned*>(&v);
            #pragma unroll
            for (int d = 0; d < 4; ++d) {
                f32x2 lo = __builtin_amdgcn_cvt_pk_f32_fp8((int)vw[d], false);
                f32x2 hi = __builtin_amdgcn_cvt_pk_f32_fp8((int)vw[d], true);
                acc[d * 4 + 0] += lo[0] * w; acc[d * 4 + 1] += lo[1] * w;
                acc[d * 4 + 2] += hi[0] * w; acc[d * 4 + 3] += hi[1] * w;
            }
        }
    }
    ushort8 o0, o1;
    #pragma unroll
    for (int i = 0; i < 8; ++i) o0[i] = f2b(acc[i]);
    #pragma unroll
    for (int i = 0; i < 8; ++i) o1[i] = f2b(acc[8 + i]);
    unsigned short* op = Hout + (size_t)node * HIDF + lane * 16;
    *reinterpret_cast<ushort8*>(op) = o0;
    *reinterpret_cast<ushort8*>(op + 8) = o1;
}

// ---------------- fused mean pool + centroid head: one block per graph ----------------
__device__ __forceinline__ int lower_bound_i(const int* __restrict__ a, int n, int key) {
    int lo = 0, hi = n;
    while (lo < hi) { int mid = (lo + hi) >> 1; if (a[mid] < key) lo = mid + 1; else hi = mid; }
    return lo;
}

__global__ __launch_bounds__(256) void pool_final_kernel(const unsigned short* __restrict__ H,
                                                         const int* __restrict__ batch,
                                                         const float* __restrict__ b3,
                                                         const float* __restrict__ centroids,
                                                         const float* __restrict__ std_scale,
                                                         const float* __restrict__ ac_temp,
                                                         float* __restrict__ out, int n) {
    __shared__ float part[8][HIDF];
    __shared__ float gm[HIDF];
    int b = blockIdx.x;
    int g = threadIdx.x >> 5;
    int lane = threadIdx.x & 31;
    int s = lower_bound_i(batch, n, b);
    int e = lower_bound_i(batch, n, b + 1);
    float4 acc = {0.f, 0.f, 0.f, 0.f};
    for (int i = s + g; i < e; i += 8) {
        ushort4 v = *reinterpret_cast<const ushort4*>(&H[(size_t)i * HIDF + lane * 4]);
        acc.x += b2f(v.x); acc.y += b2f(v.y);
        acc.z += b2f(v.z); acc.w += b2f(v.w);
    }
    part[g][lane * 4 + 0] = acc.x;
    part[g][lane * 4 + 1] = acc.y;
    part[g][lane * 4 + 2] = acc.z;
    part[g][lane * 4 + 3] = acc.w;
    __syncthreads();
    if (threadIdx.x < HIDF) {
        int f = threadIdx.x;
        float sum = 0.f;
        #pragma unroll
        for (int gg = 0; gg < 8; ++gg) sum += part[gg][f];
        float cnt = fmaxf((float)(e - s), 1.0f);
        gm[f] = sum / cnt + b3[f];
    }
    __syncthreads();
    if (threadIdx.x < 64) {
        int l = threadIdx.x;
        float g0 = gm[l];
        float g1 = gm[64 + l];
        float mind = 1e30f;
        for (int c = 0; c < NCLS; ++c) {
            float dd[2];
            #pragma unroll
            for (int cent = 0; cent < 2; ++cent) {
                const float* cp = &centroids[(c * 2 + cent) * HIDF];
                float df0 = cp[l] - g0;
                float df1 = cp[64 + l] - g1;
                float p = df0 * df0 + df1 * df1;
                #pragma unroll
                for (int off = 32; off > 0; off >>= 1) p += __shfl_xor(p, off);
                dd[cent] = p;
            }
            float dist = fminf(sqrtf(dd[0]), sqrtf(dd[1]));
            mind = fminf(mind, dist);
            if (l == 0) out[b * NCLS + c] = -dist;
        }
        if (l == 0) {
            float ss = std_scale[0];
            float clipped = fminf(fmaxf(ss, 0.0f), 5.0f);
            float max_ac = 1.0f + clipped * 0.0f;      // RUNNING_MEAN=1, sqrt(RUNNING_VAR)=0
            float accept = max_ac - mind;
            float soft = 1.0f / (1.0f + expf(-accept / ac_temp[0]));
            out[NGR * NCLS + b] = soft;
        }
    }
}

// ---------------- launch ----------------
extern "C" void kernel_launch(void* const* d_in, const int* in_sizes, int n_in,
                              void* d_out, int out_size, void* d_ws, size_t ws_size,
                              hipStream_t stream) {
    const float* x         = (const float*)d_in[0];
    const int*   edge      = (const int*)d_in[1];
    const int*   batch     = (const int*)d_in[2];
    const float* W1        = (const float*)d_in[3];
    const float* b1        = (const float*)d_in[4];
    const float* W2        = (const float*)d_in[5];
    const float* b2        = (const float*)d_in[6];
    const float* W3        = (const float*)d_in[7];
    const float* b3        = (const float*)d_in[8];
    const float* centroids = (const float*)d_in[9];
    const float* std_scale = (const float*)d_in[10];
    const float* ac_temp   = (const float*)d_in[11];
    float* out = (float*)d_out;

    const int n  = NN;
    const int nE = in_sizes[1] / 2;
    const int* srcp = edge;
    const int* dstp = edge + nE;
    const int nch = (nE + CHSZ - 1) / CHSZ;

    // workspace layout (256B aligned)
    char* ws = (char*)d_ws;
    size_t off = 0;
    auto alloc = [&](size_t bytes) { void* p = ws + off; off = (off + bytes + 255) & ~(size_t)255; return p; };
    unsigned char*  hP = (unsigned char*) alloc((size_t)NN * HIDF);      // fp8 table (ping)
    unsigned char*  hQ = (unsigned char*) alloc((size_t)NN * HIDF);      // fp8 table (pong)
    unsigned short* hG = (unsigned short*)alloc((size_t)NN * HIDF * 2);  // bf16 final gather out
    unsigned short* Wf = (unsigned short*)alloc((size_t)3 * HIDF * HIDF * 2);
    float* dinv    = (float*)alloc((size_t)NN * 4);
    float* selfw   = (float*)alloc((size_t)NN * 4);
    int*   cnt     = (int*)  alloc((size_t)NN * 4);
    int*   rowptr  = (int*)  alloc((size_t)(NN + 1) * 4);
    long long* csr_rec  = (long long*)alloc((size_t)nE * 8);
    long long* recs_bin = (long long*)alloc((size_t)nE * 8);
    int2*  cando   = (int2*) alloc((size_t)nch * NBKT * 8);
    int*   bktsum  = (int*)  alloc((size_t)NBKT * 4);
    int*   bktoff  = (int*)  alloc((size_t)NBKT * 4);

    // ---- weight prep + CSR build (CSR reused by all 3 layers) ----
    wprep_kernel<<<192, 256, 0, stream>>>(W1, W2, W3, Wf);
    bin_kernel<<<nch, 256, 0, stream>>>(srcp, dstp, recs_bin, cando, nE);
    bucket_count_kernel<<<NBKT, 512, 0, stream>>>(recs_bin, cando, cnt, bktsum, dinv, selfw, nch, n);
    scan_bkt_kernel<<<1, 512, 0, stream>>>(bktsum, bktoff, NBKT);
    bucket_fill_kernel<<<NBKT, 512, 0, stream>>>(recs_bin, cando, cnt, bktoff, dinv, rowptr, csr_rec, nch, n, nE);

    int gemm_blocks  = (n + 63) / 64;
    int fused_blocks = (n + 63) / 64;
    int gath_blocks  = (n + 31) / 32;

    // layer 1 GEMM: x @ W1 -> hP (fp8)
    mfma_gemm_kernel<<<gemm_blocks, 256, 0, stream>>>(x, Wf, hP, n);
    // fused: gather(hP) -> +b1,relu -> @W2 -> hQ (fp8)
    fused_gather_gemm_kernel<<<fused_blocks, 512, 0, stream>>>(hP, rowptr, csr_rec, selfw, b1, Wf + 16384, hQ, n);
    // fused: gather(hQ) -> +b2,relu -> @W3 -> hP (fp8)
    fused_gather_gemm_kernel<<<fused_blocks, 512, 0, stream>>>(hQ, rowptr, csr_rec, selfw, b2, Wf + 32768, hP, n);
    // final gather: hP -> hG (bf16)
    gather_agg_kernel<<<gath_blocks, 256, 0, stream>>>(hP, rowptr, csr_rec, selfw, hG, n);
    // fused mean pool (+b3) + centroid head
    pool_final_kernel<<<NGR, 256, 0, stream>>>(hG, batch, b3, centroids, std_scale, ac_temp, out, n);
}

// Round 15
// 232.389 us; speedup vs baseline: 37.0921x; 1.0501x over previous
//
#include <hip/hip_runtime.h>
#include <hip/hip_bf16.h>
#include <math.h>

#define NN 100000
#define NEDGE 1600000
#define HIDF 128
#define NCLS 18
#define NGR 512
#define CHSZ 2048                     // edges per bin chunk
#define NBKT 391                      // ceil(NN/256) buckets of 256 nodes

using bf16x8  = __attribute__((ext_vector_type(8))) short;   // 8 bf16 in 4 VGPRs
using ushort8 = __attribute__((ext_vector_type(8))) unsigned short;
using f32x4   = __attribute__((ext_vector_type(4))) float;
using f32x2   = __attribute__((ext_vector_type(2))) float;

__device__ __forceinline__ float b2f(unsigned short u) {
    return __uint_as_float(((unsigned)u) << 16);
}
__device__ __forceinline__ unsigned short f2b(float f) {   // round-to-nearest-even
    unsigned u = __float_as_uint(f);
    unsigned r = (u + 0x7fffu + ((u >> 16) & 1u)) >> 16;
    return (unsigned short)r;
}
__device__ __forceinline__ unsigned char f2fp8(float f) {  // f32 -> OCP e4m3 (HW cvt)
    int p = __builtin_amdgcn_cvt_pk_fp8_f32(f, f, 0, false);
    return (unsigned char)(p & 0xff);
}

// ---------------- phase 1: bin edges into 256-node buckets, chunk-local, coalesced out ----------------
__global__ __launch_bounds__(256) void bin_kernel(const int* __restrict__ src,
                                                  const int* __restrict__ dst,
                                                  long long* __restrict__ recs_out,
                                                  int2* __restrict__ cando, int nE) {
    __shared__ int cnt[512];
    __shared__ int ssum[256];
    __shared__ long long recs[CHSZ];
    int c = blockIdx.x;
    int t = threadIdx.x;
    cnt[t] = 0; cnt[t + 256] = 0;
    __syncthreads();
    int e0 = c * CHSZ;
    int nv = nE - e0; if (nv > CHSZ) nv = CHSZ;
    int s8[8], d8[8];
    #pragma unroll
    for (int i = 0; i < 8; i++) {
        int li = t + i * 256;
        bool ok = li < nv;
        s8[i] = ok ? src[e0 + li] : -1;
        d8[i] = ok ? dst[e0 + li] : -1;
        if (ok) atomicAdd(&cnt[d8[i] >> 8], 1);
    }
    __syncthreads();
    int a = cnt[2 * t], b_ = cnt[2 * t + 1];
    ssum[t] = a + b_;
    __syncthreads();
    for (int off = 1; off < 256; off <<= 1) {       // Hillis-Steele inclusive over 256 pair-sums
        int v = (t >= off) ? ssum[t - off] : 0;
        __syncthreads();
        ssum[t] += v;
        __syncthreads();
    }
    int excl = ssum[t] - (a + b_);
    if (2 * t < NBKT)     cando[(size_t)c * NBKT + 2 * t]     = make_int2(a, excl);
    if (2 * t + 1 < NBKT) cando[(size_t)c * NBKT + 2 * t + 1] = make_int2(b_, excl + a);
    __syncthreads();
    cnt[2 * t] = excl; cnt[2 * t + 1] = excl + a;    // reuse as cursors
    __syncthreads();
    #pragma unroll
    for (int i = 0; i < 8; i++) {
        if (d8[i] >= 0) {
            int pos = atomicAdd(&cnt[d8[i] >> 8], 1);
            recs[pos] = ((long long)d8[i] << 32) | (unsigned)s8[i];
        }
    }
    __syncthreads();
    for (int j = t; j < nv; j += 256)
        recs_out[(size_t)e0 + j] = recs[j];          // fully coalesced 8B stores
}

// ---------------- per-bucket degree count + node prep + bucket totals (fused) ----------------
__global__ __launch_bounds__(512) void bucket_count_kernel(const long long* __restrict__ recs_bin,
                                                           const int2* __restrict__ cando,
                                                           int* __restrict__ cnt,
                                                           int* __restrict__ bktsum,
                                                           float* __restrict__ dinv,
                                                           float* __restrict__ selfw,
                                                           int nch, int n) {
    __shared__ int c256[256];
    __shared__ int wsum[4];
    int b = blockIdx.x;
    int t = threadIdx.x;
    if (t < 256) c256[t] = 0;
    __syncthreads();
    for (int c = t; c < nch; c += 512) {
        int2 co = cando[(size_t)c * NBKT + b];
        size_t base = (size_t)c * CHSZ + co.y;
        for (int k = 0; k < co.x; ++k) {
            long long rec = recs_bin[base + k];
            int d = (int)(rec >> 32);
            atomicAdd(&c256[d & 255], 1);
        }
    }
    __syncthreads();
    int node = (b << 8) + t;
    int cv = 0;
    if (t < 256) {
        cv = c256[t];
        if (node < n) {
            cnt[node] = cv;
            float deg = (float)cv + 1.0f;   // +1 self loop
            dinv[node]  = rsqrtf(deg);
            selfw[node] = 1.0f / deg;
        }
    }
    if (t < 256) {
        int s = cv;
        #pragma unroll
        for (int off = 32; off > 0; off >>= 1) s += __shfl_down(s, off);
        if ((t & 63) == 0) wsum[t >> 6] = s;
    }
    __syncthreads();
    if (t == 0) bktsum[b] = wsum[0] + wsum[1] + wsum[2] + wsum[3];
}

// ---------------- scan of 391 bucket sums (one tiny block) ----------------
__global__ __launch_bounds__(512) void scan_bkt_kernel(const int* __restrict__ bktsum,
                                                       int* __restrict__ bktoff, int nb) {
    __shared__ int t512[512];
    int t = threadIdx.x;
    t512[t] = (t < nb) ? bktsum[t] : 0;
    __syncthreads();
    for (int off = 1; off < 512; off <<= 1) {
        int v = (t >= off) ? t512[t - off] : 0;
        __syncthreads();
        t512[t] += v;
        __syncthreads();
    }
    if (t < nb) bktoff[t] = (t == 0) ? 0 : t512[t - 1];
}

// ---------------- phase 2: per-bucket CSR fill + rowptr write (fused) ----------------
__global__ __launch_bounds__(512) void bucket_fill_kernel(const long long* __restrict__ recs_bin,
                                                          const int2* __restrict__ cando,
                                                          const int* __restrict__ cnt,
                                                          const int* __restrict__ bktoff,
                                                          const float* __restrict__ dinv,
                                                          int* __restrict__ rowptr,
                                                          long long* __restrict__ csr_rec,
                                                          int nch, int n, int nE) {
    __shared__ int cur[256];
    __shared__ int scn[256];
    int b = blockIdx.x;
    int node0 = b << 8;
    int t = threadIdx.x;
    int cv = 0;
    if (t < 256) {
        int nd = node0 + t;
        cv = (nd < n) ? cnt[nd] : 0;
        scn[t] = cv;
    }
    __syncthreads();
    for (int off = 1; off < 256; off <<= 1) {     // inclusive scan over this bucket's 256 counts
        int v = (t < 256 && t >= off) ? scn[t - off] : 0;
        __syncthreads();
        if (t < 256) scn[t] += v;
        __syncthreads();
    }
    if (t < 256) {
        int nd = node0 + t;
        int excl = bktoff[b] + scn[t] - cv;       // exclusive prefix = global row start
        if (nd < n) { rowptr[nd] = excl; cur[t] = excl; }
    }
    if (b == NBKT - 1 && t == 0) rowptr[n] = nE;
    __syncthreads();
    for (int c = t; c < nch; c += 512) {
        int2 co = cando[(size_t)c * NBKT + b];
        size_t base = (size_t)c * CHSZ + co.y;
        for (int k = 0; k < co.x; ++k) {
            long long rec = recs_bin[base + k];
            int d = (int)(rec >> 32);
            int s = (int)(unsigned)(rec & 0xffffffffLL);
            float w = dinv[s] * dinv[d];
            int pos = atomicAdd(&cur[d & 255], 1);
            csr_rec[pos] = ((long long)__float_as_int(w) << 32) | (unsigned)s;
        }
    }
}

// ---------------- weight prep: pack W (f32 row-major 128x128) into B-fragment-linear bf16 ----------------
__global__ __launch_bounds__(256) void wprep_kernel(const float* __restrict__ W1,
                                                    const float* __restrict__ W2,
                                                    const float* __restrict__ W3,
                                                    unsigned short* __restrict__ Wf) {
    int gid = blockIdx.x * 256 + threadIdx.x;   // 0..49151
    int w = gid >> 14;
    int o = gid & 16383;
    int j = o & 7, lane = (o >> 3) & 63, ct = (o >> 9) & 7, kt = o >> 12;
    int rk = kt * 32 + (lane >> 4) * 8 + j;
    int col = ct * 16 + (lane & 15);
    const float* W = (w == 0) ? W1 : ((w == 1) ? W2 : W3);
    Wf[gid] = f2b(W[rk * HIDF + col]);
}

// ---------------- MFMA GEMM (layer 1): Hfp8 = x @ W1  (f32 in, fp8 out) ----------------
__global__ __launch_bounds__(256) void mfma_gemm_kernel(const float* __restrict__ X,
                                                        const unsigned short* __restrict__ Wfrag,
                                                        unsigned char* __restrict__ Hfp8, int n) {
    __shared__ unsigned short wl[16384];   // 32 KB: full 128x128 bf16 W in fragment-linear layout
    {
        const uint4* wsrc = reinterpret_cast<const uint4*>(Wfrag);
        uint4* wdst = reinterpret_cast<uint4*>(wl);
        for (int i = threadIdx.x; i < 2048; i += 256) wdst[i] = wsrc[i];
    }
    __syncthreads();

    int wv = threadIdx.x >> 6;          // wave 0..3
    int l  = threadIdx.x & 63;          // lane
    int row = blockIdx.x * 64 + wv * 16 + (l & 15);
    int koff = (l >> 4) * 8;
    bool rowok = row < n;

    f32x4 acc[8] = {};
    #pragma unroll
    for (int kt = 0; kt < 4; ++kt) {
        int kbase = kt * 32 + koff;
        bf16x8 a;
        float4 x0 = {0,0,0,0}, x1 = {0,0,0,0};
        if (rowok) {
            x0 = *reinterpret_cast<const float4*>(&X[(size_t)row * HIDF + kbase]);
            x1 = *reinterpret_cast<const float4*>(&X[(size_t)row * HIDF + kbase + 4]);
        }
        a[0] = (short)f2b(x0.x); a[1] = (short)f2b(x0.y);
        a[2] = (short)f2b(x0.z); a[3] = (short)f2b(x0.w);
        a[4] = (short)f2b(x1.x); a[5] = (short)f2b(x1.y);
        a[6] = (short)f2b(x1.z); a[7] = (short)f2b(x1.w);
        #pragma unroll
        for (int ct = 0; ct < 8; ++ct) {
            bf16x8 b = *reinterpret_cast<bf16x8*>(&wl[((kt * 8 + ct) * 64 + l) * 8]);
            acc[ct] = __builtin_amdgcn_mfma_f32_16x16x32_bf16(a, b, acc[ct], 0, 0, 0);
        }
    }
    int rbase = blockIdx.x * 64 + wv * 16 + ((l >> 4) << 2);
    int cbase = l & 15;
    #pragma unroll
    for (int ct = 0; ct < 8; ++ct) {
        #pragma unroll
        for (int r = 0; r < 4; ++r) {
            int gr = rbase + r;
            if (gr < n) Hfp8[(size_t)gr * HIDF + ct * 16 + cbase] = f2fp8(acc[ct][r]);
        }
    }
}

// ---------------- FUSED gather + next-layer GEMM (W read from L2, LDS = A-tile only) ----------------
// 512 threads = 8 waves, 64 nodes/block. Phase A: batched fp8 gather (8-lane groups) ->
// bias+relu -> bf16 A-tile in padded LDS. Phase B: MFMA, B-fragments straight from global
// (32 KB W block is L2-broadcast across all blocks) -> fp8 out. 17.4 KB LDS -> 4 blocks/CU.
__global__ __launch_bounds__(512) void fused_gather_gemm_kernel(
        const unsigned char* __restrict__ Hin,
        const int* __restrict__ rowptr,
        const long long* __restrict__ csr_rec,
        const float* __restrict__ selfw,
        const float* __restrict__ bias,
        const unsigned short* __restrict__ Wfrag,
        unsigned char* __restrict__ Hout, int n) {
    __shared__ unsigned short agg[64][136];  // 64 rows x 128 bf16, +8 pad
    int node0 = blockIdx.x * 64;
    int nl   = threadIdx.x >> 3;         // node-local 0..63
    int node = node0 + nl;
    int lane = threadIdx.x & 7;          // feature segment [lane*16, lane*16+16)
    if (node < n) {
        float acc[16];
        {
            uint4 sv = *reinterpret_cast<const uint4*>(Hin + (size_t)node * HIDF + lane * 16);
            const unsigned* svw = reinterpret_cast<const unsigned*>(&sv);
            float sw = selfw[node];
            #pragma unroll
            for (int d = 0; d < 4; ++d) {
                f32x2 lo = __builtin_amdgcn_cvt_pk_f32_fp8((int)svw[d], false);
                f32x2 hi = __builtin_amdgcn_cvt_pk_f32_fp8((int)svw[d], true);
                acc[d * 4 + 0] = lo[0] * sw; acc[d * 4 + 1] = lo[1] * sw;
                acc[d * 4 + 2] = hi[0] * sw; acc[d * 4 + 3] = hi[1] * sw;
            }
        }
        int beg = rowptr[node], end = rowptr[node + 1];
        int nfull = (end - beg) >> 3;
        int base = beg;
        for (int fb = 0; fb < nfull; ++fb, base += 8) {
            long long rec = csr_rec[base + lane];
            uint4 v[8];
            float w[8];
            #pragma unroll
            for (int j = 0; j < 8; ++j) {                    // 8 independent row loads in flight
                long long r = __shfl(rec, j, 8);
                int sn = (int)(unsigned)(r & 0xffffffffLL);
                w[j] = __int_as_float((int)(r >> 32));
                v[j] = *reinterpret_cast<const uint4*>(Hin + (size_t)sn * HIDF + lane * 16);
            }
            #pragma unroll
            for (int j = 0; j < 8; ++j) {
                const unsigned* vw = reinterpret_cast<const unsigned*>(&v[j]);
                #pragma unroll
                for (int d = 0; d < 4; ++d) {
                    f32x2 lo = __builtin_amdgcn_cvt_pk_f32_fp8((int)vw[d], false);
                    f32x2 hi = __builtin_amdgcn_cvt_pk_f32_fp8((int)vw[d], true);
                    acc[d * 4 + 0] += lo[0] * w[j]; acc[d * 4 + 1] += lo[1] * w[j];
                    acc[d * 4 + 2] += hi[0] * w[j]; acc[d * 4 + 3] += hi[1] * w[j];
                }
            }
        }
        int m = end - base;
        if (m > 0) {
            long long rec = (base + lane < end) ? csr_rec[base + lane] : 0;
            for (int j = 0; j < m; ++j) {
                long long r = __shfl(rec, j, 8);
                int sn = (int)(unsigned)(r & 0xffffffffLL);
                float w = __int_as_float((int)(r >> 32));
                uint4 v = *reinterpret_cast<const uint4*>(Hin + (size_t)sn * HIDF + lane * 16);
                const unsigned* vw = reinterpret_cast<const unsigned*>(&v);
                #pragma unroll
                for (int d = 0; d < 4; ++d) {
                    f32x2 lo = __builtin_amdgcn_cvt_pk_f32_fp8((int)vw[d], false);
                    f32x2 hi = __builtin_amdgcn_cvt_pk_f32_fp8((int)vw[d], true);
                    acc[d * 4 + 0] += lo[0] * w; acc[d * 4 + 1] += lo[1] * w;
                    acc[d * 4 + 2] += hi[0] * w; acc[d * 4 + 3] += hi[1] * w;
                }
            }
        }
        // bias + relu (f32, single round) -> bf16 A-tile
        #pragma unroll
        for (int i = 0; i < 16; ++i) {
            float vb = acc[i] + bias[lane * 16 + i];
            agg[nl][lane * 16 + i] = f2b(fmaxf(vb, 0.f));
        }
    } else {
        #pragma unroll
        for (int i = 0; i < 16; ++i) agg[nl][lane * 16 + i] = 0;
    }
    __syncthreads();
    // Phase B: MFMA. wave wv: row tile mt = wv>>1 (16 rows), col tiles ct0..ct0+3
    int wv = threadIdx.x >> 6;
    int l  = threadIdx.x & 63;
    int mt  = wv >> 1;
    int ct0 = (wv & 1) * 4;
    int arow = mt * 16 + (l & 15);
    int koff = (l >> 4) * 8;
    f32x4 acc4[4] = {};
    #pragma unroll
    for (int kt = 0; kt < 4; ++kt) {
        int kbase = kt * 32 + koff;
        bf16x8 a = *reinterpret_cast<bf16x8*>(&agg[arow][kbase]);
        #pragma unroll
        for (int c = 0; c < 4; ++c) {
            int ct = ct0 + c;
            bf16x8 b = *reinterpret_cast<const bf16x8*>(&Wfrag[((kt * 8 + ct) * 64 + l) * 8]);
            acc4[c] = __builtin_amdgcn_mfma_f32_16x16x32_bf16(a, b, acc4[c], 0, 0, 0);
        }
    }
    int rloc = mt * 16 + ((l >> 4) << 2);
    int cbase = l & 15;
    #pragma unroll
    for (int c = 0; c < 4; ++c) {
        int ct = ct0 + c;
        #pragma unroll
        for (int r = 0; r < 4; ++r) {
            int gr = node0 + rloc + r;
            if (gr < n) Hout[(size_t)gr * HIDF + ct * 16 + cbase] = f2fp8(acc4[c][r]);
        }
    }
}

// ---------------- FUSED final gather + mean pool + centroid head: one block per graph ----------------
// batch is sorted -> graph b's nodes form contiguous range [s,e). 64 groups of 8 lanes gather
// node rows (f32) and accumulate partial feature sums directly; reduce in LDS; head on wave 0.
__device__ __forceinline__ int lower_bound_i(const int* __restrict__ a, int n, int key) {
    int lo = 0, hi = n;
    while (lo < hi) { int mid = (lo + hi) >> 1; if (a[mid] < key) lo = mid + 1; else hi = mid; }
    return lo;
}

__global__ __launch_bounds__(512) void gather_pool_final_kernel(
        const unsigned char* __restrict__ Hin,
        const int* __restrict__ rowptr,
        const long long* __restrict__ csr_rec,
        const float* __restrict__ selfw,
        const int* __restrict__ batch,
        const float* __restrict__ b3,
        const float* __restrict__ centroids,
        const float* __restrict__ std_scale,
        const float* __restrict__ ac_temp,
        float* __restrict__ out, int n) {
    __shared__ float part[64][HIDF];   // 32 KB partial sums
    __shared__ float gm[HIDF];
    int b = blockIdx.x;
    int grp  = threadIdx.x >> 3;       // group 0..63
    int lane = threadIdx.x & 7;        // feature segment [lane*16, lane*16+16)
    int s = lower_bound_i(batch, n, b);
    int e = lower_bound_i(batch, n, b + 1);
    float acc[16];
    #pragma unroll
    for (int i = 0; i < 16; ++i) acc[i] = 0.f;
    for (int node = s + grp; node < e; node += 64) {
        float t[16];
        {
            uint4 sv = *reinterpret_cast<const uint4*>(Hin + (size_t)node * HIDF + lane * 16);
            const unsigned* svw = reinterpret_cast<const unsigned*>(&sv);
            float sw = selfw[node];
            #pragma unroll
            for (int d = 0; d < 4; ++d) {
                f32x2 lo = __builtin_amdgcn_cvt_pk_f32_fp8((int)svw[d], false);
                f32x2 hi = __builtin_amdgcn_cvt_pk_f32_fp8((int)svw[d], true);
                t[d * 4 + 0] = lo[0] * sw; t[d * 4 + 1] = lo[1] * sw;
                t[d * 4 + 2] = hi[0] * sw; t[d * 4 + 3] = hi[1] * sw;
            }
        }
        int beg = rowptr[node], end = rowptr[node + 1];
        int nfull = (end - beg) >> 3;
        int base = beg;
        for (int fb = 0; fb < nfull; ++fb, base += 8) {
            long long rec = csr_rec[base + lane];
            uint4 v[8];
            float w[8];
            #pragma unroll
            for (int j = 0; j < 8; ++j) {
                long long r = __shfl(rec, j, 8);
                int sn = (int)(unsigned)(r & 0xffffffffLL);
                w[j] = __int_as_float((int)(r >> 32));
                v[j] = *reinterpret_cast<const uint4*>(Hin + (size_t)sn * HIDF + lane * 16);
            }
            #pragma unroll
            for (int j = 0; j < 8; ++j) {
                const unsigned* vw = reinterpret_cast<const unsigned*>(&v[j]);
                #pragma unroll
                for (int d = 0; d < 4; ++d) {
                    f32x2 lo = __builtin_amdgcn_cvt_pk_f32_fp8((int)vw[d], false);
                    f32x2 hi = __builtin_amdgcn_cvt_pk_f32_fp8((int)vw[d], true);
                    t[d * 4 + 0] += lo[0] * w[j]; t[d * 4 + 1] += lo[1] * w[j];
                    t[d * 4 + 2] += hi[0] * w[j]; t[d * 4 + 3] += hi[1] * w[j];
                }
            }
        }
        int m = end - base;
        if (m > 0) {
            long long rec = (base + lane < end) ? csr_rec[base + lane] : 0;
            for (int j = 0; j < m; ++j) {
                long long r = __shfl(rec, j, 8);
                int sn = (int)(unsigned)(r & 0xffffffffLL);
                float w = __int_as_float((int)(r >> 32));
                uint4 v = *reinterpret_cast<const uint4*>(Hin + (size_t)sn * HIDF + lane * 16);
                const unsigned* vw = reinterpret_cast<const unsigned*>(&v);
                #pragma unroll
                for (int d = 0; d < 4; ++d) {
                    f32x2 lo = __builtin_amdgcn_cvt_pk_f32_fp8((int)vw[d], false);
                    f32x2 hi = __builtin_amdgcn_cvt_pk_f32_fp8((int)vw[d], true);
                    t[d * 4 + 0] += lo[0] * w; t[d * 4 + 1] += lo[1] * w;
                    t[d * 4 + 2] += hi[0] * w; t[d * 4 + 3] += hi[1] * w;
                }
            }
        }
        #pragma unroll
        for (int i = 0; i < 16; ++i) acc[i] += t[i];
    }
    #pragma unroll
    for (int i = 0; i < 16; ++i) part[grp][lane * 16 + i] = acc[i];
    __syncthreads();
    if (threadIdx.x < HIDF) {
        int f = threadIdx.x;
        float sum = 0.f;
        #pragma unroll 8
        for (int g = 0; g < 64; ++g) sum += part[g][f];
        float cnt = fmaxf((float)(e - s), 1.0f);
        gm[f] = sum / cnt + b3[f];
    }
    __syncthreads();
    if (threadIdx.x < 64) {
        int l = threadIdx.x;
        float g0 = gm[l];
        float g1 = gm[64 + l];
        float mind = 1e30f;
        for (int c = 0; c < NCLS; ++c) {
            float dd[2];
            #pragma unroll
            for (int cent = 0; cent < 2; ++cent) {
                const float* cp = &centroids[(c * 2 + cent) * HIDF];
                float df0 = cp[l] - g0;
                float df1 = cp[64 + l] - g1;
                float p = df0 * df0 + df1 * df1;
                #pragma unroll
                for (int off = 32; off > 0; off >>= 1) p += __shfl_xor(p, off);
                dd[cent] = p;
            }
            float dist = fminf(sqrtf(dd[0]), sqrtf(dd[1]));
            mind = fminf(mind, dist);
            if (l == 0) out[b * NCLS + c] = -dist;
        }
        if (l == 0) {
            float ss = std_scale[0];
            float clipped = fminf(fmaxf(ss, 0.0f), 5.0f);
            float max_ac = 1.0f + clipped * 0.0f;      // RUNNING_MEAN=1, sqrt(RUNNING_VAR)=0
            float accept = max_ac - mind;
            float soft = 1.0f / (1.0f + expf(-accept / ac_temp[0]));
            out[NGR * NCLS + b] = soft;
        }
    }
}

// ---------------- launch ----------------
extern "C" void kernel_launch(void* const* d_in, const int* in_sizes, int n_in,
                              void* d_out, int out_size, void* d_ws, size_t ws_size,
                              hipStream_t stream) {
    const float* x         = (const float*)d_in[0];
    const int*   edge      = (const int*)d_in[1];
    const int*   batch     = (const int*)d_in[2];
    const float* W1        = (const float*)d_in[3];
    const float* b1        = (const float*)d_in[4];
    const float* W2        = (const float*)d_in[5];
    const float* b2        = (const float*)d_in[6];
    const float* W3        = (const float*)d_in[7];
    const float* b3        = (const float*)d_in[8];
    const float* centroids = (const float*)d_in[9];
    const float* std_scale = (const float*)d_in[10];
    const float* ac_temp   = (const float*)d_in[11];
    float* out = (float*)d_out;

    const int n  = NN;
    const int nE = in_sizes[1] / 2;
    const int* srcp = edge;
    const int* dstp = edge + nE;
    const int nch = (nE + CHSZ - 1) / CHSZ;

    // workspace layout (256B aligned)
    char* ws = (char*)d_ws;
    size_t off = 0;
    auto alloc = [&](size_t bytes) { void* p = ws + off; off = (off + bytes + 255) & ~(size_t)255; return p; };
    unsigned char*  hP = (unsigned char*) alloc((size_t)NN * HIDF);      // fp8 table (ping)
    unsigned char*  hQ = (unsigned char*) alloc((size_t)NN * HIDF);      // fp8 table (pong)
    unsigned short* Wf = (unsigned short*)alloc((size_t)3 * HIDF * HIDF * 2);
    float* dinv    = (float*)alloc((size_t)NN * 4);
    float* selfw   = (float*)alloc((size_t)NN * 4);
    int*   cnt     = (int*)  alloc((size_t)NN * 4);
    int*   rowptr  = (int*)  alloc((size_t)(NN + 1) * 4);
    long long* csr_rec  = (long long*)alloc((size_t)nE * 8);
    long long* recs_bin = (long long*)alloc((size_t)nE * 8);
    int2*  cando   = (int2*) alloc((size_t)nch * NBKT * 8);
    int*   bktsum  = (int*)  alloc((size_t)NBKT * 4);
    int*   bktoff  = (int*)  alloc((size_t)NBKT * 4);

    // ---- weight prep + CSR build (CSR reused by all 3 layers) ----
    wprep_kernel<<<192, 256, 0, stream>>>(W1, W2, W3, Wf);
    bin_kernel<<<nch, 256, 0, stream>>>(srcp, dstp, recs_bin, cando, nE);
    bucket_count_kernel<<<NBKT, 512, 0, stream>>>(recs_bin, cando, cnt, bktsum, dinv, selfw, nch, n);
    scan_bkt_kernel<<<1, 512, 0, stream>>>(bktsum, bktoff, NBKT);
    bucket_fill_kernel<<<NBKT, 512, 0, stream>>>(recs_bin, cando, cnt, bktoff, dinv, rowptr, csr_rec, nch, n, nE);

    int gemm_blocks  = (n + 63) / 64;
    int fused_blocks = (n + 63) / 64;

    // layer 1 GEMM: x @ W1 -> hP (fp8)
    mfma_gemm_kernel<<<gemm_blocks, 256, 0, stream>>>(x, Wf, hP, n);
    // fused: gather(hP) -> +b1,relu -> @W2 -> hQ (fp8)
    fused_gather_gemm_kernel<<<fused_blocks, 512, 0, stream>>>(hP, rowptr, csr_rec, selfw, b1, Wf + 16384, hQ, n);
    // fused: gather(hQ) -> +b2,relu -> @W3 -> hP (fp8)
    fused_gather_gemm_kernel<<<fused_blocks, 512, 0, stream>>>(hQ, rowptr, csr_rec, selfw, b2, Wf + 32768, hP, n);
    // fused final gather + mean pool (+b3) + centroid head
    gather_pool_final_kernel<<<NGR, 512, 0, stream>>>(hP, rowptr, csr_rec, selfw, batch, b3,
                                                      centroids, std_scale, ac_temp, out, n);
}